// Round 8
// baseline (1491.446 us; speedup 1.0000x reference)
//
#include <hip/hip_runtime.h>
#include <cstdint>

typedef unsigned short u16;
typedef __attribute__((ext_vector_type(8))) short short8;
typedef __attribute__((ext_vector_type(4))) short s16x4;
typedef __attribute__((ext_vector_type(4))) float f32x4;

#define MFMA_16x16x32(a,b,c) __builtin_amdgcn_mfma_f32_16x16x32_bf16(a,b,c,0,0,0)

// async global->LDS, 16B per lane, wave covers 1024B (16 rows of a [*][32] bf16 tile)
#define GLDS16(lds, g) __builtin_amdgcn_global_load_lds( \
    (const __attribute__((address_space(1))) unsigned int*)(g), \
    (__attribute__((address_space(3))) unsigned int*)(lds), 16, 0, 0)

#define VMCNT8()  asm volatile("s_waitcnt vmcnt(8)" ::: "memory")
#define VMCNT6()  asm volatile("s_waitcnt vmcnt(6)" ::: "memory")
#define VMCNT0()  asm volatile("s_waitcnt vmcnt(0)" ::: "memory")

#define BB 2
#define SS 1024
#define DD 2048
#define HH 16
#define HKK 4
#define HDD 128
#define EE 16
#define NTOP 6
#define II 1024
#define ISS 2048
#define TT 2048
#define CAP 2048

__device__ __forceinline__ u16 f2b(float f) {
    union { float f; uint32_t u; } v; v.f = f;
    uint32_t r = v.u + 0x7FFFu + ((v.u >> 16) & 1u);
    return (u16)(r >> 16);
}
__device__ __forceinline__ float b2f(u16 h) {
    union { uint32_t u; float f; } v; v.u = ((uint32_t)h) << 16;
    return v.f;
}
__device__ __forceinline__ void fsplit(float f, u16& hi, u16& lo) {
    u16 h = f2b(f);
    hi = h;
    lo = f2b(f - b2f(h));
}

// ---------- Prep: transpose+convert W f32 [R][C] -> bf16 [C][R] (hi[,lo]) ---
template<bool SPLIT>
__global__ __launch_bounds__(256) void k_prep(
    const float* __restrict__ In, u16* __restrict__ Oh, u16* __restrict__ Ol,
    int R, int C)
{
    const size_t zoff = (size_t)blockIdx.z * R * C;
    In += zoff; Oh += zoff; if (SPLIT) Ol += zoff;
    const int r0 = blockIdx.y * 32, c0 = blockIdx.x * 32;
    __shared__ float tile[32][33];
    const int tx = threadIdx.x & 31, ty = threadIdx.x >> 5;
    #pragma unroll
    for (int i = 0; i < 4; ++i)
        tile[ty + i*8][tx] = In[(size_t)(r0 + ty + i*8)*C + c0 + tx];
    __syncthreads();
    const int c = threadIdx.x >> 3, rs = (threadIdx.x & 7) * 4;
    s16x4 hv, lv;
    #pragma unroll
    for (int j = 0; j < 4; ++j) {
        float f = tile[rs + j][c];
        u16 hb = f2b(f);
        hv[j] = (short)hb;
        if (SPLIT) lv[j] = (short)f2b(f - b2f(hb));
        else lv[j] = 0;
    }
    *(s16x4*)(Oh + (size_t)(c0 + c)*R + r0 + rs) = hv;
    if (SPLIT) *(s16x4*)(Ol + (size_t)(c0 + c)*R + r0 + rs) = lv;
}

// ---------------- RMSNorm f32 in -> split bf16 (hi,lo) ----------------------
__global__ __launch_bounds__(256) void k_rmsnorm_split(
    const float* __restrict__ X, const float* __restrict__ Wt,
    u16* __restrict__ Oh, u16* __restrict__ Ol)
{
    const int t = blockIdx.x;
    const float* x = X + (size_t)t * DD;
    const int base = threadIdx.x * 8;
    f32x4 v0 = *(const f32x4*)(x + base);
    f32x4 v1 = *(const f32x4*)(x + base + 4);
    float ss = 0.f;
    #pragma unroll
    for (int j = 0; j < 4; ++j) ss += v0[j]*v0[j] + v1[j]*v1[j];
    #pragma unroll
    for (int o = 1; o < 64; o <<= 1) ss += __shfl_xor(ss, o);
    __shared__ float red[4];
    if ((threadIdx.x & 63) == 0) red[threadIdx.x >> 6] = ss;
    __syncthreads();
    float tot = red[0] + red[1] + red[2] + red[3];
    float inv = rsqrtf(tot * (1.0f/DD) + 1e-6f);
    f32x4 w0 = *(const f32x4*)(Wt + base);
    f32x4 w1 = *(const f32x4*)(Wt + base + 4);
    u16* oh = Oh + (size_t)t*DD + base;
    u16* ol = Ol + (size_t)t*DD + base;
    #pragma unroll
    for (int j = 0; j < 4; ++j) {
        float y0 = v0[j]*inv*w0[j];
        float y1 = v1[j]*inv*w1[j];
        fsplit(y0, oh[j],   ol[j]);
        fsplit(y1, oh[4+j], ol[4+j]);
    }
}

// ---------------- RMSNorm f32 in -> bf16 + f32 ------------------------------
__global__ __launch_bounds__(256) void k_rmsnorm_bf(
    const float* __restrict__ X, const float* __restrict__ Wt,
    u16* __restrict__ Ob, float* __restrict__ Of)
{
    const int t = blockIdx.x;
    const float* x = X + (size_t)t * DD;
    const int base = threadIdx.x * 8;
    f32x4 v0 = *(const f32x4*)(x + base);
    f32x4 v1 = *(const f32x4*)(x + base + 4);
    float ss = 0.f;
    #pragma unroll
    for (int j = 0; j < 4; ++j) ss += v0[j]*v0[j] + v1[j]*v1[j];
    #pragma unroll
    for (int o = 1; o < 64; o <<= 1) ss += __shfl_xor(ss, o);
    __shared__ float red[4];
    if ((threadIdx.x & 63) == 0) red[threadIdx.x >> 6] = ss;
    __syncthreads();
    float tot = red[0] + red[1] + red[2] + red[3];
    float inv = rsqrtf(tot * (1.0f/DD) + 1e-6f);
    f32x4 w0 = *(const f32x4*)(Wt + base);
    f32x4 w1 = *(const f32x4*)(Wt + base + 4);
    u16* ob = Ob + (size_t)t*DD + base;
    float* of = Of + (size_t)t*DD + base;
    #pragma unroll
    for (int j = 0; j < 4; ++j) {
        float y0 = v0[j]*inv*w0[j];
        float y1 = v1[j]*inv*w1[j];
        ob[j] = f2b(y0); ob[4+j] = f2b(y1);
        of[j] = y0;      of[4+j] = y1;
    }
}

// ------- High-precision GEMM: C = Ah@Bh + Ah@Bl + Al@Bh, per-tile 3-term ----
// 2-buffer counted-vmcnt pipeline, 8 GLDS/wave/tile, 48 MFMA/wave/tile.
// EPI 1: f32 + residual; 2: f32
template<int EPI>
__global__ __launch_bounds__(256) void k8_hi(
    const u16* __restrict__ Ah, const u16* __restrict__ Al,
    const u16* __restrict__ Bth, const u16* __restrict__ Btl,
    float* __restrict__ C, const float* __restrict__ Res,
    int M, int N, int K)
{
    __shared__ u16 Ash[2][128][32];
    __shared__ u16 Asl[2][128][32];
    __shared__ u16 Bsh[2][128][32];
    __shared__ u16 Bsl[2][128][32];
    const int tid = threadIdx.x, lane = tid & 63, w = tid >> 6;
    const int m0 = blockIdx.y * 128, n0 = blockIdx.x * 128;
    const int wm = (w >> 1) * 64, wn = (w & 1) * 64;
    const int l15 = lane & 15, lhi = lane >> 4;
    f32x4 acc[4][4];
    #pragma unroll
    for (int a = 0; a < 4; ++a)
        #pragma unroll
        for (int b = 0; b < 4; ++b) acc[a][b] = 0;

    const int gr = w*32 + (lane >> 2), gc = (lane & 3) * 8;
    const u16* ahP = Ah  + (size_t)(m0 + gr) * K + gc;
    const u16* alP = Al  + (size_t)(m0 + gr) * K + gc;
    const u16* bhP = Bth + (size_t)(n0 + gr) * K + gc;
    const u16* blP = Btl + (size_t)(n0 + gr) * K + gc;
    const size_t r16 = (size_t)16 * K;
    const int nt = K >> 5;

    auto stage = [&](int bf, int t) {
        int kk = t << 5;
        GLDS16(&Ash[bf][w*32][0],      ahP + kk);
        GLDS16(&Ash[bf][w*32 + 16][0], ahP + r16 + kk);
        GLDS16(&Asl[bf][w*32][0],      alP + kk);
        GLDS16(&Asl[bf][w*32 + 16][0], alP + r16 + kk);
        GLDS16(&Bsh[bf][w*32][0],      bhP + kk);
        GLDS16(&Bsh[bf][w*32 + 16][0], bhP + r16 + kk);
        GLDS16(&Bsl[bf][w*32][0],      blP + kk);
        GLDS16(&Bsl[bf][w*32 + 16][0], blP + r16 + kk);
    };

    stage(0, 0);
    for (int t = 0; t < nt; ++t) {
        if (t + 1 < nt) { stage((t + 1) & 1, t + 1); VMCNT8(); }
        else VMCNT0();
        __builtin_amdgcn_s_barrier();
        const int cb = t & 1;
        short8 afh[4], afl[4], bfh[4], bfl[4];
        #pragma unroll
        for (int i = 0; i < 4; ++i) {
            afh[i] = *(const short8*)&Ash[cb][wm + i*16 + l15][lhi*8];
            afl[i] = *(const short8*)&Asl[cb][wm + i*16 + l15][lhi*8];
            bfh[i] = *(const short8*)&Bsh[cb][wn + i*16 + l15][lhi*8];
            bfl[i] = *(const short8*)&Bsl[cb][wn + i*16 + l15][lhi*8];
        }
        __builtin_amdgcn_s_setprio(1);
        #pragma unroll
        for (int a = 0; a < 4; ++a)
            #pragma unroll
            for (int b = 0; b < 4; ++b) {
                acc[a][b] = MFMA_16x16x32(afh[a], bfh[b], acc[a][b]);
                acc[a][b] = MFMA_16x16x32(afh[a], bfl[b], acc[a][b]);
                acc[a][b] = MFMA_16x16x32(afl[a], bfh[b], acc[a][b]);
            }
        __builtin_amdgcn_s_setprio(0);
        __builtin_amdgcn_s_barrier();
    }
    #pragma unroll
    for (int a = 0; a < 4; ++a)
      #pragma unroll
      for (int b = 0; b < 4; ++b)
        #pragma unroll
        for (int r = 0; r < 4; ++r) {
            int m = m0 + wm + a*16 + lhi*4 + r;
            int n = n0 + wn + b*16 + l15;
            size_t off = (size_t)m * N + n;
            float v = acc[a][b][r];
            if (EPI == 1) C[off] = v + Res[off];
            else C[off] = v;
        }
}

// ---------------- Plain GEMM: 128x256 tile, 3-buf counted vmcnt -------------
// EPI 0: bf16; 2: f32
template<int EPI>
__global__ __launch_bounds__(256) void k8_gemm(
    const u16* __restrict__ A, const u16* __restrict__ Bt,
    void* __restrict__ C, int M, int N, int K)
{
    __shared__ u16 As[3][128][32];
    __shared__ u16 Bs[3][256][32];
    const int tid = threadIdx.x, lane = tid & 63, w = tid >> 6;
    const int m0 = blockIdx.y * 128, n0 = blockIdx.x * 256;
    const int wm = (w >> 1) * 64, wn = (w & 1) * 128;
    const int l15 = lane & 15, lhi = lane >> 4;
    f32x4 acc[4][8];
    #pragma unroll
    for (int a = 0; a < 4; ++a)
        #pragma unroll
        for (int b = 0; b < 8; ++b) acc[a][b] = 0;

    const int grA = w*32 + (lane >> 2);
    const int grB = w*64 + (lane >> 2);
    const int gc  = (lane & 3) * 8;
    const u16* aP = A  + (size_t)(m0 + grA) * K + gc;
    const u16* bP = Bt + (size_t)(n0 + grB) * K + gc;
    const size_t r16 = (size_t)16 * K;
    const int nt = K >> 5;

    auto stage = [&](int bf, int t) {
        int kk = t << 5;
        GLDS16(&As[bf][w*32][0],      aP + kk);
        GLDS16(&As[bf][w*32 + 16][0], aP + r16 + kk);
        GLDS16(&Bs[bf][w*64][0],      bP + kk);
        GLDS16(&Bs[bf][w*64 + 16][0], bP + r16 + kk);
        GLDS16(&Bs[bf][w*64 + 32][0], bP + 2*r16 + kk);
        GLDS16(&Bs[bf][w*64 + 48][0], bP + 3*r16 + kk);
    };

    stage(0, 0); stage(1, 1);
    for (int t = 0; t < nt; ++t) {
        if (t < nt - 1) VMCNT6(); else VMCNT0();
        __builtin_amdgcn_s_barrier();
        if (t + 2 < nt) stage((t + 2) % 3, t + 2);
        const int cb = t % 3;
        short8 af[4], bf4[8];
        #pragma unroll
        for (int i = 0; i < 4; ++i) af[i] = *(const short8*)&As[cb][wm + i*16 + l15][lhi*8];
        #pragma unroll
        for (int i = 0; i < 8; ++i) bf4[i] = *(const short8*)&Bs[cb][wn + i*16 + l15][lhi*8];
        __builtin_amdgcn_s_setprio(1);
        #pragma unroll
        for (int a = 0; a < 4; ++a)
            #pragma unroll
            for (int b = 0; b < 8; ++b)
                acc[a][b] = MFMA_16x16x32(af[a], bf4[b], acc[a][b]);
        __builtin_amdgcn_s_setprio(0);
    }
    #pragma unroll
    for (int a = 0; a < 4; ++a)
      #pragma unroll
      for (int b = 0; b < 8; ++b)
        #pragma unroll
        for (int r = 0; r < 4; ++r) {
            int m = m0 + wm + a*16 + lhi*4 + r;
            int n = n0 + wn + b*16 + l15;
            size_t off = (size_t)m * N + n;
            float v = acc[a][b][r];
            if (EPI == 0) ((u16*)C)[off] = f2b(v);
            else ((float*)C)[off] = v;
        }
}

// ---------------- Fused GLU GEMM: 128x128 tile, 3-buf counted vmcnt ---------
template<bool GATHER>
__global__ __launch_bounds__(256) void k8_glu(
    const u16* __restrict__ Xb, const u16* __restrict__ W1t,
    const u16* __restrict__ W2t, u16* __restrict__ Hout,
    const int* __restrict__ list, const int* __restrict__ cntp,
    int M, int NE, int K)
{
    const int e = GATHER ? blockIdx.z : 0;
    const int cnt = GATHER ? cntp[e] : M;
    const int m0 = blockIdx.y * 128;
    if (m0 >= cnt) return;
    const int n0 = blockIdx.x * 128;
    const u16* w1 = W1t + (size_t)e * NE * K;
    const u16* w2 = W2t + (size_t)e * NE * K;
    u16* hout = Hout + (size_t)e * CAP * NE;
    const int* lst = GATHER ? (list + e * CAP) : nullptr;

    __shared__ u16 As[3][128][32];
    __shared__ u16 B1s[3][128][32];
    __shared__ u16 B2s[3][128][32];

    const int tid = threadIdx.x, lane = tid & 63, w = tid >> 6;
    const int wm = (w >> 1) * 64, wn = (w & 1) * 64;
    const int l15 = lane & 15, lhi = lane >> 4;
    f32x4 acc1[4][4], acc2[4][4];
    #pragma unroll
    for (int a = 0; a < 4; ++a)
        #pragma unroll
        for (int j = 0; j < 4; ++j) { acc1[a][j] = 0; acc2[a][j] = 0; }

    const int gr = w*32 + (lane >> 2);
    const int gc = (lane & 3) * 8;
    int arow0, arow1;
    if (GATHER) {
        int mr0 = m0 + gr, mr1 = m0 + gr + 16;
        arow0 = (mr0 < cnt) ? (lst[mr0] >> 3) : 0;
        arow1 = (mr1 < cnt) ? (lst[mr1] >> 3) : 0;
    } else { arow0 = m0 + gr; arow1 = m0 + gr + 16; }
    const u16* aP0 = Xb + (size_t)arow0 * K + gc;
    const u16* aP1 = Xb + (size_t)arow1 * K + gc;
    const u16* b1P = w1 + (size_t)(n0 + gr) * K + gc;
    const u16* b2P = w2 + (size_t)(n0 + gr) * K + gc;
    const size_t r16 = (size_t)16 * K;
    const int nt = K >> 5;

    auto stage = [&](int bf, int t) {
        int kk = t << 5;
        GLDS16(&As[bf][w*32][0],       aP0 + kk);
        GLDS16(&As[bf][w*32 + 16][0],  aP1 + kk);
        GLDS16(&B1s[bf][w*32][0],      b1P + kk);
        GLDS16(&B1s[bf][w*32 + 16][0], b1P + r16 + kk);
        GLDS16(&B2s[bf][w*32][0],      b2P + kk);
        GLDS16(&B2s[bf][w*32 + 16][0], b2P + r16 + kk);
    };

    stage(0, 0); stage(1, 1);
    for (int t = 0; t < nt; ++t) {
        if (t < nt - 1) VMCNT6(); else VMCNT0();
        __builtin_amdgcn_s_barrier();
        if (t + 2 < nt) stage((t + 2) % 3, t + 2);
        const int cb = t % 3;
        short8 af[4], b1[4], b2[4];
        #pragma unroll
        for (int i = 0; i < 4; ++i) {
            af[i] = *(const short8*)&As[cb][wm + i*16 + l15][lhi*8];
            b1[i] = *(const short8*)&B1s[cb][wn + i*16 + l15][lhi*8];
            b2[i] = *(const short8*)&B2s[cb][wn + i*16 + l15][lhi*8];
        }
        __builtin_amdgcn_s_setprio(1);
        #pragma unroll
        for (int a = 0; a < 4; ++a)
            #pragma unroll
            for (int j = 0; j < 4; ++j) {
                acc1[a][j] = MFMA_16x16x32(af[a], b1[j], acc1[a][j]);
                acc2[a][j] = MFMA_16x16x32(af[a], b2[j], acc2[a][j]);
            }
        __builtin_amdgcn_s_setprio(0);
    }
    #pragma unroll
    for (int a = 0; a < 4; ++a)
      #pragma unroll
      for (int j = 0; j < 4; ++j)
        #pragma unroll
        for (int r = 0; r < 4; ++r) {
            int m = m0 + wm + a*16 + lhi*4 + r;
            if (m < cnt) {
                int n = n0 + wn + j*16 + l15;
                float g = acc1[a][j][r], u = acc2[a][j][r];
                float hval = g / (1.0f + __expf(-g)) * u;
                hout[(size_t)m * NE + n] = f2b(hval);
            }
        }
}

// ---------------- Routed down GEMM 128x256 with scatter + weight ------------
__global__ __launch_bounds__(256) void k8_down_scatter(
    const u16* __restrict__ Hb, const u16* __restrict__ WdTt,
    u16* __restrict__ Rbuf, const int* __restrict__ list,
    const float* __restrict__ wts, const int* __restrict__ cntp,
    int N, int K)
{
    const int e = blockIdx.z;
    const int cnt = cntp[e];
    const int m0 = blockIdx.y * 128;
    if (m0 >= cnt) return;
    const int n0 = blockIdx.x * 256;
    const u16* A  = Hb   + (size_t)e * CAP * K;
    const u16* Bt = WdTt + (size_t)e * N * K;

    __shared__ u16 As[3][128][32];
    __shared__ u16 Bs[3][256][32];
    const int tid = threadIdx.x, lane = tid & 63, w = tid >> 6;
    const int wm = (w >> 1) * 64, wn = (w & 1) * 128;
    const int l15 = lane & 15, lhi = lane >> 4;
    f32x4 acc[4][8];
    #pragma unroll
    for (int a = 0; a < 4; ++a)
        #pragma unroll
        for (int b = 0; b < 8; ++b) acc[a][b] = 0;

    const int grA = w*32 + (lane >> 2);
    const int grB = w*64 + (lane >> 2);
    const int gc  = (lane & 3) * 8;
    const u16* aP = A  + (size_t)(m0 + grA) * K + gc;
    const u16* bP = Bt + (size_t)(n0 + grB) * K + gc;
    const size_t r16 = (size_t)16 * K;
    const int nt = K >> 5;

    auto stage = [&](int bf, int t) {
        int kk = t << 5;
        GLDS16(&As[bf][w*32][0],      aP + kk);
        GLDS16(&As[bf][w*32 + 16][0], aP + r16 + kk);
        GLDS16(&Bs[bf][w*64][0],      bP + kk);
        GLDS16(&Bs[bf][w*64 + 16][0], bP + r16 + kk);
        GLDS16(&Bs[bf][w*64 + 32][0], bP + 2*r16 + kk);
        GLDS16(&Bs[bf][w*64 + 48][0], bP + 3*r16 + kk);
    };

    stage(0, 0); stage(1, 1);
    for (int t = 0; t < nt; ++t) {
        if (t < nt - 1) VMCNT6(); else VMCNT0();
        __builtin_amdgcn_s_barrier();
        if (t + 2 < nt) stage((t + 2) % 3, t + 2);
        const int cb = t % 3;
        short8 af[4], bf4[8];
        #pragma unroll
        for (int i = 0; i < 4; ++i) af[i] = *(const short8*)&As[cb][wm + i*16 + l15][lhi*8];
        #pragma unroll
        for (int i = 0; i < 8; ++i) bf4[i] = *(const short8*)&Bs[cb][wn + i*16 + l15][lhi*8];
        __builtin_amdgcn_s_setprio(1);
        #pragma unroll
        for (int a = 0; a < 4; ++a)
            #pragma unroll
            for (int b = 0; b < 8; ++b)
                acc[a][b] = MFMA_16x16x32(af[a], bf4[b], acc[a][b]);
        __builtin_amdgcn_s_setprio(0);
    }
    #pragma unroll
    for (int a = 0; a < 4; ++a)
      #pragma unroll
      for (int b = 0; b < 8; ++b)
        #pragma unroll
        for (int r = 0; r < 4; ++r) {
            int m = m0 + wm + a*16 + lhi*4 + r;
            if (m < cnt) {
                int n = n0 + wn + b*16 + l15;
                int enc = list[e*CAP + m];
                float wgt = wts[e*CAP + m];
                int tok = enc >> 3, kk = enc & 7;
                Rbuf[((size_t)tok*NTOP + kk)*N + n] = f2b(acc[a][b][r] * wgt);
            }
        }
}

// ---------------- Fused RoPE + split for q,k (f32 in -> hi/lo bf16) ---------
__global__ __launch_bounds__(256) void k_rope_split(
    const float* __restrict__ QKV,
    const float* __restrict__ Cs, const float* __restrict__ Sn,
    u16* __restrict__ Qh, u16* __restrict__ Ql,
    u16* __restrict__ Kh, u16* __restrict__ Kl)
{
    int id = blockIdx.x * 256 + threadIdx.x;   // TT * 20 * 64
    int pr = id & 63;
    int rest = id >> 6;
    int hh = rest % 20;
    int tok = rest / 20;
    if (tok >= TT) return;
    int d0 = pr * 2;
    float c0 = Cs[(size_t)tok*HDD + d0];
    float c1 = Cs[(size_t)tok*HDD + d0 + 1];
    float s0 = Sn[(size_t)tok*HDD + d0];
    float s1 = Sn[(size_t)tok*HDD + d0 + 1];
    const float* p = QKV + (size_t)tok*3072 + (hh < HH ? hh*HDD : 2048 + (hh - HH)*HDD);
    float x0 = p[d0], x1 = p[d0+1];
    float y0 = x0*c0 - x1*s0;
    float y1 = x1*c1 + x0*s1;
    u16 *oh, *ol;
    size_t ooff;
    if (hh < HH) { ooff = ((size_t)tok*HH + hh)*HDD + d0; oh = Qh; ol = Ql; }
    else         { ooff = ((size_t)tok*HKK + (hh - HH))*HDD + d0; oh = Kh; ol = Kl; }
    fsplit(y0, oh[ooff],     ol[ooff]);
    fsplit(y1, oh[ooff + 1], ol[ooff + 1]);
}

// ---------------- V from qkvf -> split V^T (b,hk,d,s) -----------------------
__global__ __launch_bounds__(256) void k_split_vt(
    const float* __restrict__ QKV, u16* __restrict__ Vth, u16* __restrict__ Vtl)
{
    int id = blockIdx.x * 256 + threadIdx.x;   // TT*HKK*HDD/8
    int oid = id * 8;
    int s0 = oid & (SS - 1);
    int r = oid >> 10;
    int d = r & (HDD - 1);
    int bh = r >> 7;
    int b = bh >> 2, hk = bh & 3;
    #pragma unroll
    for (int j = 0; j < 8; ++j) {
        int s = s0 + j;
        float v = QKV[(size_t)(b*SS + s)*3072 + 2560 + hk*HDD + d];
        fsplit(v, Vth[oid + j], Vtl[oid + j]);
    }
}

// ---------------- Flash attention, split-bf16 precision ---------------------
__global__ __launch_bounds__(256) void k_attn_hi(
    const u16* __restrict__ Qh, const u16* __restrict__ Ql,
    const u16* __restrict__ Kh, const u16* __restrict__ Kl,
    const u16* __restrict__ Vth, const u16* __restrict__ Vtl,
    u16* __restrict__ Oh, u16* __restrict__ Ol)
{
    const int tid = threadIdx.x;
    const int lane = tid & 63;
    const int w = tid >> 6;
    const int q0 = blockIdx.x * 64;
    const int b = blockIdx.y >> 4;
    const int h = blockIdx.y & 15;
    const int hk = h >> 2;
    const int l15 = lane & 15, lhi = lane >> 4;

    __shared__ u16 Ksh[32][136];
    __shared__ u16 Ksl[32][136];
    __shared__ u16 Vsh[128][40];
    __shared__ u16 Vsl[128][40];
    __shared__ u16 Psh[4][16][40];
    __shared__ u16 Psl[4][16][40];

    short8 qfh[4], qfl[4];
    {
        const int qrow = q0 + w*16 + l15;
        const u16* qph = Qh + ((size_t)(b*SS + qrow)*HH + h)*HDD;
        const u16* qpl = Ql + ((size_t)(b*SS + qrow)*HH + h)*HDD;
        #pragma unroll
        for (int c = 0; c < 4; ++c) {
            qfh[c] = *(const short8*)(qph + c*32 + lhi*8);
            qfl[c] = *(const short8*)(qpl + c*32 + lhi*8);
        }
    }

    f32x4 oacc[8];
    #pragma unroll
    for (int ch = 0; ch < 8; ++ch) oacc[ch] = 0;
    float m_r[4] = {-1e30f, -1e30f, -1e30f, -1e30f};
    float l_r[4] = {0.f, 0.f, 0.f, 0.f};

    const int nkt = (q0 + 64) >> 5;
    const int kr = tid >> 3, kc = (tid & 7) * 16;
    const int vd = tid >> 1, vj = (tid & 1) * 16;

    for (int kt = 0; kt < nkt; ++kt) {
        __syncthreads();
        {
            size_t koff = ((size_t)(b*SS + kt*32 + kr)*HKK + hk)*HDD + kc;
            *(short8*)&Ksh[kr][kc]     = *(const short8*)(Kh + koff);
            *(short8*)&Ksh[kr][kc + 8] = *(const short8*)(Kh + koff + 8);
            *(short8*)&Ksl[kr][kc]     = *(const short8*)(Kl + koff);
            *(short8*)&Ksl[kr][kc + 8] = *(const short8*)(Kl + koff + 8);
        }
        {
            size_t voff = ((size_t)(b*HKK + hk)*HDD + vd)*SS + kt*32 + vj;
            *(short8*)&Vsh[vd][vj]     = *(const short8*)(Vth + voff);
            *(short8*)&Vsh[vd][vj + 8] = *(const short8*)(Vth + voff + 8);
            *(short8*)&Vsl[vd][vj]     = *(const short8*)(Vtl + voff);
            *(short8*)&Vsl[vd][vj + 8] = *(const short8*)(Vtl + voff + 8);
        }
        __syncthreads();

        f32x4 s0 = 0, s1 = 0;
        #pragma unroll
        for (int c = 0; c < 4; ++c) {
            short8 kh0 = *(const short8*)&Ksh[l15][c*32 + lhi*8];
            short8 kl0 = *(const short8*)&Ksl[l15][c*32 + lhi*8];
            short8 kh1 = *(const short8*)&Ksh[16 + l15][c*32 + lhi*8];
            short8 kl1 = *(const short8*)&Ksl[16 + l15][c*32 + lhi*8];
            s0 = MFMA_16x16x32(qfh[c], kh0, s0);
            s0 = MFMA_16x16x32(qfh[c], kl0, s0);
            s0 = MFMA_16x16x32(qfl[c], kh0, s0);
            s1 = MFMA_16x16x32(qfh[c], kh1, s1);
            s1 = MFMA_16x16x32(qfh[c], kl1, s1);
            s1 = MFMA_16x16x32(qfl[c], kh1, s1);
        }
        const int irow0 = q0 + w*16 + lhi*4;
        const int j0 = kt*32 + l15;
        float ef[4];
        #pragma unroll
        for (int r = 0; r < 4; ++r) {
            float a0 = s0[r] * 0.08838834764831845f;
            float a1 = s1[r] * 0.08838834764831845f;
            const int ir = irow0 + r;
            if (j0 > ir) a0 = -1e30f;
            if (j0 + 16 > ir) a1 = -1e30f;
            float mx = fmaxf(a0, a1);
            #pragma unroll
            for (int o = 1; o < 16; o <<= 1) mx = fmaxf(mx, __shfl_xor(mx, o));
            float mn = fmaxf(m_r[r], mx);
            ef[r] = __expf(m_r[r] - mn);
            m_r[r] = mn;
            float p0 = __expf(a0 - mn);
            float p1 = __expf(a1 - mn);
            float ps = p0 + p1;
            #pragma unroll
            for (int o = 1; o < 16; o <<= 1) ps += __shfl_xor(ps, o);
            l_r[r] = l_r[r]*ef[r] + ps;
            fsplit(p0, Psh[w][lhi*4 + r][l15],      Psl[w][lhi*4 + r][l15]);
            fsplit(p1, Psh[w][lhi*4 + r][16 + l15], Psl[w][lhi*4 + r][16 + l15]);
        }
        #pragma unroll
        for (int ch = 0; ch < 8; ++ch) {
            f32x4 t = oacc[ch];
            t[0] *= ef[0]; t[1] *= ef[1]; t[2] *= ef[2]; t[3] *= ef[3];
            oacc[ch] = t;
        }
        __syncthreads();
        short8 pah = *(const short8*)&Psh[w][l15][lhi*8];
        short8 pal = *(const short8*)&Psl[w][l15][lhi*8];
        #pragma unroll
        for (int ch = 0; ch < 8; ++ch) {
            short8 bvh = *(const short8*)&Vsh[ch*16 + l15][lhi*8];
            short8 bvl = *(const short8*)&Vsl[ch*16 + l15][lhi*8];
            oacc[ch] = MFMA_16x16x32(pah, bvh, oacc[ch]);
            oacc[ch] = MFMA_16x16x32(pah, bvl, oacc[ch]);
            oacc[ch] = MFMA_16x16x32(pal, bvh, oacc[ch]);
        }
    }
    #pragma unroll
    for (int r = 0; r < 4; ++r) {
        const int row = q0 + w*16 + lhi*4 + r;
        const float inv = 1.0f / l_r[r];
        u16* oph = Oh + ((size_t)(b*SS + row)*HH + h)*HDD;
        u16* opl = Ol + ((size_t)(b*SS + row)*HH + h)*HDD;
        #pragma unroll
        for (int ch = 0; ch < 8; ++ch) {
            float o = oacc[ch][r] * inv;
            fsplit(o, oph[ch*16 + l15], opl[ch*16 + l15]);
        }
    }
}

// ---------------- Router: f32 logits, softmax, top-6, slot lists ------------
__global__ __launch_bounds__(256) void k_router(
    const float* __restrict__ X, const float* __restrict__ Wg,
    const float* __restrict__ bias,
    int* __restrict__ cnt, int* __restrict__ list, float* __restrict__ wts)
{
    const int t = blockIdx.x;
    const int e = threadIdx.x & 15, sl = threadIdx.x >> 4;
    const float* x = X + (size_t)t * DD;
    float part = 0.f;
    for (int i = 0; i < 128; ++i) {
        int k = sl * 128 + i;
        part += x[k] * Wg[(size_t)k * EE + e];
    }
    __shared__ float red[16][17];
    red[sl][e] = part;
    __syncthreads();
    if (threadIdx.x == 0) {
        float lg[16], pr[16];
        for (int ee = 0; ee < 16; ++ee) {
            float s = 0.f;
            for (int q = 0; q < 16; ++q) s += red[q][ee];
            lg[ee] = s;
        }
        float mx = lg[0];
        for (int ee = 1; ee < 16; ++ee) mx = fmaxf(mx, lg[ee]);
        float sum = 0.f;
        for (int ee = 0; ee < 16; ++ee) { pr[ee] = expf(lg[ee] - mx); sum += pr[ee]; }
        float isum = 1.0f / sum;
        for (int ee = 0; ee < 16; ++ee) pr[ee] *= isum;
        unsigned used = 0;
        int sel[NTOP]; float rw[NTOP]; float s6 = 0.f;
        for (int kk = 0; kk < NTOP; ++kk) {
            int best = 0; float bv = -1e30f;
            for (int ee = 0; ee < 16; ++ee) {
                if (used & (1u << ee)) continue;
                float sc = pr[ee] + bias[ee];
                if (sc > bv) { bv = sc; best = ee; }
            }
            used |= 1u << best;
            sel[kk] = best; rw[kk] = pr[best]; s6 += pr[best];
        }
        float inv6 = 1.0f / fmaxf(s6, 1e-12f);
        for (int kk = 0; kk < NTOP; ++kk) {
            int ee = sel[kk];
            int pos = atomicAdd(&cnt[ee], 1);
            list[ee*CAP + pos] = (t << 3) | kk;
            wts[ee*CAP + pos] = rw[kk] * inv6;
        }
    }
}

// ---------------- Final: out = h2 + shared + sum_kk routed ------------------
__global__ __launch_bounds__(256) void k_final(
    const float* __restrict__ h2, const float* __restrict__ yb,
    const u16* __restrict__ rb, float* __restrict__ out)
{
    int id = blockIdx.x * 256 + threadIdx.x;     // T*D/4
    size_t i4 = (size_t)id * 4;
    int t = id >> 9;
    int d = (id & 511) * 4;
    f32x4 acc = *(const f32x4*)(h2 + i4);
    f32x4 y = *(const f32x4*)(yb + i4);
    acc += y;
    #pragma unroll
    for (int kk = 0; kk < NTOP; ++kk) {
        s16x4 rv = *(const s16x4*)(rb + ((size_t)t*NTOP + kk)*DD + d);
        acc[0] += b2f((u16)rv[0]); acc[1] += b2f((u16)rv[1]);
        acc[2] += b2f((u16)rv[2]); acc[3] += b2f((u16)rv[3]);
    }
    *(f32x4*)(out + i4) = acc;
}

extern "C" void kernel_launch(void* const* d_in, const int* in_sizes, int n_in,
                              void* d_out, int out_size, void* d_ws, size_t ws_size,
                              hipStream_t stream)
{
    (void)in_sizes; (void)n_in; (void)out_size; (void)ws_size;
    const float* hidden = (const float*)d_in[0];
    const float* cosb   = (const float*)d_in[1];
    const float* sinb   = (const float*)d_in[2];
    const float* ln1    = (const float*)d_in[3];
    const float* ln2    = (const float*)d_in[4];
    const float* Wq     = (const float*)d_in[5];
    const float* Wk     = (const float*)d_in[6];
    const float* Wv     = (const float*)d_in[7];
    const float* Wo     = (const float*)d_in[8];
    const float* Wgate  = (const float*)d_in[9];
    const float* cbias  = (const float*)d_in[10];
    const float* Wg     = (const float*)d_in[11];
    const float* Wu     = (const float*)d_in[12];
    const float* Wd     = (const float*)d_in[13];
    const float* Wgs    = (const float*)d_in[14];
    const float* Wus    = (const float*)d_in[15];
    const float* Wds    = (const float*)d_in[16];
    float* out = (float*)d_out;

    char* ws = (char*)d_ws;
    size_t off = 0;
    auto alloc = [&](size_t bytes) {
        void* p = ws + off;
        off = (off + bytes + 255) & ~(size_t)255;
        return p;
    };
    // Pre-transposed bf16 weights
    u16* WqkvTh = (u16*)alloc((size_t)3072*2048*2);
    u16* WqkvTl = (u16*)alloc((size_t)3072*2048*2);
    u16* WoTh   = (u16*)alloc((size_t)2048*2048*2);
    u16* WoTl   = (u16*)alloc((size_t)2048*2048*2);
    u16* WgsT   = (u16*)alloc((size_t)2048*2048*2);
    u16* WusT   = (u16*)alloc((size_t)2048*2048*2);
    u16* WdsT   = (u16*)alloc((size_t)2048*2048*2);
    u16* WgT    = (u16*)alloc((size_t)EE*II*DD*2);
    u16* WuT    = (u16*)alloc((size_t)EE*II*DD*2);
    u16* WdT    = (u16*)alloc((size_t)EE*DD*II*2);
    // Activations
    u16*   x1h  = (u16*)  alloc((size_t)TT*DD*2);
    u16*   x1l  = (u16*)  alloc((size_t)TT*DD*2);
    float* qkvf = (float*)alloc((size_t)TT*3072*4);
    u16*   qh   = (u16*)  alloc((size_t)TT*HH*HDD*2);
    u16*   ql   = (u16*)  alloc((size_t)TT*HH*HDD*2);
    u16*   kh   = (u16*)  alloc((size_t)TT*HKK*HDD*2);
    u16*   kl   = (u16*)  alloc((size_t)TT*HKK*HDD*2);
    u16*   vth  = (u16*)  alloc((size_t)TT*HKK*HDD*2);
    u16*   vtl  = (u16*)  alloc((size_t)TT*HKK*HDD*2);
    u16*   aoh  = (u16*)  alloc((size_t)TT*HH*HDD*2);
    u16*   aol  = (u16*)  alloc((size_t)TT*HH*HDD*2);
    float* h2   = (float*)alloc((size_t)TT*DD*4);
    u16*   x2   = (u16*)  alloc((size_t)TT*DD*2);
    float* x2f  = (float*)alloc((size_t)TT*DD*4);
    int*   cnt  = (int*)  alloc(256);
    int*   lst  = (int*)  alloc((size_t)EE*CAP*4);
    float* wts  = (float*)alloc((size_t)EE*CAP*4);
    u16*   hE   = (u16*)  alloc((size_t)EE*CAP*II*2);
    u16*   rbuf = (u16*)  alloc((size_t)TT*NTOP*DD*2);
    // Aliases (lifetimes disjoint):
    u16*   hs   = x1h;            // [TT][ISS] bf16 = 8MB, x1h dead after QKV
    float* ybuf = qkvf;           // [TT][DD] f32 = 16MB, qkvf dead after splits

    // ---- Weight prep (transpose + bf16 convert [+ split]) ----
    k_prep<true ><<<dim3(64,64,1), 256, 0, stream>>>(Wq, WqkvTh, WqkvTl, 2048, 2048);
    k_prep<true ><<<dim3(16,64,1), 256, 0, stream>>>(Wk, WqkvTh + (size_t)2048*2048, WqkvTl + (size_t)2048*2048, 2048, 512);
    k_prep<true ><<<dim3(16,64,1), 256, 0, stream>>>(Wv, WqkvTh + (size_t)2560*2048, WqkvTl + (size_t)2560*2048, 2048, 512);
    k_prep<true ><<<dim3(64,64,1), 256, 0, stream>>>(Wo, WoTh, WoTl, 2048, 2048);
    k_prep<false><<<dim3(64,64,1), 256, 0, stream>>>(Wgs, WgsT, nullptr, 2048, 2048);
    k_prep<false><<<dim3(64,64,1), 256, 0, stream>>>(Wus, WusT, nullptr, 2048, 2048);
    k_prep<false><<<dim3(64,64,1), 256, 0, stream>>>(Wds, WdsT, nullptr, 2048, 2048);
    k_prep<false><<<dim3(32,64,EE), 256, 0, stream>>>(Wg, WgT, nullptr, 2048, 1024);
    k_prep<false><<<dim3(32,64,EE), 256, 0, stream>>>(Wu, WuT, nullptr, 2048, 1024);
    k_prep<false><<<dim3(64,32,EE), 256, 0, stream>>>(Wd, WdT, nullptr, 1024, 2048);

    // ---- Attention path (split-bf16 high precision) ----
    k_rmsnorm_split<<<TT, 256, 0, stream>>>(hidden, ln1, x1h, x1l);
    k8_hi<2><<<dim3(24,16), 256, 0, stream>>>(x1h, x1l, WqkvTh, WqkvTl, qkvf, nullptr, TT, 3072, DD);
    k_rope_split<<<(TT*20*64)/256, 256, 0, stream>>>(qkvf, cosb, sinb, qh, ql, kh, kl);
    k_split_vt<<<(TT*HKK*HDD/8)/256, 256, 0, stream>>>(qkvf, vth, vtl);
    k_attn_hi<<<dim3(SS/64, BB*HH), 256, 0, stream>>>(qh, ql, kh, kl, vth, vtl, aoh, aol);
    k8_hi<1><<<dim3(16,16), 256, 0, stream>>>(aoh, aol, WoTh, WoTl, h2, hidden, TT, DD, HH*HDD);

    // ---- MoE path ----
    k_rmsnorm_bf<<<TT, 256, 0, stream>>>(h2, ln2, x2, x2f);
    (void)hipMemsetAsync(cnt, 0, 256, stream);
    k_router<<<TT, 256, 0, stream>>>(x2f, Wgate, cbias, cnt, lst, wts);
    k8_glu<false><<<dim3(ISS/128, TT/128, 1), 256, 0, stream>>>(x2, WgsT, WusT, hs, nullptr, nullptr, TT, ISS, DD);
    k8_gemm<2><<<dim3(DD/256, TT/128), 256, 0, stream>>>(hs, WdsT, ybuf, TT, DD, ISS);
    k8_glu<true><<<dim3(II/128, CAP/128, EE), 256, 0, stream>>>(x2, WgT, WuT, hE, lst, cnt, CAP, II, DD);
    k8_down_scatter<<<dim3(DD/256, CAP/128, EE), 256, 0, stream>>>(hE, WdT, rbuf, lst, wts, cnt, DD, II);
    k_final<<<(TT*DD/4)/256, 256, 0, stream>>>(h2, ybuf, rbuf, out);
}

// Round 9
// 1303.544 us; speedup vs baseline: 1.1441x; 1.1441x over previous
//
#include <hip/hip_runtime.h>
#include <cstdint>

typedef unsigned short u16;
typedef __attribute__((ext_vector_type(8))) short short8;
typedef __attribute__((ext_vector_type(4))) short s16x4;
typedef __attribute__((ext_vector_type(4))) float f32x4;

#define MFMA_16x16x32(a,b,c) __builtin_amdgcn_mfma_f32_16x16x32_bf16(a,b,c,0,0,0)

// async global->LDS, 16B per lane, wave covers 1024B (16 rows of a [*][32] bf16 tile)
#define GLDS16(lds, g) __builtin_amdgcn_global_load_lds( \
    (const __attribute__((address_space(1))) unsigned int*)(g), \
    (__attribute__((address_space(3))) unsigned int*)(lds), 16, 0, 0)

#define BB 2
#define SS 1024
#define DD 2048
#define HH 16
#define HKK 4
#define HDD 128
#define EE 16
#define NTOP 6
#define II 1024
#define ISS 2048
#define TT 2048
#define CAP 2048

__device__ __forceinline__ u16 f2b(float f) {
    union { float f; uint32_t u; } v; v.f = f;
    uint32_t r = v.u + 0x7FFFu + ((v.u >> 16) & 1u);
    return (u16)(r >> 16);
}
__device__ __forceinline__ float b2f(u16 h) {
    union { uint32_t u; float f; } v; v.u = ((uint32_t)h) << 16;
    return v.f;
}
__device__ __forceinline__ void fsplit(float f, u16& hi, u16& lo) {
    u16 h = f2b(f);
    hi = h;
    lo = f2b(f - b2f(h));
}

// ---------- Prep: transpose+convert W f32 [R][C] -> bf16 [C][R] (hi[,lo]) ---
template<bool SPLIT>
__global__ __launch_bounds__(256) void k_prep(
    const float* __restrict__ In, u16* __restrict__ Oh, u16* __restrict__ Ol,
    int R, int C)
{
    const size_t zoff = (size_t)blockIdx.z * R * C;
    In += zoff; Oh += zoff; if (SPLIT) Ol += zoff;
    const int r0 = blockIdx.y * 32, c0 = blockIdx.x * 32;
    __shared__ float tile[32][33];
    const int tx = threadIdx.x & 31, ty = threadIdx.x >> 5;
    #pragma unroll
    for (int i = 0; i < 4; ++i)
        tile[ty + i*8][tx] = In[(size_t)(r0 + ty + i*8)*C + c0 + tx];
    __syncthreads();
    const int c = threadIdx.x >> 3, rs = (threadIdx.x & 7) * 4;
    s16x4 hv, lv;
    #pragma unroll
    for (int j = 0; j < 4; ++j) {
        float f = tile[rs + j][c];
        u16 hb = f2b(f);
        hv[j] = (short)hb;
        if (SPLIT) lv[j] = (short)f2b(f - b2f(hb));
        else lv[j] = 0;
    }
    *(s16x4*)(Oh + (size_t)(c0 + c)*R + r0 + rs) = hv;
    if (SPLIT) *(s16x4*)(Ol + (size_t)(c0 + c)*R + r0 + rs) = lv;
}

// ---------------- RMSNorm f32 in -> split bf16 (hi,lo) ----------------------
__global__ __launch_bounds__(256) void k_rmsnorm_split(
    const float* __restrict__ X, const float* __restrict__ Wt,
    u16* __restrict__ Oh, u16* __restrict__ Ol)
{
    const int t = blockIdx.x;
    const float* x = X + (size_t)t * DD;
    const int base = threadIdx.x * 8;
    f32x4 v0 = *(const f32x4*)(x + base);
    f32x4 v1 = *(const f32x4*)(x + base + 4);
    float ss = 0.f;
    #pragma unroll
    for (int j = 0; j < 4; ++j) ss += v0[j]*v0[j] + v1[j]*v1[j];
    #pragma unroll
    for (int o = 1; o < 64; o <<= 1) ss += __shfl_xor(ss, o);
    __shared__ float red[4];
    if ((threadIdx.x & 63) == 0) red[threadIdx.x >> 6] = ss;
    __syncthreads();
    float tot = red[0] + red[1] + red[2] + red[3];
    float inv = rsqrtf(tot * (1.0f/DD) + 1e-6f);
    f32x4 w0 = *(const f32x4*)(Wt + base);
    f32x4 w1 = *(const f32x4*)(Wt + base + 4);
    u16* oh = Oh + (size_t)t*DD + base;
    u16* ol = Ol + (size_t)t*DD + base;
    #pragma unroll
    for (int j = 0; j < 4; ++j) {
        float y0 = v0[j]*inv*w0[j];
        float y1 = v1[j]*inv*w1[j];
        fsplit(y0, oh[j],   ol[j]);
        fsplit(y1, oh[4+j], ol[4+j]);
    }
}

// ---------------- RMSNorm f32 in -> bf16 + f32 ------------------------------
__global__ __launch_bounds__(256) void k_rmsnorm_bf(
    const float* __restrict__ X, const float* __restrict__ Wt,
    u16* __restrict__ Ob, float* __restrict__ Of)
{
    const int t = blockIdx.x;
    const float* x = X + (size_t)t * DD;
    const int base = threadIdx.x * 8;
    f32x4 v0 = *(const f32x4*)(x + base);
    f32x4 v1 = *(const f32x4*)(x + base + 4);
    float ss = 0.f;
    #pragma unroll
    for (int j = 0; j < 4; ++j) ss += v0[j]*v0[j] + v1[j]*v1[j];
    #pragma unroll
    for (int o = 1; o < 64; o <<= 1) ss += __shfl_xor(ss, o);
    __shared__ float red[4];
    if ((threadIdx.x & 63) == 0) red[threadIdx.x >> 6] = ss;
    __syncthreads();
    float tot = red[0] + red[1] + red[2] + red[3];
    float inv = rsqrtf(tot * (1.0f/DD) + 1e-6f);
    f32x4 w0 = *(const f32x4*)(Wt + base);
    f32x4 w1 = *(const f32x4*)(Wt + base + 4);
    u16* ob = Ob + (size_t)t*DD + base;
    float* of = Of + (size_t)t*DD + base;
    #pragma unroll
    for (int j = 0; j < 4; ++j) {
        float y0 = v0[j]*inv*w0[j];
        float y1 = v1[j]*inv*w1[j];
        ob[j] = f2b(y0); ob[4+j] = f2b(y1);
        of[j] = y0;      of[4+j] = y1;
    }
}

// ------- High-precision GEMM: C = (Ah+Al) @ (Bh+Bl)^T, pre-split bf16 -------
// 2-phase prefetch, dbuf LDS. EPI 1: f32 + residual; 2: f32
template<int EPI>
__global__ __launch_bounds__(256) void k_gemm_hi(
    const u16* __restrict__ Ah, const u16* __restrict__ Al,
    const u16* __restrict__ Bth, const u16* __restrict__ Btl,
    float* __restrict__ C, const float* __restrict__ Res,
    int M, int N, int K)
{
    __shared__ u16 Ash[2][128][32];
    __shared__ u16 Asl[2][128][32];
    __shared__ u16 Bsh[2][128][32];
    __shared__ u16 Bsl[2][128][32];
    const int tid = threadIdx.x;
    const int lane = tid & 63;
    const int w = tid >> 6;
    const int m0 = blockIdx.y * 128, n0 = blockIdx.x * 128;
    const int wm = (w >> 1) * 64, wn = (w & 1) * 64;
    const int l15 = lane & 15, lhi = lane >> 4;
    f32x4 acc[4][4];
    #pragma unroll
    for (int a = 0; a < 4; ++a)
        #pragma unroll
        for (int b = 0; b < 4; ++b) acc[a][b] = 0;

    const int gr = w*32 + (lane >> 2);
    const int gc = (lane & 3) * 8;
    const u16* ahP0 = Ah  + (size_t)(m0 + gr) * K + gc;
    const u16* alP0 = Al  + (size_t)(m0 + gr) * K + gc;
    const u16* bhP0 = Bth + (size_t)(n0 + gr) * K + gc;
    const u16* blP0 = Btl + (size_t)(n0 + gr) * K + gc;
    const size_t r16 = (size_t)16 * K;

    // prologue: stage tile 0 into buf 0
    GLDS16(&Ash[0][w*32][0],      ahP0);
    GLDS16(&Ash[0][w*32 + 16][0], ahP0 + r16);
    GLDS16(&Asl[0][w*32][0],      alP0);
    GLDS16(&Asl[0][w*32 + 16][0], alP0 + r16);
    GLDS16(&Bsh[0][w*32][0],      bhP0);
    GLDS16(&Bsh[0][w*32 + 16][0], bhP0 + r16);
    GLDS16(&Bsl[0][w*32][0],      blP0);
    GLDS16(&Bsl[0][w*32 + 16][0], blP0 + r16);
    __syncthreads();

    int cur = 0;
    for (int k0 = 0; k0 < K; k0 += 32) {
        const int nxt = k0 + 32;
        if (nxt < K) {
            GLDS16(&Ash[cur^1][w*32][0],      ahP0 + nxt);
            GLDS16(&Ash[cur^1][w*32 + 16][0], ahP0 + r16 + nxt);
            GLDS16(&Asl[cur^1][w*32][0],      alP0 + nxt);
            GLDS16(&Asl[cur^1][w*32 + 16][0], alP0 + r16 + nxt);
            GLDS16(&Bsh[cur^1][w*32][0],      bhP0 + nxt);
            GLDS16(&Bsh[cur^1][w*32 + 16][0], bhP0 + r16 + nxt);
            GLDS16(&Bsl[cur^1][w*32][0],      blP0 + nxt);
            GLDS16(&Bsl[cur^1][w*32 + 16][0], blP0 + r16 + nxt);
        }
        short8 afh[4], afl[4], bfh[4], bfl[4];
        #pragma unroll
        for (int i = 0; i < 4; ++i) {
            afh[i] = *(const short8*)&Ash[cur][wm + i*16 + l15][lhi*8];
            afl[i] = *(const short8*)&Asl[cur][wm + i*16 + l15][lhi*8];
            bfh[i] = *(const short8*)&Bsh[cur][wn + i*16 + l15][lhi*8];
            bfl[i] = *(const short8*)&Bsl[cur][wn + i*16 + l15][lhi*8];
        }
        #pragma unroll
        for (int a = 0; a < 4; ++a)
            #pragma unroll
            for (int b = 0; b < 4; ++b) {
                acc[a][b] = MFMA_16x16x32(afh[a], bfh[b], acc[a][b]);
                acc[a][b] = MFMA_16x16x32(afh[a], bfl[b], acc[a][b]);
                acc[a][b] = MFMA_16x16x32(afl[a], bfh[b], acc[a][b]);
            }
        __syncthreads();
        cur ^= 1;
    }
    #pragma unroll
    for (int a = 0; a < 4; ++a)
      #pragma unroll
      for (int b = 0; b < 4; ++b)
        #pragma unroll
        for (int r = 0; r < 4; ++r) {
            int m = m0 + wm + a*16 + lhi*4 + r;
            int n = n0 + wn + b*16 + l15;
            size_t off = (size_t)m * N + n;
            float v = acc[a][b][r];
            if (EPI == 1) C[off] = v + Res[off];
            else C[off] = v;
        }
}

// ---------------- Dense GEMM: C(MxN) = A_bf16 @ Bt_bf16^T, 2-phase ----------
// EPI 0: bf16 store; 2: f32 store
template<int EPI>
__global__ __launch_bounds__(256) void k_gemm(
    const u16* __restrict__ A, const u16* __restrict__ Bt,
    void* __restrict__ C, int M, int N, int K)
{
    __shared__ u16 As[2][128][32];
    __shared__ u16 Bs[2][128][32];
    const int tid = threadIdx.x;
    const int lane = tid & 63;
    const int w = tid >> 6;
    const int m0 = blockIdx.y * 128, n0 = blockIdx.x * 128;
    const int wm = (w >> 1) * 64, wn = (w & 1) * 64;
    const int l15 = lane & 15, lhi = lane >> 4;
    f32x4 acc[4][4];
    #pragma unroll
    for (int a = 0; a < 4; ++a)
        #pragma unroll
        for (int b = 0; b < 4; ++b) acc[a][b] = 0;

    const int gr = w*32 + (lane >> 2);
    const int gc = (lane & 3) * 8;
    const u16* aP0 = A  + (size_t)(m0 + gr) * K + gc;
    const u16* bP0 = Bt + (size_t)(n0 + gr) * K + gc;
    const size_t r16 = (size_t)16 * K;

    GLDS16(&As[0][w*32][0],      aP0);
    GLDS16(&As[0][w*32 + 16][0], aP0 + r16);
    GLDS16(&Bs[0][w*32][0],      bP0);
    GLDS16(&Bs[0][w*32 + 16][0], bP0 + r16);
    __syncthreads();

    int cur = 0;
    for (int k0 = 0; k0 < K; k0 += 32) {
        const int nxt = k0 + 32;
        if (nxt < K) {
            GLDS16(&As[cur^1][w*32][0],      aP0 + nxt);
            GLDS16(&As[cur^1][w*32 + 16][0], aP0 + r16 + nxt);
            GLDS16(&Bs[cur^1][w*32][0],      bP0 + nxt);
            GLDS16(&Bs[cur^1][w*32 + 16][0], bP0 + r16 + nxt);
        }
        short8 af[4], bf[4];
        #pragma unroll
        for (int i = 0; i < 4; ++i) af[i] = *(const short8*)&As[cur][wm + i*16 + l15][lhi*8];
        #pragma unroll
        for (int i = 0; i < 4; ++i) bf[i] = *(const short8*)&Bs[cur][wn + i*16 + l15][lhi*8];
        #pragma unroll
        for (int a = 0; a < 4; ++a)
            #pragma unroll
            for (int b = 0; b < 4; ++b)
                acc[a][b] = MFMA_16x16x32(af[a], bf[b], acc[a][b]);
        __syncthreads();
        cur ^= 1;
    }
    #pragma unroll
    for (int a = 0; a < 4; ++a)
      #pragma unroll
      for (int b = 0; b < 4; ++b)
        #pragma unroll
        for (int r = 0; r < 4; ++r) {
            int m = m0 + wm + a*16 + lhi*4 + r;
            int n = n0 + wn + b*16 + l15;
            size_t off = (size_t)m * N + n;
            float v = acc[a][b][r];
            if (EPI == 0) ((u16*)C)[off] = f2b(v);
            else ((float*)C)[off] = v;
        }
}

// ------- Fused GLU GEMM: 128x128 tile, 2-buf (48KB), h=silu(A@W1)*(A@W2) ----
// bpm 562 B/MFMA (vs 750 at N=64) with occupancy-safe LDS (R8 lesson: <=48KB).
template<bool GATHER>
__global__ __launch_bounds__(256) void k_glu(
    const u16* __restrict__ Xb, const u16* __restrict__ W1t,
    const u16* __restrict__ W2t, u16* __restrict__ Hout,
    const int* __restrict__ list, const int* __restrict__ cntp,
    int M, int NE, int K)
{
    const int e = GATHER ? blockIdx.z : 0;
    const int cnt = GATHER ? cntp[e] : M;
    const int m0 = blockIdx.y * 128;
    if (m0 >= cnt) return;
    const int n0 = blockIdx.x * 128;
    const u16* w1 = W1t + (size_t)e * NE * K;
    const u16* w2 = W2t + (size_t)e * NE * K;
    u16* hout = Hout + (size_t)e * CAP * NE;
    const int* lst = GATHER ? (list + e * CAP) : nullptr;

    __shared__ u16 As[2][128][32];
    __shared__ u16 B1s[2][128][32];
    __shared__ u16 B2s[2][128][32];

    const int tid = threadIdx.x, lane = tid & 63, w = tid >> 6;
    const int wm = (w >> 1) * 64, wn = (w & 1) * 64;
    const int l15 = lane & 15, lhi = lane >> 4;
    f32x4 acc1[4][4], acc2[4][4];
    #pragma unroll
    for (int a = 0; a < 4; ++a)
        #pragma unroll
        for (int j = 0; j < 4; ++j) { acc1[a][j] = 0; acc2[a][j] = 0; }

    const int gr = w*32 + (lane >> 2);
    const int gc = (lane & 3) * 8;
    int arow0, arow1;
    if (GATHER) {
        int mr0 = m0 + gr, mr1 = m0 + gr + 16;
        arow0 = (mr0 < cnt) ? (lst[mr0] >> 3) : 0;
        arow1 = (mr1 < cnt) ? (lst[mr1] >> 3) : 0;
    } else { arow0 = m0 + gr; arow1 = m0 + gr + 16; }
    const u16* aP0 = Xb + (size_t)arow0 * K + gc;
    const u16* aP1 = Xb + (size_t)arow1 * K + gc;
    const u16* b1P = w1 + (size_t)(n0 + gr) * K + gc;
    const u16* b2P = w2 + (size_t)(n0 + gr) * K + gc;
    const size_t r16 = (size_t)16 * K;

    auto stage = [&](int bf, int kk) {
        GLDS16(&As[bf][w*32][0],       aP0 + kk);
        GLDS16(&As[bf][w*32 + 16][0],  aP1 + kk);
        GLDS16(&B1s[bf][w*32][0],      b1P + kk);
        GLDS16(&B1s[bf][w*32 + 16][0], b1P + r16 + kk);
        GLDS16(&B2s[bf][w*32][0],      b2P + kk);
        GLDS16(&B2s[bf][w*32 + 16][0], b2P + r16 + kk);
    };

    stage(0, 0);
    __syncthreads();
    int cur = 0;
    for (int k0 = 0; k0 < K; k0 += 32) {
        const int nxt = k0 + 32;
        if (nxt < K) stage(cur ^ 1, nxt);
        short8 af[4], b1[4], b2[4];
        #pragma unroll
        for (int i = 0; i < 4; ++i) {
            af[i] = *(const short8*)&As[cur][wm + i*16 + l15][lhi*8];
            b1[i] = *(const short8*)&B1s[cur][wn + i*16 + l15][lhi*8];
            b2[i] = *(const short8*)&B2s[cur][wn + i*16 + l15][lhi*8];
        }
        #pragma unroll
        for (int a = 0; a < 4; ++a)
            #pragma unroll
            for (int j = 0; j < 4; ++j) {
                acc1[a][j] = MFMA_16x16x32(af[a], b1[j], acc1[a][j]);
                acc2[a][j] = MFMA_16x16x32(af[a], b2[j], acc2[a][j]);
            }
        __syncthreads();
        cur ^= 1;
    }
    #pragma unroll
    for (int a = 0; a < 4; ++a)
      #pragma unroll
      for (int j = 0; j < 4; ++j)
        #pragma unroll
        for (int r = 0; r < 4; ++r) {
            int m = m0 + wm + a*16 + lhi*4 + r;
            if (m < cnt) {
                int n = n0 + wn + j*16 + l15;
                float g = acc1[a][j][r], u = acc2[a][j][r];
                float hval = g / (1.0f + __expf(-g)) * u;
                hout[(size_t)m * NE + n] = f2b(hval);
            }
        }
}

// ---------------- Routed down GEMM with scatter + weight, 2-phase -----------
__global__ __launch_bounds__(256) void k_down_scatter(
    const u16* __restrict__ Hb, const u16* __restrict__ WdTt,
    u16* __restrict__ Rbuf, const int* __restrict__ list,
    const float* __restrict__ wts, const int* __restrict__ cntp,
    int N, int K)
{
    const int e = blockIdx.z;
    const int cnt = cntp[e];
    const int m0 = blockIdx.y * 128;
    if (m0 >= cnt) return;
    const int n0 = blockIdx.x * 128;
    const u16* A  = Hb   + (size_t)e * CAP * K;
    const u16* Bt = WdTt + (size_t)e * N * K;

    __shared__ u16 As[2][128][32];
    __shared__ u16 Bs[2][128][32];
    const int tid = threadIdx.x, lane = tid & 63, w = tid >> 6;
    const int wm = (w >> 1) * 64, wn = (w & 1) * 64;
    const int l15 = lane & 15, lhi = lane >> 4;
    f32x4 acc[4][4];
    #pragma unroll
    for (int a = 0; a < 4; ++a)
        #pragma unroll
        for (int b = 0; b < 4; ++b) acc[a][b] = 0;

    const int gr = w*32 + (lane >> 2);
    const int gc = (lane & 3) * 8;
    const u16* aP0 = A  + (size_t)(m0 + gr) * K + gc;
    const u16* bP0 = Bt + (size_t)(n0 + gr) * K + gc;
    const size_t r16 = (size_t)16 * K;

    GLDS16(&As[0][w*32][0],      aP0);
    GLDS16(&As[0][w*32 + 16][0], aP0 + r16);
    GLDS16(&Bs[0][w*32][0],      bP0);
    GLDS16(&Bs[0][w*32 + 16][0], bP0 + r16);
    __syncthreads();

    int cur = 0;
    for (int k0 = 0; k0 < K; k0 += 32) {
        const int nxt = k0 + 32;
        if (nxt < K) {
            GLDS16(&As[cur^1][w*32][0],      aP0 + nxt);
            GLDS16(&As[cur^1][w*32 + 16][0], aP0 + r16 + nxt);
            GLDS16(&Bs[cur^1][w*32][0],      bP0 + nxt);
            GLDS16(&Bs[cur^1][w*32 + 16][0], bP0 + r16 + nxt);
        }
        short8 af[4], bf[4];
        #pragma unroll
        for (int i = 0; i < 4; ++i) af[i] = *(const short8*)&As[cur][wm + i*16 + l15][lhi*8];
        #pragma unroll
        for (int i = 0; i < 4; ++i) bf[i] = *(const short8*)&Bs[cur][wn + i*16 + l15][lhi*8];
        #pragma unroll
        for (int a = 0; a < 4; ++a)
            #pragma unroll
            for (int b = 0; b < 4; ++b)
                acc[a][b] = MFMA_16x16x32(af[a], bf[b], acc[a][b]);
        __syncthreads();
        cur ^= 1;
    }
    #pragma unroll
    for (int a = 0; a < 4; ++a)
      #pragma unroll
      for (int b = 0; b < 4; ++b)
        #pragma unroll
        for (int r = 0; r < 4; ++r) {
            int m = m0 + wm + a*16 + lhi*4 + r;
            if (m < cnt) {
                int n = n0 + wn + b*16 + l15;
                int enc = list[e*CAP + m];
                float wgt = wts[e*CAP + m];
                int tok = enc >> 3, kk = enc & 7;
                Rbuf[((size_t)tok*NTOP + kk)*N + n] = f2b(acc[a][b][r] * wgt);
            }
        }
}

// ---------------- Fused RoPE + split for q,k (f32 in -> hi/lo bf16) ---------
__global__ __launch_bounds__(256) void k_rope_split(
    const float* __restrict__ QKV,
    const float* __restrict__ Cs, const float* __restrict__ Sn,
    u16* __restrict__ Qh, u16* __restrict__ Ql,
    u16* __restrict__ Kh, u16* __restrict__ Kl)
{
    int id = blockIdx.x * 256 + threadIdx.x;   // TT * 20 * 64
    int pr = id & 63;
    int rest = id >> 6;
    int hh = rest % 20;
    int tok = rest / 20;
    if (tok >= TT) return;
    int d0 = pr * 2;
    float c0 = Cs[(size_t)tok*HDD + d0];
    float c1 = Cs[(size_t)tok*HDD + d0 + 1];
    float s0 = Sn[(size_t)tok*HDD + d0];
    float s1 = Sn[(size_t)tok*HDD + d0 + 1];
    const float* p = QKV + (size_t)tok*3072 + (hh < HH ? hh*HDD : 2048 + (hh - HH)*HDD);
    float x0 = p[d0], x1 = p[d0+1];
    float y0 = x0*c0 - x1*s0;
    float y1 = x1*c1 + x0*s1;
    u16 *oh, *ol;
    size_t ooff;
    if (hh < HH) { ooff = ((size_t)tok*HH + hh)*HDD + d0; oh = Qh; ol = Ql; }
    else         { ooff = ((size_t)tok*HKK + (hh - HH))*HDD + d0; oh = Kh; ol = Kl; }
    fsplit(y0, oh[ooff],     ol[ooff]);
    fsplit(y1, oh[ooff + 1], ol[ooff + 1]);
}

// ---------------- V from qkvf -> split V^T (b,hk,d,s) -----------------------
__global__ __launch_bounds__(256) void k_split_vt(
    const float* __restrict__ QKV, u16* __restrict__ Vth, u16* __restrict__ Vtl)
{
    int id = blockIdx.x * 256 + threadIdx.x;   // TT*HKK*HDD/8
    int oid = id * 8;
    int s0 = oid & (SS - 1);
    int r = oid >> 10;
    int d = r & (HDD - 1);
    int bh = r >> 7;
    int b = bh >> 2, hk = bh & 3;
    #pragma unroll
    for (int j = 0; j < 8; ++j) {
        int s = s0 + j;
        float v = QKV[(size_t)(b*SS + s)*3072 + 2560 + hk*HDD + d];
        fsplit(v, Vth[oid + j], Vtl[oid + j]);
    }
}

// ---------------- Flash attention, split-bf16 precision ---------------------
__global__ __launch_bounds__(256) void k_attn_hi(
    const u16* __restrict__ Qh, const u16* __restrict__ Ql,
    const u16* __restrict__ Kh, const u16* __restrict__ Kl,
    const u16* __restrict__ Vth, const u16* __restrict__ Vtl,
    u16* __restrict__ Oh, u16* __restrict__ Ol)
{
    const int tid = threadIdx.x;
    const int lane = tid & 63;
    const int w = tid >> 6;
    const int q0 = blockIdx.x * 64;
    const int b = blockIdx.y >> 4;
    const int h = blockIdx.y & 15;
    const int hk = h >> 2;
    const int l15 = lane & 15, lhi = lane >> 4;

    __shared__ u16 Ksh[32][136];
    __shared__ u16 Ksl[32][136];
    __shared__ u16 Vsh[128][40];
    __shared__ u16 Vsl[128][40];
    __shared__ u16 Psh[4][16][40];
    __shared__ u16 Psl[4][16][40];

    short8 qfh[4], qfl[4];
    {
        const int qrow = q0 + w*16 + l15;
        const u16* qph = Qh + ((size_t)(b*SS + qrow)*HH + h)*HDD;
        const u16* qpl = Ql + ((size_t)(b*SS + qrow)*HH + h)*HDD;
        #pragma unroll
        for (int c = 0; c < 4; ++c) {
            qfh[c] = *(const short8*)(qph + c*32 + lhi*8);
            qfl[c] = *(const short8*)(qpl + c*32 + lhi*8);
        }
    }

    f32x4 oacc[8];
    #pragma unroll
    for (int ch = 0; ch < 8; ++ch) oacc[ch] = 0;
    float m_r[4] = {-1e30f, -1e30f, -1e30f, -1e30f};
    float l_r[4] = {0.f, 0.f, 0.f, 0.f};

    const int nkt = (q0 + 64) >> 5;
    const int kr = tid >> 3, kc = (tid & 7) * 16;
    const int vd = tid >> 1, vj = (tid & 1) * 16;

    for (int kt = 0; kt < nkt; ++kt) {
        __syncthreads();
        {
            size_t koff = ((size_t)(b*SS + kt*32 + kr)*HKK + hk)*HDD + kc;
            *(short8*)&Ksh[kr][kc]     = *(const short8*)(Kh + koff);
            *(short8*)&Ksh[kr][kc + 8] = *(const short8*)(Kh + koff + 8);
            *(short8*)&Ksl[kr][kc]     = *(const short8*)(Kl + koff);
            *(short8*)&Ksl[kr][kc + 8] = *(const short8*)(Kl + koff + 8);
        }
        {
            size_t voff = ((size_t)(b*HKK + hk)*HDD + vd)*SS + kt*32 + vj;
            *(short8*)&Vsh[vd][vj]     = *(const short8*)(Vth + voff);
            *(short8*)&Vsh[vd][vj + 8] = *(const short8*)(Vth + voff + 8);
            *(short8*)&Vsl[vd][vj]     = *(const short8*)(Vtl + voff);
            *(short8*)&Vsl[vd][vj + 8] = *(const short8*)(Vtl + voff + 8);
        }
        __syncthreads();

        f32x4 s0 = 0, s1 = 0;
        #pragma unroll
        for (int c = 0; c < 4; ++c) {
            short8 kh0 = *(const short8*)&Ksh[l15][c*32 + lhi*8];
            short8 kl0 = *(const short8*)&Ksl[l15][c*32 + lhi*8];
            short8 kh1 = *(const short8*)&Ksh[16 + l15][c*32 + lhi*8];
            short8 kl1 = *(const short8*)&Ksl[16 + l15][c*32 + lhi*8];
            s0 = MFMA_16x16x32(qfh[c], kh0, s0);
            s0 = MFMA_16x16x32(qfh[c], kl0, s0);
            s0 = MFMA_16x16x32(qfl[c], kh0, s0);
            s1 = MFMA_16x16x32(qfh[c], kh1, s1);
            s1 = MFMA_16x16x32(qfh[c], kl1, s1);
            s1 = MFMA_16x16x32(qfl[c], kh1, s1);
        }
        const int irow0 = q0 + w*16 + lhi*4;
        const int j0 = kt*32 + l15;
        float ef[4];
        #pragma unroll
        for (int r = 0; r < 4; ++r) {
            float a0 = s0[r] * 0.08838834764831845f;
            float a1 = s1[r] * 0.08838834764831845f;
            const int ir = irow0 + r;
            if (j0 > ir) a0 = -1e30f;
            if (j0 + 16 > ir) a1 = -1e30f;
            float mx = fmaxf(a0, a1);
            #pragma unroll
            for (int o = 1; o < 16; o <<= 1) mx = fmaxf(mx, __shfl_xor(mx, o));
            float mn = fmaxf(m_r[r], mx);
            ef[r] = __expf(m_r[r] - mn);
            m_r[r] = mn;
            float p0 = __expf(a0 - mn);
            float p1 = __expf(a1 - mn);
            float ps = p0 + p1;
            #pragma unroll
            for (int o = 1; o < 16; o <<= 1) ps += __shfl_xor(ps, o);
            l_r[r] = l_r[r]*ef[r] + ps;
            fsplit(p0, Psh[w][lhi*4 + r][l15],      Psl[w][lhi*4 + r][l15]);
            fsplit(p1, Psh[w][lhi*4 + r][16 + l15], Psl[w][lhi*4 + r][16 + l15]);
        }
        #pragma unroll
        for (int ch = 0; ch < 8; ++ch) {
            f32x4 t = oacc[ch];
            t[0] *= ef[0]; t[1] *= ef[1]; t[2] *= ef[2]; t[3] *= ef[3];
            oacc[ch] = t;
        }
        __syncthreads();
        short8 pah = *(const short8*)&Psh[w][l15][lhi*8];
        short8 pal = *(const short8*)&Psl[w][l15][lhi*8];
        #pragma unroll
        for (int ch = 0; ch < 8; ++ch) {
            short8 bvh = *(const short8*)&Vsh[ch*16 + l15][lhi*8];
            short8 bvl = *(const short8*)&Vsl[ch*16 + l15][lhi*8];
            oacc[ch] = MFMA_16x16x32(pah, bvh, oacc[ch]);
            oacc[ch] = MFMA_16x16x32(pah, bvl, oacc[ch]);
            oacc[ch] = MFMA_16x16x32(pal, bvh, oacc[ch]);
        }
    }
    #pragma unroll
    for (int r = 0; r < 4; ++r) {
        const int row = q0 + w*16 + lhi*4 + r;
        const float inv = 1.0f / l_r[r];
        u16* oph = Oh + ((size_t)(b*SS + row)*HH + h)*HDD;
        u16* opl = Ol + ((size_t)(b*SS + row)*HH + h)*HDD;
        #pragma unroll
        for (int ch = 0; ch < 8; ++ch) {
            float o = oacc[ch][r] * inv;
            fsplit(o, oph[ch*16 + l15], opl[ch*16 + l15]);
        }
    }
}

// ---------------- Router: f32 logits, softmax, top-6, slot lists ------------
__global__ __launch_bounds__(256) void k_router(
    const float* __restrict__ X, const float* __restrict__ Wg,
    const float* __restrict__ bias,
    int* __restrict__ cnt, int* __restrict__ list, float* __restrict__ wts)
{
    const int t = blockIdx.x;
    const int e = threadIdx.x & 15, sl = threadIdx.x >> 4;
    const float* x = X + (size_t)t * DD;
    float part = 0.f;
    for (int i = 0; i < 128; ++i) {
        int k = sl * 128 + i;
        part += x[k] * Wg[(size_t)k * EE + e];
    }
    __shared__ float red[16][17];
    red[sl][e] = part;
    __syncthreads();
    if (threadIdx.x == 0) {
        float lg[16], pr[16];
        for (int ee = 0; ee < 16; ++ee) {
            float s = 0.f;
            for (int q = 0; q < 16; ++q) s += red[q][ee];
            lg[ee] = s;
        }
        float mx = lg[0];
        for (int ee = 1; ee < 16; ++ee) mx = fmaxf(mx, lg[ee]);
        float sum = 0.f;
        for (int ee = 0; ee < 16; ++ee) { pr[ee] = expf(lg[ee] - mx); sum += pr[ee]; }
        float isum = 1.0f / sum;
        for (int ee = 0; ee < 16; ++ee) pr[ee] *= isum;
        unsigned used = 0;
        int sel[NTOP]; float rw[NTOP]; float s6 = 0.f;
        for (int kk = 0; kk < NTOP; ++kk) {
            int best = 0; float bv = -1e30f;
            for (int ee = 0; ee < 16; ++ee) {
                if (used & (1u << ee)) continue;
                float sc = pr[ee] + bias[ee];
                if (sc > bv) { bv = sc; best = ee; }
            }
            used |= 1u << best;
            sel[kk] = best; rw[kk] = pr[best]; s6 += pr[best];
        }
        float inv6 = 1.0f / fmaxf(s6, 1e-12f);
        for (int kk = 0; kk < NTOP; ++kk) {
            int ee = sel[kk];
            int pos = atomicAdd(&cnt[ee], 1);
            list[ee*CAP + pos] = (t << 3) | kk;
            wts[ee*CAP + pos] = rw[kk] * inv6;
        }
    }
}

// ---------------- Final: out = h2 + shared + sum_kk routed ------------------
__global__ __launch_bounds__(256) void k_final(
    const float* __restrict__ h2, const float* __restrict__ yb,
    const u16* __restrict__ rb, float* __restrict__ out)
{
    int id = blockIdx.x * 256 + threadIdx.x;     // T*D/4
    size_t i4 = (size_t)id * 4;
    int t = id >> 9;
    int d = (id & 511) * 4;
    f32x4 acc = *(const f32x4*)(h2 + i4);
    f32x4 y = *(const f32x4*)(yb + i4);
    acc += y;
    #pragma unroll
    for (int kk = 0; kk < NTOP; ++kk) {
        s16x4 rv = *(const s16x4*)(rb + ((size_t)t*NTOP + kk)*DD + d);
        acc[0] += b2f((u16)rv[0]); acc[1] += b2f((u16)rv[1]);
        acc[2] += b2f((u16)rv[2]); acc[3] += b2f((u16)rv[3]);
    }
    *(f32x4*)(out + i4) = acc;
}

extern "C" void kernel_launch(void* const* d_in, const int* in_sizes, int n_in,
                              void* d_out, int out_size, void* d_ws, size_t ws_size,
                              hipStream_t stream)
{
    (void)in_sizes; (void)n_in; (void)out_size; (void)ws_size;
    const float* hidden = (const float*)d_in[0];
    const float* cosb   = (const float*)d_in[1];
    const float* sinb   = (const float*)d_in[2];
    const float* ln1    = (const float*)d_in[3];
    const float* ln2    = (const float*)d_in[4];
    const float* Wq     = (const float*)d_in[5];
    const float* Wk     = (const float*)d_in[6];
    const float* Wv     = (const float*)d_in[7];
    const float* Wo     = (const float*)d_in[8];
    const float* Wgate  = (const float*)d_in[9];
    const float* cbias  = (const float*)d_in[10];
    const float* Wg     = (const float*)d_in[11];
    const float* Wu     = (const float*)d_in[12];
    const float* Wd     = (const float*)d_in[13];
    const float* Wgs    = (const float*)d_in[14];
    const float* Wus    = (const float*)d_in[15];
    const float* Wds    = (const float*)d_in[16];
    float* out = (float*)d_out;

    char* ws = (char*)d_ws;
    size_t off = 0;
    auto alloc = [&](size_t bytes) {
        void* p = ws + off;
        off = (off + bytes + 255) & ~(size_t)255;
        return p;
    };
    // Pre-transposed bf16 weights
    u16* WqkvTh = (u16*)alloc((size_t)3072*2048*2);
    u16* WqkvTl = (u16*)alloc((size_t)3072*2048*2);
    u16* WoTh   = (u16*)alloc((size_t)2048*2048*2);
    u16* WoTl   = (u16*)alloc((size_t)2048*2048*2);
    u16* WgsT   = (u16*)alloc((size_t)2048*2048*2);
    u16* WusT   = (u16*)alloc((size_t)2048*2048*2);
    u16* WdsT   = (u16*)alloc((size_t)2048*2048*2);
    u16* WgT    = (u16*)alloc((size_t)EE*II*DD*2);
    u16* WuT    = (u16*)alloc((size_t)EE*II*DD*2);
    u16* WdT    = (u16*)alloc((size_t)EE*DD*II*2);
    // Activations
    u16*   x1h  = (u16*)  alloc((size_t)TT*DD*2);
    u16*   x1l  = (u16*)  alloc((size_t)TT*DD*2);
    float* qkvf = (float*)alloc((size_t)TT*3072*4);
    u16*   qh   = (u16*)  alloc((size_t)TT*HH*HDD*2);
    u16*   ql   = (u16*)  alloc((size_t)TT*HH*HDD*2);
    u16*   kh   = (u16*)  alloc((size_t)TT*HKK*HDD*2);
    u16*   kl   = (u16*)  alloc((size_t)TT*HKK*HDD*2);
    u16*   vth  = (u16*)  alloc((size_t)TT*HKK*HDD*2);
    u16*   vtl  = (u16*)  alloc((size_t)TT*HKK*HDD*2);
    u16*   aoh  = (u16*)  alloc((size_t)TT*HH*HDD*2);
    u16*   aol  = (u16*)  alloc((size_t)TT*HH*HDD*2);
    float* h2   = (float*)alloc((size_t)TT*DD*4);
    u16*   x2   = (u16*)  alloc((size_t)TT*DD*2);
    float* x2f  = (float*)alloc((size_t)TT*DD*4);
    int*   cnt  = (int*)  alloc(256);
    int*   lst  = (int*)  alloc((size_t)EE*CAP*4);
    float* wts  = (float*)alloc((size_t)EE*CAP*4);
    u16*   hE   = (u16*)  alloc((size_t)EE*CAP*II*2);
    u16*   rbuf = (u16*)  alloc((size_t)TT*NTOP*DD*2);
    // Aliases (lifetimes disjoint):
    u16*   hs   = x1h;            // [TT][ISS] bf16 = 8MB, x1h dead after QKV
    float* ybuf = qkvf;           // [TT][DD] f32 = 16MB, qkvf dead after splits

    // ---- Weight prep (transpose + bf16 convert [+ split]) ----
    k_prep<true ><<<dim3(64,64,1), 256, 0, stream>>>(Wq, WqkvTh, WqkvTl, 2048, 2048);
    k_prep<true ><<<dim3(16,64,1), 256, 0, stream>>>(Wk, WqkvTh + (size_t)2048*2048, WqkvTl + (size_t)2048*2048, 2048, 512);
    k_prep<true ><<<dim3(16,64,1), 256, 0, stream>>>(Wv, WqkvTh + (size_t)2560*2048, WqkvTl + (size_t)2560*2048, 2048, 512);
    k_prep<true ><<<dim3(64,64,1), 256, 0, stream>>>(Wo, WoTh, WoTl, 2048, 2048);
    k_prep<false><<<dim3(64,64,1), 256, 0, stream>>>(Wgs, WgsT, nullptr, 2048, 2048);
    k_prep<false><<<dim3(64,64,1), 256, 0, stream>>>(Wus, WusT, nullptr, 2048, 2048);
    k_prep<false><<<dim3(64,64,1), 256, 0, stream>>>(Wds, WdsT, nullptr, 2048, 2048);
    k_prep<false><<<dim3(32,64,EE), 256, 0, stream>>>(Wg, WgT, nullptr, 2048, 1024);
    k_prep<false><<<dim3(32,64,EE), 256, 0, stream>>>(Wu, WuT, nullptr, 2048, 1024);
    k_prep<false><<<dim3(64,32,EE), 256, 0, stream>>>(Wd, WdT, nullptr, 1024, 2048);

    // ---- Attention path (split-bf16 high precision) ----
    k_rmsnorm_split<<<TT, 256, 0, stream>>>(hidden, ln1, x1h, x1l);
    k_gemm_hi<2><<<dim3(24,16), 256, 0, stream>>>(x1h, x1l, WqkvTh, WqkvTl, qkvf, nullptr, TT, 3072, DD);
    k_rope_split<<<(TT*20*64)/256, 256, 0, stream>>>(qkvf, cosb, sinb, qh, ql, kh, kl);
    k_split_vt<<<(TT*HKK*HDD/8)/256, 256, 0, stream>>>(qkvf, vth, vtl);
    k_attn_hi<<<dim3(SS/64, BB*HH), 256, 0, stream>>>(qh, ql, kh, kl, vth, vtl, aoh, aol);
    k_gemm_hi<1><<<dim3(16,16), 256, 0, stream>>>(aoh, aol, WoTh, WoTl, h2, hidden, TT, DD, HH*HDD);

    // ---- MoE path ----
    k_rmsnorm_bf<<<TT, 256, 0, stream>>>(h2, ln2, x2, x2f);
    (void)hipMemsetAsync(cnt, 0, 256, stream);
    k_router<<<TT, 256, 0, stream>>>(x2f, Wgate, cbias, cnt, lst, wts);
    k_glu<false><<<dim3(ISS/128, TT/128, 1), 256, 0, stream>>>(x2, WgsT, WusT, hs, nullptr, nullptr, TT, ISS, DD);
    k_gemm<2><<<dim3(DD/128, TT/128), 256, 0, stream>>>(hs, WdsT, ybuf, TT, DD, ISS);
    k_glu<true><<<dim3(II/128, CAP/128, EE), 256, 0, stream>>>(x2, WgT, WuT, hE, lst, cnt, CAP, II, DD);
    k_down_scatter<<<dim3(DD/128, CAP/128, EE), 256, 0, stream>>>(hE, WdT, rbuf, lst, wts, cnt, DD, II);
    k_final<<<(TT*DD/4)/256, 256, 0, stream>>>(h2, ybuf, rbuf, out);
}

// Round 10
// 1179.723 us; speedup vs baseline: 1.2642x; 1.1050x over previous
//
#include <hip/hip_runtime.h>
#include <cstdint>

typedef unsigned short u16;
typedef __attribute__((ext_vector_type(8))) short short8;
typedef __attribute__((ext_vector_type(4))) short s16x4;
typedef __attribute__((ext_vector_type(4))) float f32x4;

#define MFMA_16x16x32(a,b,c) __builtin_amdgcn_mfma_f32_16x16x32_bf16(a,b,c,0,0,0)

// async global->LDS, 16B per lane, wave covers 1024B (16 rows of a [*][32] bf16 tile)
#define GLDS16(lds, g) __builtin_amdgcn_global_load_lds( \
    (const __attribute__((address_space(1))) unsigned int*)(g), \
    (__attribute__((address_space(3))) unsigned int*)(lds), 16, 0, 0)

#define BB 2
#define SS 1024
#define DD 2048
#define HH 16
#define HKK 4
#define HDD 128
#define EE 16
#define NTOP 6
#define II 1024
#define ISS 2048
#define TT 2048
#define CAP 2048

__device__ __forceinline__ u16 f2b(float f) {
    union { float f; uint32_t u; } v; v.f = f;
    uint32_t r = v.u + 0x7FFFu + ((v.u >> 16) & 1u);
    return (u16)(r >> 16);
}
__device__ __forceinline__ float b2f(u16 h) {
    union { uint32_t u; float f; } v; v.u = ((uint32_t)h) << 16;
    return v.f;
}
__device__ __forceinline__ void fsplit(float f, u16& hi, u16& lo) {
    u16 h = f2b(f);
    hi = h;
    lo = f2b(f - b2f(h));
}

// ---------- Prep: transpose+convert W f32 [R][C] -> bf16 [C][R] (hi[,lo]) ---
template<bool SPLIT>
__global__ __launch_bounds__(256) void k_prep(
    const float* __restrict__ In, u16* __restrict__ Oh, u16* __restrict__ Ol,
    int R, int C)
{
    const size_t zoff = (size_t)blockIdx.z * R * C;
    In += zoff; Oh += zoff; if (SPLIT) Ol += zoff;
    const int r0 = blockIdx.y * 32, c0 = blockIdx.x * 32;
    __shared__ float tile[32][33];
    const int tx = threadIdx.x & 31, ty = threadIdx.x >> 5;
    #pragma unroll
    for (int i = 0; i < 4; ++i)
        tile[ty + i*8][tx] = In[(size_t)(r0 + ty + i*8)*C + c0 + tx];
    __syncthreads();
    const int c = threadIdx.x >> 3, rs = (threadIdx.x & 7) * 4;
    s16x4 hv, lv;
    #pragma unroll
    for (int j = 0; j < 4; ++j) {
        float f = tile[rs + j][c];
        u16 hb = f2b(f);
        hv[j] = (short)hb;
        if (SPLIT) lv[j] = (short)f2b(f - b2f(hb));
        else lv[j] = 0;
    }
    *(s16x4*)(Oh + (size_t)(c0 + c)*R + r0 + rs) = hv;
    if (SPLIT) *(s16x4*)(Ol + (size_t)(c0 + c)*R + r0 + rs) = lv;
}

// ---------------- RMSNorm f32 in -> split bf16 (hi,lo) ----------------------
__global__ __launch_bounds__(256) void k_rmsnorm_split(
    const float* __restrict__ X, const float* __restrict__ Wt,
    u16* __restrict__ Oh, u16* __restrict__ Ol)
{
    const int t = blockIdx.x;
    const float* x = X + (size_t)t * DD;
    const int base = threadIdx.x * 8;
    f32x4 v0 = *(const f32x4*)(x + base);
    f32x4 v1 = *(const f32x4*)(x + base + 4);
    float ss = 0.f;
    #pragma unroll
    for (int j = 0; j < 4; ++j) ss += v0[j]*v0[j] + v1[j]*v1[j];
    #pragma unroll
    for (int o = 1; o < 64; o <<= 1) ss += __shfl_xor(ss, o);
    __shared__ float red[4];
    if ((threadIdx.x & 63) == 0) red[threadIdx.x >> 6] = ss;
    __syncthreads();
    float tot = red[0] + red[1] + red[2] + red[3];
    float inv = rsqrtf(tot * (1.0f/DD) + 1e-6f);
    f32x4 w0 = *(const f32x4*)(Wt + base);
    f32x4 w1 = *(const f32x4*)(Wt + base + 4);
    u16* oh = Oh + (size_t)t*DD + base;
    u16* ol = Ol + (size_t)t*DD + base;
    #pragma unroll
    for (int j = 0; j < 4; ++j) {
        float y0 = v0[j]*inv*w0[j];
        float y1 = v1[j]*inv*w1[j];
        fsplit(y0, oh[j],   ol[j]);
        fsplit(y1, oh[4+j], ol[4+j]);
    }
}

// ---------------- RMSNorm f32 in -> bf16 + f32 ------------------------------
__global__ __launch_bounds__(256) void k_rmsnorm_bf(
    const float* __restrict__ X, const float* __restrict__ Wt,
    u16* __restrict__ Ob, float* __restrict__ Of)
{
    const int t = blockIdx.x;
    const float* x = X + (size_t)t * DD;
    const int base = threadIdx.x * 8;
    f32x4 v0 = *(const f32x4*)(x + base);
    f32x4 v1 = *(const f32x4*)(x + base + 4);
    float ss = 0.f;
    #pragma unroll
    for (int j = 0; j < 4; ++j) ss += v0[j]*v0[j] + v1[j]*v1[j];
    #pragma unroll
    for (int o = 1; o < 64; o <<= 1) ss += __shfl_xor(ss, o);
    __shared__ float red[4];
    if ((threadIdx.x & 63) == 0) red[threadIdx.x >> 6] = ss;
    __syncthreads();
    float tot = red[0] + red[1] + red[2] + red[3];
    float inv = rsqrtf(tot * (1.0f/DD) + 1e-6f);
    f32x4 w0 = *(const f32x4*)(Wt + base);
    f32x4 w1 = *(const f32x4*)(Wt + base + 4);
    u16* ob = Ob + (size_t)t*DD + base;
    float* of = Of + (size_t)t*DD + base;
    #pragma unroll
    for (int j = 0; j < 4; ++j) {
        float y0 = v0[j]*inv*w0[j];
        float y1 = v1[j]*inv*w1[j];
        ob[j] = f2b(y0); ob[4+j] = f2b(y1);
        of[j] = y0;      of[4+j] = y1;
    }
}

// ------- High-precision GEMM: C = (Ah+Al) @ (Bh+Bl)^T, pre-split bf16 -------
// 2-phase prefetch, dbuf LDS. EPI 1: f32 + residual; 2: f32
template<int EPI>
__global__ __launch_bounds__(256) void k_gemm_hi(
    const u16* __restrict__ Ah, const u16* __restrict__ Al,
    const u16* __restrict__ Bth, const u16* __restrict__ Btl,
    float* __restrict__ C, const float* __restrict__ Res,
    int M, int N, int K)
{
    __shared__ u16 Ash[2][128][32];
    __shared__ u16 Asl[2][128][32];
    __shared__ u16 Bsh[2][128][32];
    __shared__ u16 Bsl[2][128][32];
    const int tid = threadIdx.x;
    const int lane = tid & 63;
    const int w = tid >> 6;
    const int m0 = blockIdx.y * 128, n0 = blockIdx.x * 128;
    const int wm = (w >> 1) * 64, wn = (w & 1) * 64;
    const int l15 = lane & 15, lhi = lane >> 4;
    f32x4 acc[4][4];
    #pragma unroll
    for (int a = 0; a < 4; ++a)
        #pragma unroll
        for (int b = 0; b < 4; ++b) acc[a][b] = 0;

    const int gr = w*32 + (lane >> 2);
    const int gc = (lane & 3) * 8;
    const u16* ahP0 = Ah  + (size_t)(m0 + gr) * K + gc;
    const u16* alP0 = Al  + (size_t)(m0 + gr) * K + gc;
    const u16* bhP0 = Bth + (size_t)(n0 + gr) * K + gc;
    const u16* blP0 = Btl + (size_t)(n0 + gr) * K + gc;
    const size_t r16 = (size_t)16 * K;

    GLDS16(&Ash[0][w*32][0],      ahP0);
    GLDS16(&Ash[0][w*32 + 16][0], ahP0 + r16);
    GLDS16(&Asl[0][w*32][0],      alP0);
    GLDS16(&Asl[0][w*32 + 16][0], alP0 + r16);
    GLDS16(&Bsh[0][w*32][0],      bhP0);
    GLDS16(&Bsh[0][w*32 + 16][0], bhP0 + r16);
    GLDS16(&Bsl[0][w*32][0],      blP0);
    GLDS16(&Bsl[0][w*32 + 16][0], blP0 + r16);
    __syncthreads();

    int cur = 0;
    for (int k0 = 0; k0 < K; k0 += 32) {
        const int nxt = k0 + 32;
        if (nxt < K) {
            GLDS16(&Ash[cur^1][w*32][0],      ahP0 + nxt);
            GLDS16(&Ash[cur^1][w*32 + 16][0], ahP0 + r16 + nxt);
            GLDS16(&Asl[cur^1][w*32][0],      alP0 + nxt);
            GLDS16(&Asl[cur^1][w*32 + 16][0], alP0 + r16 + nxt);
            GLDS16(&Bsh[cur^1][w*32][0],      bhP0 + nxt);
            GLDS16(&Bsh[cur^1][w*32 + 16][0], bhP0 + r16 + nxt);
            GLDS16(&Bsl[cur^1][w*32][0],      blP0 + nxt);
            GLDS16(&Bsl[cur^1][w*32 + 16][0], blP0 + r16 + nxt);
        }
        short8 afh[4], afl[4], bfh[4], bfl[4];
        #pragma unroll
        for (int i = 0; i < 4; ++i) {
            afh[i] = *(const short8*)&Ash[cur][wm + i*16 + l15][lhi*8];
            afl[i] = *(const short8*)&Asl[cur][wm + i*16 + l15][lhi*8];
            bfh[i] = *(const short8*)&Bsh[cur][wn + i*16 + l15][lhi*8];
            bfl[i] = *(const short8*)&Bsl[cur][wn + i*16 + l15][lhi*8];
        }
        #pragma unroll
        for (int a = 0; a < 4; ++a)
            #pragma unroll
            for (int b = 0; b < 4; ++b) {
                acc[a][b] = MFMA_16x16x32(afh[a], bfh[b], acc[a][b]);
                acc[a][b] = MFMA_16x16x32(afh[a], bfl[b], acc[a][b]);
                acc[a][b] = MFMA_16x16x32(afl[a], bfh[b], acc[a][b]);
            }
        __syncthreads();
        cur ^= 1;
    }
    #pragma unroll
    for (int a = 0; a < 4; ++a)
      #pragma unroll
      for (int b = 0; b < 4; ++b)
        #pragma unroll
        for (int r = 0; r < 4; ++r) {
            int m = m0 + wm + a*16 + lhi*4 + r;
            int n = n0 + wn + b*16 + l15;
            size_t off = (size_t)m * N + n;
            float v = acc[a][b][r];
            if (EPI == 1) C[off] = v + Res[off];
            else C[off] = v;
        }
}

// ---------------- Dense GEMM: C(MxN) = A_bf16 @ Bt_bf16^T, 2-phase ----------
// EPI 0: bf16 store; 2: f32 store
template<int EPI>
__global__ __launch_bounds__(256) void k_gemm(
    const u16* __restrict__ A, const u16* __restrict__ Bt,
    void* __restrict__ C, int M, int N, int K)
{
    __shared__ u16 As[2][128][32];
    __shared__ u16 Bs[2][128][32];
    const int tid = threadIdx.x;
    const int lane = tid & 63;
    const int w = tid >> 6;
    const int m0 = blockIdx.y * 128, n0 = blockIdx.x * 128;
    const int wm = (w >> 1) * 64, wn = (w & 1) * 64;
    const int l15 = lane & 15, lhi = lane >> 4;
    f32x4 acc[4][4];
    #pragma unroll
    for (int a = 0; a < 4; ++a)
        #pragma unroll
        for (int b = 0; b < 4; ++b) acc[a][b] = 0;

    const int gr = w*32 + (lane >> 2);
    const int gc = (lane & 3) * 8;
    const u16* aP0 = A  + (size_t)(m0 + gr) * K + gc;
    const u16* bP0 = Bt + (size_t)(n0 + gr) * K + gc;
    const size_t r16 = (size_t)16 * K;

    GLDS16(&As[0][w*32][0],      aP0);
    GLDS16(&As[0][w*32 + 16][0], aP0 + r16);
    GLDS16(&Bs[0][w*32][0],      bP0);
    GLDS16(&Bs[0][w*32 + 16][0], bP0 + r16);
    __syncthreads();

    int cur = 0;
    for (int k0 = 0; k0 < K; k0 += 32) {
        const int nxt = k0 + 32;
        if (nxt < K) {
            GLDS16(&As[cur^1][w*32][0],      aP0 + nxt);
            GLDS16(&As[cur^1][w*32 + 16][0], aP0 + r16 + nxt);
            GLDS16(&Bs[cur^1][w*32][0],      bP0 + nxt);
            GLDS16(&Bs[cur^1][w*32 + 16][0], bP0 + r16 + nxt);
        }
        short8 af[4], bf[4];
        #pragma unroll
        for (int i = 0; i < 4; ++i) af[i] = *(const short8*)&As[cur][wm + i*16 + l15][lhi*8];
        #pragma unroll
        for (int i = 0; i < 4; ++i) bf[i] = *(const short8*)&Bs[cur][wn + i*16 + l15][lhi*8];
        #pragma unroll
        for (int a = 0; a < 4; ++a)
            #pragma unroll
            for (int b = 0; b < 4; ++b)
                acc[a][b] = MFMA_16x16x32(af[a], bf[b], acc[a][b]);
        __syncthreads();
        cur ^= 1;
    }
    #pragma unroll
    for (int a = 0; a < 4; ++a)
      #pragma unroll
      for (int b = 0; b < 4; ++b)
        #pragma unroll
        for (int r = 0; r < 4; ++r) {
            int m = m0 + wm + a*16 + lhi*4 + r;
            int n = n0 + wn + b*16 + l15;
            size_t off = (size_t)m * N + n;
            float v = acc[a][b][r];
            if (EPI == 0) ((u16*)C)[off] = f2b(v);
            else ((float*)C)[off] = v;
        }
}

// ------- Fused GLU GEMM: tile 256M x 64N(dual), per-wave 128x(32+32) --------
// acc 8x2+8x2 = 128 regs; __launch_bounds__(256,2) pins 2 waves/SIMD.
template<bool GATHER>
__global__ __launch_bounds__(256, 2) void k_glu(
    const u16* __restrict__ Xb, const u16* __restrict__ W1t,
    const u16* __restrict__ W2t, u16* __restrict__ Hout,
    const int* __restrict__ list, const int* __restrict__ cntp,
    int M, int NE, int K)
{
    const int e = GATHER ? blockIdx.z : 0;
    const int cnt = GATHER ? cntp[e] : M;
    const int m0 = blockIdx.y * 256;
    if (m0 >= cnt) return;
    const int n0 = blockIdx.x * 64;
    const u16* w1 = W1t + (size_t)e * NE * K;
    const u16* w2 = W2t + (size_t)e * NE * K;
    u16* hout = Hout + (size_t)e * CAP * NE;
    const int* lst = GATHER ? (list + e * CAP) : nullptr;

    __shared__ u16 As[2][256][32];
    __shared__ u16 B1s[2][64][32];
    __shared__ u16 B2s[2][64][32];

    const int tid = threadIdx.x, lane = tid & 63, w = tid >> 6;
    const int wm = (w >> 1) * 128, wn = (w & 1) * 32;
    const int l15 = lane & 15, lhi = lane >> 4;
    f32x4 acc1[8][2], acc2[8][2];
    #pragma unroll
    for (int a = 0; a < 8; ++a)
        #pragma unroll
        for (int j = 0; j < 2; ++j) { acc1[a][j] = 0; acc2[a][j] = 0; }

    const int gr = lane >> 2;          // 0..15
    const int gc = (lane & 3) * 8;
    const u16* aP[4];
    #pragma unroll
    for (int j = 0; j < 4; ++j) {
        int mr = m0 + w*64 + j*16 + gr;
        int arow;
        if (GATHER) arow = (mr < cnt) ? (lst[mr] >> 3) : 0;
        else arow = mr;
        aP[j] = Xb + (size_t)arow * K + gc;
    }
    const u16* b1P = w1 + (size_t)(n0 + w*16 + gr) * K + gc;
    const u16* b2P = w2 + (size_t)(n0 + w*16 + gr) * K + gc;

    auto stage = [&](int bf, int kk) {
        #pragma unroll
        for (int j = 0; j < 4; ++j)
            GLDS16(&As[bf][w*64 + j*16][0], aP[j] + kk);
        GLDS16(&B1s[bf][w*16][0], b1P + kk);
        GLDS16(&B2s[bf][w*16][0], b2P + kk);
    };

    stage(0, 0);
    __syncthreads();
    int cur = 0;
    for (int k0 = 0; k0 < K; k0 += 32) {
        const int nxt = k0 + 32;
        if (nxt < K) stage(cur ^ 1, nxt);
        short8 af[8], b1[2], b2[2];
        #pragma unroll
        for (int i = 0; i < 8; ++i) af[i] = *(const short8*)&As[cur][wm + i*16 + l15][lhi*8];
        #pragma unroll
        for (int j = 0; j < 2; ++j) {
            b1[j] = *(const short8*)&B1s[cur][wn + j*16 + l15][lhi*8];
            b2[j] = *(const short8*)&B2s[cur][wn + j*16 + l15][lhi*8];
        }
        #pragma unroll
        for (int a = 0; a < 8; ++a)
            #pragma unroll
            for (int j = 0; j < 2; ++j) {
                acc1[a][j] = MFMA_16x16x32(af[a], b1[j], acc1[a][j]);
                acc2[a][j] = MFMA_16x16x32(af[a], b2[j], acc2[a][j]);
            }
        __syncthreads();
        cur ^= 1;
    }
    #pragma unroll
    for (int a = 0; a < 8; ++a)
      #pragma unroll
      for (int j = 0; j < 2; ++j)
        #pragma unroll
        for (int r = 0; r < 4; ++r) {
            int m = m0 + wm + a*16 + lhi*4 + r;
            if (m < cnt) {
                int n = n0 + wn + j*16 + l15;
                float g = acc1[a][j][r], u = acc2[a][j][r];
                float hval = g / (1.0f + __expf(-g)) * u;
                hout[(size_t)m * NE + n] = f2b(hval);
            }
        }
}

// ------- Routed down GEMM: tile 256x128, per-wave 128x64 (8x4), scatter -----
__global__ __launch_bounds__(256, 2) void k_down_scatter(
    const u16* __restrict__ Hb, const u16* __restrict__ WdTt,
    u16* __restrict__ Rbuf, const int* __restrict__ list,
    const float* __restrict__ wts, const int* __restrict__ cntp,
    int N, int K)
{
    const int e = blockIdx.z;
    const int cnt = cntp[e];
    const int m0 = blockIdx.y * 256;
    if (m0 >= cnt) return;
    const int n0 = blockIdx.x * 128;
    const u16* A  = Hb   + (size_t)e * CAP * K;
    const u16* Bt = WdTt + (size_t)e * N * K;

    __shared__ u16 As[2][256][32];
    __shared__ u16 Bs[2][128][32];
    const int tid = threadIdx.x, lane = tid & 63, w = tid >> 6;
    const int wm = (w >> 1) * 128, wn = (w & 1) * 64;
    const int l15 = lane & 15, lhi = lane >> 4;
    f32x4 acc[8][4];
    #pragma unroll
    for (int a = 0; a < 8; ++a)
        #pragma unroll
        for (int b = 0; b < 4; ++b) acc[a][b] = 0;

    const int gr = lane >> 2;
    const int gc = (lane & 3) * 8;
    const u16* aP = A  + (size_t)(m0 + w*64 + gr) * K + gc;
    const u16* bP = Bt + (size_t)(n0 + w*32 + gr) * K + gc;
    const size_t r16 = (size_t)16 * K;

    auto stage = [&](int bf, int kk) {
        GLDS16(&As[bf][w*64][0],      aP + kk);
        GLDS16(&As[bf][w*64 + 16][0], aP + r16 + kk);
        GLDS16(&As[bf][w*64 + 32][0], aP + 2*r16 + kk);
        GLDS16(&As[bf][w*64 + 48][0], aP + 3*r16 + kk);
        GLDS16(&Bs[bf][w*32][0],      bP + kk);
        GLDS16(&Bs[bf][w*32 + 16][0], bP + r16 + kk);
    };

    stage(0, 0);
    __syncthreads();
    int cur = 0;
    for (int k0 = 0; k0 < K; k0 += 32) {
        const int nxt = k0 + 32;
        if (nxt < K) stage(cur ^ 1, nxt);
        short8 af[8], bf4[4];
        #pragma unroll
        for (int i = 0; i < 8; ++i) af[i] = *(const short8*)&As[cur][wm + i*16 + l15][lhi*8];
        #pragma unroll
        for (int i = 0; i < 4; ++i) bf4[i] = *(const short8*)&Bs[cur][wn + i*16 + l15][lhi*8];
        #pragma unroll
        for (int a = 0; a < 8; ++a)
            #pragma unroll
            for (int b = 0; b < 4; ++b)
                acc[a][b] = MFMA_16x16x32(af[a], bf4[b], acc[a][b]);
        __syncthreads();
        cur ^= 1;
    }
    #pragma unroll
    for (int a = 0; a < 8; ++a)
      #pragma unroll
      for (int b = 0; b < 4; ++b)
        #pragma unroll
        for (int r = 0; r < 4; ++r) {
            int m = m0 + wm + a*16 + lhi*4 + r;
            if (m < cnt) {
                int n = n0 + wn + b*16 + l15;
                int enc = list[e*CAP + m];
                float wgt = wts[e*CAP + m];
                int tok = enc >> 3, kk = enc & 7;
                Rbuf[((size_t)tok*NTOP + kk)*N + n] = f2b(acc[a][b][r] * wgt);
            }
        }
}

// -------- Fused RoPE+split (q,k) AND V^T split, single launch ---------------
__global__ __launch_bounds__(256) void k_rope_vt(
    const float* __restrict__ QKV,
    const float* __restrict__ Cs, const float* __restrict__ Sn,
    u16* __restrict__ Qh, u16* __restrict__ Ql,
    u16* __restrict__ Kh, u16* __restrict__ Kl,
    u16* __restrict__ Vth, u16* __restrict__ Vtl)
{
    int id = blockIdx.x * 256 + threadIdx.x;
    if (id < TT*20*64) {
        int pr = id & 63;
        int rest = id >> 6;
        int hh = rest % 20;
        int tok = rest / 20;
        int d0 = pr * 2;
        float c0 = Cs[(size_t)tok*HDD + d0];
        float c1 = Cs[(size_t)tok*HDD + d0 + 1];
        float s0 = Sn[(size_t)tok*HDD + d0];
        float s1 = Sn[(size_t)tok*HDD + d0 + 1];
        const float* p = QKV + (size_t)tok*3072 + (hh < HH ? hh*HDD : 2048 + (hh - HH)*HDD);
        float x0 = p[d0], x1 = p[d0+1];
        float y0 = x0*c0 - x1*s0;
        float y1 = x1*c1 + x0*s1;
        u16 *oh, *ol;
        size_t ooff;
        if (hh < HH) { ooff = ((size_t)tok*HH + hh)*HDD + d0; oh = Qh; ol = Ql; }
        else         { ooff = ((size_t)tok*HKK + (hh - HH))*HDD + d0; oh = Kh; ol = Kl; }
        fsplit(y0, oh[ooff],     ol[ooff]);
        fsplit(y1, oh[ooff + 1], ol[ooff + 1]);
    } else {
        int vid = id - TT*20*64;       // 0 .. TT*HKK*HDD/8 - 1
        int oid = vid * 8;
        int s0 = oid & (SS - 1);
        int r = oid >> 10;
        int d = r & (HDD - 1);
        int bh = r >> 7;
        int b = bh >> 2, hk = bh & 3;
        #pragma unroll
        for (int j = 0; j < 8; ++j) {
            int s = s0 + j;
            float v = QKV[(size_t)(b*SS + s)*3072 + 2560 + hk*HDD + d];
            fsplit(v, Vth[oid + j], Vtl[oid + j]);
        }
    }
}

// ---------------- Flash attention, split-bf16 precision ---------------------
__global__ __launch_bounds__(256) void k_attn_hi(
    const u16* __restrict__ Qh, const u16* __restrict__ Ql,
    const u16* __restrict__ Kh, const u16* __restrict__ Kl,
    const u16* __restrict__ Vth, const u16* __restrict__ Vtl,
    u16* __restrict__ Oh, u16* __restrict__ Ol)
{
    const int tid = threadIdx.x;
    const int lane = tid & 63;
    const int w = tid >> 6;
    const int q0 = blockIdx.x * 64;
    const int b = blockIdx.y >> 4;
    const int h = blockIdx.y & 15;
    const int hk = h >> 2;
    const int l15 = lane & 15, lhi = lane >> 4;

    __shared__ u16 Ksh[32][136];
    __shared__ u16 Ksl[32][136];
    __shared__ u16 Vsh[128][40];
    __shared__ u16 Vsl[128][40];
    __shared__ u16 Psh[4][16][40];
    __shared__ u16 Psl[4][16][40];

    short8 qfh[4], qfl[4];
    {
        const int qrow = q0 + w*16 + l15;
        const u16* qph = Qh + ((size_t)(b*SS + qrow)*HH + h)*HDD;
        const u16* qpl = Ql + ((size_t)(b*SS + qrow)*HH + h)*HDD;
        #pragma unroll
        for (int c = 0; c < 4; ++c) {
            qfh[c] = *(const short8*)(qph + c*32 + lhi*8);
            qfl[c] = *(const short8*)(qpl + c*32 + lhi*8);
        }
    }

    f32x4 oacc[8];
    #pragma unroll
    for (int ch = 0; ch < 8; ++ch) oacc[ch] = 0;
    float m_r[4] = {-1e30f, -1e30f, -1e30f, -1e30f};
    float l_r[4] = {0.f, 0.f, 0.f, 0.f};

    const int nkt = (q0 + 64) >> 5;
    const int kr = tid >> 3, kc = (tid & 7) * 16;
    const int vd = tid >> 1, vj = (tid & 1) * 16;

    for (int kt = 0; kt < nkt; ++kt) {
        __syncthreads();
        {
            size_t koff = ((size_t)(b*SS + kt*32 + kr)*HKK + hk)*HDD + kc;
            *(short8*)&Ksh[kr][kc]     = *(const short8*)(Kh + koff);
            *(short8*)&Ksh[kr][kc + 8] = *(const short8*)(Kh + koff + 8);
            *(short8*)&Ksl[kr][kc]     = *(const short8*)(Kl + koff);
            *(short8*)&Ksl[kr][kc + 8] = *(const short8*)(Kl + koff + 8);
        }
        {
            size_t voff = ((size_t)(b*HKK + hk)*HDD + vd)*SS + kt*32 + vj;
            *(short8*)&Vsh[vd][vj]     = *(const short8*)(Vth + voff);
            *(short8*)&Vsh[vd][vj + 8] = *(const short8*)(Vth + voff + 8);
            *(short8*)&Vsl[vd][vj]     = *(const short8*)(Vtl + voff);
            *(short8*)&Vsl[vd][vj + 8] = *(const short8*)(Vtl + voff + 8);
        }
        __syncthreads();

        f32x4 s0 = 0, s1 = 0;
        #pragma unroll
        for (int c = 0; c < 4; ++c) {
            short8 kh0 = *(const short8*)&Ksh[l15][c*32 + lhi*8];
            short8 kl0 = *(const short8*)&Ksl[l15][c*32 + lhi*8];
            short8 kh1 = *(const short8*)&Ksh[16 + l15][c*32 + lhi*8];
            short8 kl1 = *(const short8*)&Ksl[16 + l15][c*32 + lhi*8];
            s0 = MFMA_16x16x32(qfh[c], kh0, s0);
            s0 = MFMA_16x16x32(qfh[c], kl0, s0);
            s0 = MFMA_16x16x32(qfl[c], kh0, s0);
            s1 = MFMA_16x16x32(qfh[c], kh1, s1);
            s1 = MFMA_16x16x32(qfh[c], kl1, s1);
            s1 = MFMA_16x16x32(qfl[c], kh1, s1);
        }
        const int irow0 = q0 + w*16 + lhi*4;
        const int j0 = kt*32 + l15;
        float ef[4];
        #pragma unroll
        for (int r = 0; r < 4; ++r) {
            float a0 = s0[r] * 0.08838834764831845f;
            float a1 = s1[r] * 0.08838834764831845f;
            const int ir = irow0 + r;
            if (j0 > ir) a0 = -1e30f;
            if (j0 + 16 > ir) a1 = -1e30f;
            float mx = fmaxf(a0, a1);
            #pragma unroll
            for (int o = 1; o < 16; o <<= 1) mx = fmaxf(mx, __shfl_xor(mx, o));
            float mn = fmaxf(m_r[r], mx);
            ef[r] = __expf(m_r[r] - mn);
            m_r[r] = mn;
            float p0 = __expf(a0 - mn);
            float p1 = __expf(a1 - mn);
            float ps = p0 + p1;
            #pragma unroll
            for (int o = 1; o < 16; o <<= 1) ps += __shfl_xor(ps, o);
            l_r[r] = l_r[r]*ef[r] + ps;
            fsplit(p0, Psh[w][lhi*4 + r][l15],      Psl[w][lhi*4 + r][l15]);
            fsplit(p1, Psh[w][lhi*4 + r][16 + l15], Psl[w][lhi*4 + r][16 + l15]);
        }
        #pragma unroll
        for (int ch = 0; ch < 8; ++ch) {
            f32x4 t = oacc[ch];
            t[0] *= ef[0]; t[1] *= ef[1]; t[2] *= ef[2]; t[3] *= ef[3];
            oacc[ch] = t;
        }
        __syncthreads();
        short8 pah = *(const short8*)&Psh[w][l15][lhi*8];
        short8 pal = *(const short8*)&Psl[w][l15][lhi*8];
        #pragma unroll
        for (int ch = 0; ch < 8; ++ch) {
            short8 bvh = *(const short8*)&Vsh[ch*16 + l15][lhi*8];
            short8 bvl = *(const short8*)&Vsl[ch*16 + l15][lhi*8];
            oacc[ch] = MFMA_16x16x32(pah, bvh, oacc[ch]);
            oacc[ch] = MFMA_16x16x32(pah, bvl, oacc[ch]);
            oacc[ch] = MFMA_16x16x32(pal, bvh, oacc[ch]);
        }
    }
    #pragma unroll
    for (int r = 0; r < 4; ++r) {
        const int row = q0 + w*16 + lhi*4 + r;
        const float inv = 1.0f / l_r[r];
        u16* oph = Oh + ((size_t)(b*SS + row)*HH + h)*HDD;
        u16* opl = Ol + ((size_t)(b*SS + row)*HH + h)*HDD;
        #pragma unroll
        for (int ch = 0; ch < 8; ++ch) {
            float o = oacc[ch][r] * inv;
            fsplit(o, oph[ch*16 + l15], opl[ch*16 + l15]);
        }
    }
}

// ---------------- Router: f32 logits, softmax, top-6, slot lists ------------
__global__ __launch_bounds__(256) void k_router(
    const float* __restrict__ X, const float* __restrict__ Wg,
    const float* __restrict__ bias,
    int* __restrict__ cnt, int* __restrict__ list, float* __restrict__ wts)
{
    const int t = blockIdx.x;
    const int e = threadIdx.x & 15, sl = threadIdx.x >> 4;
    const float* x = X + (size_t)t * DD;
    float part = 0.f;
    for (int i = 0; i < 128; ++i) {
        int k = sl * 128 + i;
        part += x[k] * Wg[(size_t)k * EE + e];
    }
    __shared__ float red[16][17];
    red[sl][e] = part;
    __syncthreads();
    if (threadIdx.x == 0) {
        float lg[16], pr[16];
        for (int ee = 0; ee < 16; ++ee) {
            float s = 0.f;
            for (int q = 0; q < 16; ++q) s += red[q][ee];
            lg[ee] = s;
        }
        float mx = lg[0];
        for (int ee = 1; ee < 16; ++ee) mx = fmaxf(mx, lg[ee]);
        float sum = 0.f;
        for (int ee = 0; ee < 16; ++ee) { pr[ee] = expf(lg[ee] - mx); sum += pr[ee]; }
        float isum = 1.0f / sum;
        for (int ee = 0; ee < 16; ++ee) pr[ee] *= isum;
        unsigned used = 0;
        int sel[NTOP]; float rw[NTOP]; float s6 = 0.f;
        for (int kk = 0; kk < NTOP; ++kk) {
            int best = 0; float bv = -1e30f;
            for (int ee = 0; ee < 16; ++ee) {
                if (used & (1u << ee)) continue;
                float sc = pr[ee] + bias[ee];
                if (sc > bv) { bv = sc; best = ee; }
            }
            used |= 1u << best;
            sel[kk] = best; rw[kk] = pr[best]; s6 += pr[best];
        }
        float inv6 = 1.0f / fmaxf(s6, 1e-12f);
        for (int kk = 0; kk < NTOP; ++kk) {
            int ee = sel[kk];
            int pos = atomicAdd(&cnt[ee], 1);
            list[ee*CAP + pos] = (t << 3) | kk;
            wts[ee*CAP + pos] = rw[kk] * inv6;
        }
    }
}

// ---------------- Final: out = h2 + shared + sum_kk routed ------------------
__global__ __launch_bounds__(256) void k_final(
    const float* __restrict__ h2, const float* __restrict__ yb,
    const u16* __restrict__ rb, float* __restrict__ out)
{
    int id = blockIdx.x * 256 + threadIdx.x;     // T*D/4
    size_t i4 = (size_t)id * 4;
    int t = id >> 9;
    int d = (id & 511) * 4;
    f32x4 acc = *(const f32x4*)(h2 + i4);
    f32x4 y = *(const f32x4*)(yb + i4);
    acc += y;
    #pragma unroll
    for (int kk = 0; kk < NTOP; ++kk) {
        s16x4 rv = *(const s16x4*)(rb + ((size_t)t*NTOP + kk)*DD + d);
        acc[0] += b2f((u16)rv[0]); acc[1] += b2f((u16)rv[1]);
        acc[2] += b2f((u16)rv[2]); acc[3] += b2f((u16)rv[3]);
    }
    *(f32x4*)(out + i4) = acc;
}

extern "C" void kernel_launch(void* const* d_in, const int* in_sizes, int n_in,
                              void* d_out, int out_size, void* d_ws, size_t ws_size,
                              hipStream_t stream)
{
    (void)in_sizes; (void)n_in; (void)out_size; (void)ws_size;
    const float* hidden = (const float*)d_in[0];
    const float* cosb   = (const float*)d_in[1];
    const float* sinb   = (const float*)d_in[2];
    const float* ln1    = (const float*)d_in[3];
    const float* ln2    = (const float*)d_in[4];
    const float* Wq     = (const float*)d_in[5];
    const float* Wk     = (const float*)d_in[6];
    const float* Wv     = (const float*)d_in[7];
    const float* Wo     = (const float*)d_in[8];
    const float* Wgate  = (const float*)d_in[9];
    const float* cbias  = (const float*)d_in[10];
    const float* Wg     = (const float*)d_in[11];
    const float* Wu     = (const float*)d_in[12];
    const float* Wd     = (const float*)d_in[13];
    const float* Wgs    = (const float*)d_in[14];
    const float* Wus    = (const float*)d_in[15];
    const float* Wds    = (const float*)d_in[16];
    float* out = (float*)d_out;

    char* ws = (char*)d_ws;
    size_t off = 0;
    auto alloc = [&](size_t bytes) {
        void* p = ws + off;
        off = (off + bytes + 255) & ~(size_t)255;
        return p;
    };
    // Pre-transposed bf16 weights
    u16* WqkvTh = (u16*)alloc((size_t)3072*2048*2);
    u16* WqkvTl = (u16*)alloc((size_t)3072*2048*2);
    u16* WoTh   = (u16*)alloc((size_t)2048*2048*2);
    u16* WoTl   = (u16*)alloc((size_t)2048*2048*2);
    u16* WgsT   = (u16*)alloc((size_t)2048*2048*2);
    u16* WusT   = (u16*)alloc((size_t)2048*2048*2);
    u16* WdsT   = (u16*)alloc((size_t)2048*2048*2);
    u16* WgT    = (u16*)alloc((size_t)EE*II*DD*2);
    u16* WuT    = (u16*)alloc((size_t)EE*II*DD*2);
    u16* WdT    = (u16*)alloc((size_t)EE*DD*II*2);
    // Activations
    u16*   x1h  = (u16*)  alloc((size_t)TT*DD*2);
    u16*   x1l  = (u16*)  alloc((size_t)TT*DD*2);
    float* qkvf = (float*)alloc((size_t)TT*3072*4);
    u16*   qh   = (u16*)  alloc((size_t)TT*HH*HDD*2);
    u16*   ql   = (u16*)  alloc((size_t)TT*HH*HDD*2);
    u16*   kh   = (u16*)  alloc((size_t)TT*HKK*HDD*2);
    u16*   kl   = (u16*)  alloc((size_t)TT*HKK*HDD*2);
    u16*   vth  = (u16*)  alloc((size_t)TT*HKK*HDD*2);
    u16*   vtl  = (u16*)  alloc((size_t)TT*HKK*HDD*2);
    u16*   aoh  = (u16*)  alloc((size_t)TT*HH*HDD*2);
    u16*   aol  = (u16*)  alloc((size_t)TT*HH*HDD*2);
    float* h2   = (float*)alloc((size_t)TT*DD*4);
    u16*   x2   = (u16*)  alloc((size_t)TT*DD*2);
    float* x2f  = (float*)alloc((size_t)TT*DD*4);
    int*   cnt  = (int*)  alloc(256);
    int*   lst  = (int*)  alloc((size_t)EE*CAP*4);
    float* wts  = (float*)alloc((size_t)EE*CAP*4);
    u16*   hE   = (u16*)  alloc((size_t)EE*CAP*II*2);
    u16*   rbuf = (u16*)  alloc((size_t)TT*NTOP*DD*2);
    // Aliases (lifetimes disjoint):
    u16*   hs   = x1h;            // [TT][ISS] bf16 = 8MB, x1h dead after QKV
    float* ybuf = qkvf;           // [TT][DD] f32 = 16MB, qkvf dead after splits

    // ---- Weight prep (transpose + bf16 convert [+ split]) ----
    k_prep<true ><<<dim3(64,64,1), 256, 0, stream>>>(Wq, WqkvTh, WqkvTl, 2048, 2048);
    k_prep<true ><<<dim3(16,64,1), 256, 0, stream>>>(Wk, WqkvTh + (size_t)2048*2048, WqkvTl + (size_t)2048*2048, 2048, 512);
    k_prep<true ><<<dim3(16,64,1), 256, 0, stream>>>(Wv, WqkvTh + (size_t)2560*2048, WqkvTl + (size_t)2560*2048, 2048, 512);
    k_prep<true ><<<dim3(64,64,1), 256, 0, stream>>>(Wo, WoTh, WoTl, 2048, 2048);
    k_prep<false><<<dim3(64,64,1), 256, 0, stream>>>(Wgs, WgsT, nullptr, 2048, 2048);
    k_prep<false><<<dim3(64,64,1), 256, 0, stream>>>(Wus, WusT, nullptr, 2048, 2048);
    k_prep<false><<<dim3(64,64,1), 256, 0, stream>>>(Wds, WdsT, nullptr, 2048, 2048);
    k_prep<false><<<dim3(32,64,EE), 256, 0, stream>>>(Wg, WgT, nullptr, 2048, 1024);
    k_prep<false><<<dim3(32,64,EE), 256, 0, stream>>>(Wu, WuT, nullptr, 2048, 1024);
    k_prep<false><<<dim3(64,32,EE), 256, 0, stream>>>(Wd, WdT, nullptr, 1024, 2048);

    // ---- Attention path (split-bf16 high precision) ----
    k_rmsnorm_split<<<TT, 256, 0, stream>>>(hidden, ln1, x1h, x1l);
    k_gemm_hi<2><<<dim3(24,16), 256, 0, stream>>>(x1h, x1l, WqkvTh, WqkvTl, qkvf, nullptr, TT, 3072, DD);
    k_rope_vt<<<(TT*20*64 + TT*HKK*HDD/8)/256, 256, 0, stream>>>(qkvf, cosb, sinb, qh, ql, kh, kl, vth, vtl);
    k_attn_hi<<<dim3(SS/64, BB*HH), 256, 0, stream>>>(qh, ql, kh, kl, vth, vtl, aoh, aol);
    k_gemm_hi<1><<<dim3(16,16), 256, 0, stream>>>(aoh, aol, WoTh, WoTl, h2, hidden, TT, DD, HH*HDD);

    // ---- MoE path ----
    k_rmsnorm_bf<<<TT, 256, 0, stream>>>(h2, ln2, x2, x2f);
    (void)hipMemsetAsync(cnt, 0, 256, stream);
    k_router<<<TT, 256, 0, stream>>>(x2f, Wgate, cbias, cnt, lst, wts);
    k_glu<false><<<dim3(ISS/64, TT/256, 1), 256, 0, stream>>>(x2, WgsT, WusT, hs, nullptr, nullptr, TT, ISS, DD);
    k_gemm<2><<<dim3(DD/128, TT/128), 256, 0, stream>>>(hs, WdsT, ybuf, TT, DD, ISS);
    k_glu<true><<<dim3(II/64, CAP/256, EE), 256, 0, stream>>>(x2, WgT, WuT, hE, lst, cnt, CAP, II, DD);
    k_down_scatter<<<dim3(DD/128, CAP/256, EE), 256, 0, stream>>>(hE, WdT, rbuf, lst, wts, cnt, DD, II);
    k_final<<<(TT*DD/4)/256, 256, 0, stream>>>(h2, ybuf, rbuf, out);
}

// Round 11
// 1142.293 us; speedup vs baseline: 1.3057x; 1.0328x over previous
//
#include <hip/hip_runtime.h>
#include <cstdint>

typedef unsigned short u16;
typedef __attribute__((ext_vector_type(8))) short short8;
typedef __attribute__((ext_vector_type(4))) short s16x4;
typedef __attribute__((ext_vector_type(4))) float f32x4;

#define MFMA_16x16x32(a,b,c) __builtin_amdgcn_mfma_f32_16x16x32_bf16(a,b,c,0,0,0)

// async global->LDS, 16B per lane, wave covers 1024B (16 rows of a [*][32] bf16 tile)
#define GLDS16(lds, g) __builtin_amdgcn_global_load_lds( \
    (const __attribute__((address_space(1))) unsigned int*)(g), \
    (__attribute__((address_space(3))) unsigned int*)(lds), 16, 0, 0)

#define BB 2
#define SS 1024
#define DD 2048
#define HH 16
#define HKK 4
#define HDD 128
#define EE 16
#define NTOP 6
#define II 1024
#define ISS 2048
#define TT 2048
#define CAP 2048

__device__ __forceinline__ u16 f2b(float f) {
    union { float f; uint32_t u; } v; v.f = f;
    uint32_t r = v.u + 0x7FFFu + ((v.u >> 16) & 1u);
    return (u16)(r >> 16);
}
__device__ __forceinline__ float b2f(u16 h) {
    union { uint32_t u; float f; } v; v.u = ((uint32_t)h) << 16;
    return v.f;
}
__device__ __forceinline__ void fsplit(float f, u16& hi, u16& lo) {
    u16 h = f2b(f);
    hi = h;
    lo = f2b(f - b2f(h));
}

// ---- Prep: transpose+convert W f32 [R][C] -> bf16 [C][R] (hi[,lo]) ---------
// 64x64 tiles, 16B stores (R11: was 32x32 with 8B stores).
template<bool SPLIT>
__global__ __launch_bounds__(256) void k_prep(
    const float* __restrict__ In, u16* __restrict__ Oh, u16* __restrict__ Ol,
    int R, int C)
{
    const size_t zoff = (size_t)blockIdx.z * R * C;
    In += zoff; Oh += zoff; if (SPLIT) Ol += zoff;
    const int r0 = blockIdx.y * 64, c0 = blockIdx.x * 64;
    __shared__ float tile[64][65];
    const int tx = threadIdx.x & 15, ty = threadIdx.x >> 4;   // 16 x 16
    #pragma unroll
    for (int i = 0; i < 4; ++i) {
        f32x4 v = *(const f32x4*)(In + (size_t)(r0 + ty + i*16)*C + c0 + tx*4);
        tile[ty + i*16][tx*4 + 0] = v[0];
        tile[ty + i*16][tx*4 + 1] = v[1];
        tile[ty + i*16][tx*4 + 2] = v[2];
        tile[ty + i*16][tx*4 + 3] = v[3];
    }
    __syncthreads();
    const int c = threadIdx.x >> 2;          // 0..63
    const int rs = (threadIdx.x & 3) * 16;   // 0,16,32,48
    short8 hv0, hv1, lv0, lv1;
    #pragma unroll
    for (int j = 0; j < 8; ++j) {
        float f = tile[rs + j][c];
        u16 hb = f2b(f);
        hv0[j] = (short)hb;
        lv0[j] = SPLIT ? (short)f2b(f - b2f(hb)) : (short)0;
    }
    #pragma unroll
    for (int j = 0; j < 8; ++j) {
        float f = tile[rs + 8 + j][c];
        u16 hb = f2b(f);
        hv1[j] = (short)hb;
        lv1[j] = SPLIT ? (short)f2b(f - b2f(hb)) : (short)0;
    }
    u16* po = Oh + (size_t)(c0 + c)*R + r0 + rs;
    *(short8*)po       = hv0;
    *(short8*)(po + 8) = hv1;
    if (SPLIT) {
        u16* pl = Ol + (size_t)(c0 + c)*R + r0 + rs;
        *(short8*)pl       = lv0;
        *(short8*)(pl + 8) = lv1;
    }
}

// ---------------- RMSNorm f32 in -> split bf16 (hi,lo) ----------------------
__global__ __launch_bounds__(256) void k_rmsnorm_split(
    const float* __restrict__ X, const float* __restrict__ Wt,
    u16* __restrict__ Oh, u16* __restrict__ Ol)
{
    const int t = blockIdx.x;
    const float* x = X + (size_t)t * DD;
    const int base = threadIdx.x * 8;
    f32x4 v0 = *(const f32x4*)(x + base);
    f32x4 v1 = *(const f32x4*)(x + base + 4);
    float ss = 0.f;
    #pragma unroll
    for (int j = 0; j < 4; ++j) ss += v0[j]*v0[j] + v1[j]*v1[j];
    #pragma unroll
    for (int o = 1; o < 64; o <<= 1) ss += __shfl_xor(ss, o);
    __shared__ float red[4];
    if ((threadIdx.x & 63) == 0) red[threadIdx.x >> 6] = ss;
    __syncthreads();
    float tot = red[0] + red[1] + red[2] + red[3];
    float inv = rsqrtf(tot * (1.0f/DD) + 1e-6f);
    f32x4 w0 = *(const f32x4*)(Wt + base);
    f32x4 w1 = *(const f32x4*)(Wt + base + 4);
    u16* oh = Oh + (size_t)t*DD + base;
    u16* ol = Ol + (size_t)t*DD + base;
    #pragma unroll
    for (int j = 0; j < 4; ++j) {
        float y0 = v0[j]*inv*w0[j];
        float y1 = v1[j]*inv*w1[j];
        fsplit(y0, oh[j],   ol[j]);
        fsplit(y1, oh[4+j], ol[4+j]);
    }
}

// ---------------- RMSNorm f32 in -> bf16 + f32 ------------------------------
__global__ __launch_bounds__(256) void k_rmsnorm_bf(
    const float* __restrict__ X, const float* __restrict__ Wt,
    u16* __restrict__ Ob, float* __restrict__ Of)
{
    const int t = blockIdx.x;
    const float* x = X + (size_t)t * DD;
    const int base = threadIdx.x * 8;
    f32x4 v0 = *(const f32x4*)(x + base);
    f32x4 v1 = *(const f32x4*)(x + base + 4);
    float ss = 0.f;
    #pragma unroll
    for (int j = 0; j < 4; ++j) ss += v0[j]*v0[j] + v1[j]*v1[j];
    #pragma unroll
    for (int o = 1; o < 64; o <<= 1) ss += __shfl_xor(ss, o);
    __shared__ float red[4];
    if ((threadIdx.x & 63) == 0) red[threadIdx.x >> 6] = ss;
    __syncthreads();
    float tot = red[0] + red[1] + red[2] + red[3];
    float inv = rsqrtf(tot * (1.0f/DD) + 1e-6f);
    f32x4 w0 = *(const f32x4*)(Wt + base);
    f32x4 w1 = *(const f32x4*)(Wt + base + 4);
    u16* ob = Ob + (size_t)t*DD + base;
    float* of = Of + (size_t)t*DD + base;
    #pragma unroll
    for (int j = 0; j < 4; ++j) {
        float y0 = v0[j]*inv*w0[j];
        float y1 = v1[j]*inv*w1[j];
        ob[j] = f2b(y0); ob[4+j] = f2b(y1);
        of[j] = y0;      of[4+j] = y1;
    }
}

// ------- High-precision GEMM: C = (Ah+Al) @ (Bh+Bl)^T, pre-split bf16 -------
// 2-phase prefetch, dbuf LDS. EPI 1: f32 + residual; 2: f32
template<int EPI>
__global__ __launch_bounds__(256) void k_gemm_hi(
    const u16* __restrict__ Ah, const u16* __restrict__ Al,
    const u16* __restrict__ Bth, const u16* __restrict__ Btl,
    float* __restrict__ C, const float* __restrict__ Res,
    int M, int N, int K)
{
    __shared__ u16 Ash[2][128][32];
    __shared__ u16 Asl[2][128][32];
    __shared__ u16 Bsh[2][128][32];
    __shared__ u16 Bsl[2][128][32];
    const int tid = threadIdx.x;
    const int lane = tid & 63;
    const int w = tid >> 6;
    const int m0 = blockIdx.y * 128, n0 = blockIdx.x * 128;
    const int wm = (w >> 1) * 64, wn = (w & 1) * 64;
    const int l15 = lane & 15, lhi = lane >> 4;
    f32x4 acc[4][4];
    #pragma unroll
    for (int a = 0; a < 4; ++a)
        #pragma unroll
        for (int b = 0; b < 4; ++b) acc[a][b] = 0;

    const int gr = w*32 + (lane >> 2);
    const int gc = (lane & 3) * 8;
    const u16* ahP0 = Ah  + (size_t)(m0 + gr) * K + gc;
    const u16* alP0 = Al  + (size_t)(m0 + gr) * K + gc;
    const u16* bhP0 = Bth + (size_t)(n0 + gr) * K + gc;
    const u16* blP0 = Btl + (size_t)(n0 + gr) * K + gc;
    const size_t r16 = (size_t)16 * K;

    GLDS16(&Ash[0][w*32][0],      ahP0);
    GLDS16(&Ash[0][w*32 + 16][0], ahP0 + r16);
    GLDS16(&Asl[0][w*32][0],      alP0);
    GLDS16(&Asl[0][w*32 + 16][0], alP0 + r16);
    GLDS16(&Bsh[0][w*32][0],      bhP0);
    GLDS16(&Bsh[0][w*32 + 16][0], bhP0 + r16);
    GLDS16(&Bsl[0][w*32][0],      blP0);
    GLDS16(&Bsl[0][w*32 + 16][0], blP0 + r16);
    __syncthreads();

    int cur = 0;
    for (int k0 = 0; k0 < K; k0 += 32) {
        const int nxt = k0 + 32;
        if (nxt < K) {
            GLDS16(&Ash[cur^1][w*32][0],      ahP0 + nxt);
            GLDS16(&Ash[cur^1][w*32 + 16][0], ahP0 + r16 + nxt);
            GLDS16(&Asl[cur^1][w*32][0],      alP0 + nxt);
            GLDS16(&Asl[cur^1][w*32 + 16][0], alP0 + r16 + nxt);
            GLDS16(&Bsh[cur^1][w*32][0],      bhP0 + nxt);
            GLDS16(&Bsh[cur^1][w*32 + 16][0], bhP0 + r16 + nxt);
            GLDS16(&Bsl[cur^1][w*32][0],      blP0 + nxt);
            GLDS16(&Bsl[cur^1][w*32 + 16][0], blP0 + r16 + nxt);
        }
        short8 afh[4], afl[4], bfh[4], bfl[4];
        #pragma unroll
        for (int i = 0; i < 4; ++i) {
            afh[i] = *(const short8*)&Ash[cur][wm + i*16 + l15][lhi*8];
            afl[i] = *(const short8*)&Asl[cur][wm + i*16 + l15][lhi*8];
            bfh[i] = *(const short8*)&Bsh[cur][wn + i*16 + l15][lhi*8];
            bfl[i] = *(const short8*)&Bsl[cur][wn + i*16 + l15][lhi*8];
        }
        #pragma unroll
        for (int a = 0; a < 4; ++a)
            #pragma unroll
            for (int b = 0; b < 4; ++b) {
                acc[a][b] = MFMA_16x16x32(afh[a], bfh[b], acc[a][b]);
                acc[a][b] = MFMA_16x16x32(afh[a], bfl[b], acc[a][b]);
                acc[a][b] = MFMA_16x16x32(afl[a], bfh[b], acc[a][b]);
            }
        __syncthreads();
        cur ^= 1;
    }
    #pragma unroll
    for (int a = 0; a < 4; ++a)
      #pragma unroll
      for (int b = 0; b < 4; ++b)
        #pragma unroll
        for (int r = 0; r < 4; ++r) {
            int m = m0 + wm + a*16 + lhi*4 + r;
            int n = n0 + wn + b*16 + l15;
            size_t off = (size_t)m * N + n;
            float v = acc[a][b][r];
            if (EPI == 1) C[off] = v + Res[off];
            else C[off] = v;
        }
}

// ---------------- Dense GEMM: C(MxN) = A_bf16 @ Bt_bf16^T, 2-phase ----------
// EPI 0: bf16 store; 2: f32 store
template<int EPI>
__global__ __launch_bounds__(256) void k_gemm(
    const u16* __restrict__ A, const u16* __restrict__ Bt,
    void* __restrict__ C, int M, int N, int K)
{
    __shared__ u16 As[2][128][32];
    __shared__ u16 Bs[2][128][32];
    const int tid = threadIdx.x;
    const int lane = tid & 63;
    const int w = tid >> 6;
    const int m0 = blockIdx.y * 128, n0 = blockIdx.x * 128;
    const int wm = (w >> 1) * 64, wn = (w & 1) * 64;
    const int l15 = lane & 15, lhi = lane >> 4;
    f32x4 acc[4][4];
    #pragma unroll
    for (int a = 0; a < 4; ++a)
        #pragma unroll
        for (int b = 0; b < 4; ++b) acc[a][b] = 0;

    const int gr = w*32 + (lane >> 2);
    const int gc = (lane & 3) * 8;
    const u16* aP0 = A  + (size_t)(m0 + gr) * K + gc;
    const u16* bP0 = Bt + (size_t)(n0 + gr) * K + gc;
    const size_t r16 = (size_t)16 * K;

    GLDS16(&As[0][w*32][0],      aP0);
    GLDS16(&As[0][w*32 + 16][0], aP0 + r16);
    GLDS16(&Bs[0][w*32][0],      bP0);
    GLDS16(&Bs[0][w*32 + 16][0], bP0 + r16);
    __syncthreads();

    int cur = 0;
    for (int k0 = 0; k0 < K; k0 += 32) {
        const int nxt = k0 + 32;
        if (nxt < K) {
            GLDS16(&As[cur^1][w*32][0],      aP0 + nxt);
            GLDS16(&As[cur^1][w*32 + 16][0], aP0 + r16 + nxt);
            GLDS16(&Bs[cur^1][w*32][0],      bP0 + nxt);
            GLDS16(&Bs[cur^1][w*32 + 16][0], bP0 + r16 + nxt);
        }
        short8 af[4], bf[4];
        #pragma unroll
        for (int i = 0; i < 4; ++i) af[i] = *(const short8*)&As[cur][wm + i*16 + l15][lhi*8];
        #pragma unroll
        for (int i = 0; i < 4; ++i) bf[i] = *(const short8*)&Bs[cur][wn + i*16 + l15][lhi*8];
        #pragma unroll
        for (int a = 0; a < 4; ++a)
            #pragma unroll
            for (int b = 0; b < 4; ++b)
                acc[a][b] = MFMA_16x16x32(af[a], bf[b], acc[a][b]);
        __syncthreads();
        cur ^= 1;
    }
    #pragma unroll
    for (int a = 0; a < 4; ++a)
      #pragma unroll
      for (int b = 0; b < 4; ++b)
        #pragma unroll
        for (int r = 0; r < 4; ++r) {
            int m = m0 + wm + a*16 + lhi*4 + r;
            int n = n0 + wn + b*16 + l15;
            size_t off = (size_t)m * N + n;
            float v = acc[a][b][r];
            if (EPI == 0) ((u16*)C)[off] = f2b(v);
            else ((float*)C)[off] = v;
        }
}

// ------- Shared GLU GEMM (R6-proven): 128M x 64N dual, 3 blocks/CU ----------
__global__ __launch_bounds__(256) void k_glu_sh(
    const u16* __restrict__ Xb, const u16* __restrict__ W1t,
    const u16* __restrict__ W2t, u16* __restrict__ Hout,
    int M, int NE, int K)
{
    const int m0 = blockIdx.y * 128;
    const int n0 = blockIdx.x * 64;

    __shared__ u16 As[2][128][32];
    __shared__ u16 B1s[2][64][32];
    __shared__ u16 B2s[2][64][32];

    const int tid = threadIdx.x, lane = tid & 63, w = tid >> 6;
    const int wm = (w >> 1) * 64, wn = (w & 1) * 32;
    const int l15 = lane & 15, lhi = lane >> 4;
    f32x4 acc1[4][2], acc2[4][2];
    #pragma unroll
    for (int a = 0; a < 4; ++a)
        #pragma unroll
        for (int j = 0; j < 2; ++j) { acc1[a][j] = 0; acc2[a][j] = 0; }

    const int gr  = w*32 + (lane >> 2);
    const int grB = w*16 + (lane >> 2);
    const int gc  = (lane & 3) * 8;
    const u16* aP0 = Xb  + (size_t)(m0 + gr) * K + gc;
    const u16* aP1 = Xb  + (size_t)(m0 + gr + 16) * K + gc;
    const u16* b1P = W1t + (size_t)(n0 + grB) * K + gc;
    const u16* b2P = W2t + (size_t)(n0 + grB) * K + gc;

    auto stage = [&](int bf, int kk) {
        GLDS16(&As[bf][w*32][0],      aP0 + kk);
        GLDS16(&As[bf][w*32 + 16][0], aP1 + kk);
        GLDS16(&B1s[bf][w*16][0],     b1P + kk);
        GLDS16(&B2s[bf][w*16][0],     b2P + kk);
    };

    stage(0, 0);
    __syncthreads();
    int cur = 0;
    for (int k0 = 0; k0 < K; k0 += 32) {
        const int nxt = k0 + 32;
        if (nxt < K) stage(cur ^ 1, nxt);
        short8 af[4], b1[2], b2[2];
        #pragma unroll
        for (int i = 0; i < 4; ++i) af[i] = *(const short8*)&As[cur][wm + i*16 + l15][lhi*8];
        #pragma unroll
        for (int j = 0; j < 2; ++j) {
            b1[j] = *(const short8*)&B1s[cur][wn + j*16 + l15][lhi*8];
            b2[j] = *(const short8*)&B2s[cur][wn + j*16 + l15][lhi*8];
        }
        #pragma unroll
        for (int a = 0; a < 4; ++a)
            #pragma unroll
            for (int j = 0; j < 2; ++j) {
                acc1[a][j] = MFMA_16x16x32(af[a], b1[j], acc1[a][j]);
                acc2[a][j] = MFMA_16x16x32(af[a], b2[j], acc2[a][j]);
            }
        __syncthreads();
        cur ^= 1;
    }
    #pragma unroll
    for (int a = 0; a < 4; ++a)
      #pragma unroll
      for (int j = 0; j < 2; ++j)
        #pragma unroll
        for (int r = 0; r < 4; ++r) {
            int m = m0 + wm + a*16 + lhi*4 + r;
            int n = n0 + wn + j*16 + l15;
            float g = acc1[a][j][r], u = acc2[a][j][r];
            float hval = g / (1.0f + __expf(-g)) * u;
            Hout[(size_t)m * NE + n] = f2b(hval);
        }
}

// ------- Routed GLU GEMM (R10): tile 256M x 64N dual, per-wave 128x(32+32) --
__global__ __launch_bounds__(256, 2) void k_glu_rt(
    const u16* __restrict__ Xb, const u16* __restrict__ W1t,
    const u16* __restrict__ W2t, u16* __restrict__ Hout,
    const int* __restrict__ list, const int* __restrict__ cntp,
    int NE, int K)
{
    const int e = blockIdx.z;
    const int cnt = cntp[e];
    const int m0 = blockIdx.y * 256;
    if (m0 >= cnt) return;
    const int n0 = blockIdx.x * 64;
    const u16* w1 = W1t + (size_t)e * NE * K;
    const u16* w2 = W2t + (size_t)e * NE * K;
    u16* hout = Hout + (size_t)e * CAP * NE;
    const int* lst = list + e * CAP;

    __shared__ u16 As[2][256][32];
    __shared__ u16 B1s[2][64][32];
    __shared__ u16 B2s[2][64][32];

    const int tid = threadIdx.x, lane = tid & 63, w = tid >> 6;
    const int wm = (w >> 1) * 128, wn = (w & 1) * 32;
    const int l15 = lane & 15, lhi = lane >> 4;
    f32x4 acc1[8][2], acc2[8][2];
    #pragma unroll
    for (int a = 0; a < 8; ++a)
        #pragma unroll
        for (int j = 0; j < 2; ++j) { acc1[a][j] = 0; acc2[a][j] = 0; }

    const int gr = lane >> 2;
    const int gc = (lane & 3) * 8;
    const u16* aP[4];
    #pragma unroll
    for (int j = 0; j < 4; ++j) {
        int mr = m0 + w*64 + j*16 + gr;
        int arow = (mr < cnt) ? (lst[mr] >> 3) : 0;
        aP[j] = Xb + (size_t)arow * K + gc;
    }
    const u16* b1P = w1 + (size_t)(n0 + w*16 + gr) * K + gc;
    const u16* b2P = w2 + (size_t)(n0 + w*16 + gr) * K + gc;

    auto stage = [&](int bf, int kk) {
        #pragma unroll
        for (int j = 0; j < 4; ++j)
            GLDS16(&As[bf][w*64 + j*16][0], aP[j] + kk);
        GLDS16(&B1s[bf][w*16][0], b1P + kk);
        GLDS16(&B2s[bf][w*16][0], b2P + kk);
    };

    stage(0, 0);
    __syncthreads();
    int cur = 0;
    for (int k0 = 0; k0 < K; k0 += 32) {
        const int nxt = k0 + 32;
        if (nxt < K) stage(cur ^ 1, nxt);
        short8 af[8], b1[2], b2[2];
        #pragma unroll
        for (int i = 0; i < 8; ++i) af[i] = *(const short8*)&As[cur][wm + i*16 + l15][lhi*8];
        #pragma unroll
        for (int j = 0; j < 2; ++j) {
            b1[j] = *(const short8*)&B1s[cur][wn + j*16 + l15][lhi*8];
            b2[j] = *(const short8*)&B2s[cur][wn + j*16 + l15][lhi*8];
        }
        #pragma unroll
        for (int a = 0; a < 8; ++a)
            #pragma unroll
            for (int j = 0; j < 2; ++j) {
                acc1[a][j] = MFMA_16x16x32(af[a], b1[j], acc1[a][j]);
                acc2[a][j] = MFMA_16x16x32(af[a], b2[j], acc2[a][j]);
            }
        __syncthreads();
        cur ^= 1;
    }
    #pragma unroll
    for (int a = 0; a < 8; ++a)
      #pragma unroll
      for (int j = 0; j < 2; ++j)
        #pragma unroll
        for (int r = 0; r < 4; ++r) {
            int m = m0 + wm + a*16 + lhi*4 + r;
            if (m < cnt) {
                int n = n0 + wn + j*16 + l15;
                float g = acc1[a][j][r], u = acc2[a][j][r];
                float hval = g / (1.0f + __expf(-g)) * u;
                hout[(size_t)m * NE + n] = f2b(hval);
            }
        }
}

// ------- Routed down GEMM (R10): tile 256x128, per-wave 128x64, scatter -----
__global__ __launch_bounds__(256, 2) void k_down_scatter(
    const u16* __restrict__ Hb, const u16* __restrict__ WdTt,
    u16* __restrict__ Rbuf, const int* __restrict__ list,
    const float* __restrict__ wts, const int* __restrict__ cntp,
    int N, int K)
{
    const int e = blockIdx.z;
    const int cnt = cntp[e];
    const int m0 = blockIdx.y * 256;
    if (m0 >= cnt) return;
    const int n0 = blockIdx.x * 128;
    const u16* A  = Hb   + (size_t)e * CAP * K;
    const u16* Bt = WdTt + (size_t)e * N * K;

    __shared__ u16 As[2][256][32];
    __shared__ u16 Bs[2][128][32];
    const int tid = threadIdx.x, lane = tid & 63, w = tid >> 6;
    const int wm = (w >> 1) * 128, wn = (w & 1) * 64;
    const int l15 = lane & 15, lhi = lane >> 4;
    f32x4 acc[8][4];
    #pragma unroll
    for (int a = 0; a < 8; ++a)
        #pragma unroll
        for (int b = 0; b < 4; ++b) acc[a][b] = 0;

    const int gr = lane >> 2;
    const int gc = (lane & 3) * 8;
    const u16* aP = A  + (size_t)(m0 + w*64 + gr) * K + gc;
    const u16* bP = Bt + (size_t)(n0 + w*32 + gr) * K + gc;
    const size_t r16 = (size_t)16 * K;

    auto stage = [&](int bf, int kk) {
        GLDS16(&As[bf][w*64][0],      aP + kk);
        GLDS16(&As[bf][w*64 + 16][0], aP + r16 + kk);
        GLDS16(&As[bf][w*64 + 32][0], aP + 2*r16 + kk);
        GLDS16(&As[bf][w*64 + 48][0], aP + 3*r16 + kk);
        GLDS16(&Bs[bf][w*32][0],      bP + kk);
        GLDS16(&Bs[bf][w*32 + 16][0], bP + r16 + kk);
    };

    stage(0, 0);
    __syncthreads();
    int cur = 0;
    for (int k0 = 0; k0 < K; k0 += 32) {
        const int nxt = k0 + 32;
        if (nxt < K) stage(cur ^ 1, nxt);
        short8 af[8], bf4[4];
        #pragma unroll
        for (int i = 0; i < 8; ++i) af[i] = *(const short8*)&As[cur][wm + i*16 + l15][lhi*8];
        #pragma unroll
        for (int i = 0; i < 4; ++i) bf4[i] = *(const short8*)&Bs[cur][wn + i*16 + l15][lhi*8];
        #pragma unroll
        for (int a = 0; a < 8; ++a)
            #pragma unroll
            for (int b = 0; b < 4; ++b)
                acc[a][b] = MFMA_16x16x32(af[a], bf4[b], acc[a][b]);
        __syncthreads();
        cur ^= 1;
    }
    #pragma unroll
    for (int a = 0; a < 8; ++a)
      #pragma unroll
      for (int b = 0; b < 4; ++b)
        #pragma unroll
        for (int r = 0; r < 4; ++r) {
            int m = m0 + wm + a*16 + lhi*4 + r;
            if (m < cnt) {
                int n = n0 + wn + b*16 + l15;
                int enc = list[e*CAP + m];
                float wgt = wts[e*CAP + m];
                int tok = enc >> 3, kk = enc & 7;
                Rbuf[((size_t)tok*NTOP + kk)*N + n] = f2b(acc[a][b][r] * wgt);
            }
        }
}

// -------- Fused RoPE+split (q,k) AND V^T split, single launch ---------------
__global__ __launch_bounds__(256) void k_rope_vt(
    const float* __restrict__ QKV,
    const float* __restrict__ Cs, const float* __restrict__ Sn,
    u16* __restrict__ Qh, u16* __restrict__ Ql,
    u16* __restrict__ Kh, u16* __restrict__ Kl,
    u16* __restrict__ Vth, u16* __restrict__ Vtl)
{
    int id = blockIdx.x * 256 + threadIdx.x;
    if (id < TT*20*64) {
        int pr = id & 63;
        int rest = id >> 6;
        int hh = rest % 20;
        int tok = rest / 20;
        int d0 = pr * 2;
        float c0 = Cs[(size_t)tok*HDD + d0];
        float c1 = Cs[(size_t)tok*HDD + d0 + 1];
        float s0 = Sn[(size_t)tok*HDD + d0];
        float s1 = Sn[(size_t)tok*HDD + d0 + 1];
        const float* p = QKV + (size_t)tok*3072 + (hh < HH ? hh*HDD : 2048 + (hh - HH)*HDD);
        float x0 = p[d0], x1 = p[d0+1];
        float y0 = x0*c0 - x1*s0;
        float y1 = x1*c1 + x0*s1;
        u16 *oh, *ol;
        size_t ooff;
        if (hh < HH) { ooff = ((size_t)tok*HH + hh)*HDD + d0; oh = Qh; ol = Ql; }
        else         { ooff = ((size_t)tok*HKK + (hh - HH))*HDD + d0; oh = Kh; ol = Kl; }
        fsplit(y0, oh[ooff],     ol[ooff]);
        fsplit(y1, oh[ooff + 1], ol[ooff + 1]);
    } else {
        int vid = id - TT*20*64;       // 0 .. TT*HKK*HDD/8 - 1
        int oid = vid * 8;
        int s0 = oid & (SS - 1);
        int r = oid >> 10;
        int d = r & (HDD - 1);
        int bh = r >> 7;
        int b = bh >> 2, hk = bh & 3;
        #pragma unroll
        for (int j = 0; j < 8; ++j) {
            int s = s0 + j;
            float v = QKV[(size_t)(b*SS + s)*3072 + 2560 + hk*HDD + d];
            fsplit(v, Vth[oid + j], Vtl[oid + j]);
        }
    }
}

// ---------------- Flash attention, split-bf16 precision ---------------------
__global__ __launch_bounds__(256) void k_attn_hi(
    const u16* __restrict__ Qh, const u16* __restrict__ Ql,
    const u16* __restrict__ Kh, const u16* __restrict__ Kl,
    const u16* __restrict__ Vth, const u16* __restrict__ Vtl,
    u16* __restrict__ Oh, u16* __restrict__ Ol)
{
    const int tid = threadIdx.x;
    const int lane = tid & 63;
    const int w = tid >> 6;
    const int q0 = blockIdx.x * 64;
    const int b = blockIdx.y >> 4;
    const int h = blockIdx.y & 15;
    const int hk = h >> 2;
    const int l15 = lane & 15, lhi = lane >> 4;

    __shared__ u16 Ksh[32][136];
    __shared__ u16 Ksl[32][136];
    __shared__ u16 Vsh[128][40];
    __shared__ u16 Vsl[128][40];
    __shared__ u16 Psh[4][16][40];
    __shared__ u16 Psl[4][16][40];

    short8 qfh[4], qfl[4];
    {
        const int qrow = q0 + w*16 + l15;
        const u16* qph = Qh + ((size_t)(b*SS + qrow)*HH + h)*HDD;
        const u16* qpl = Ql + ((size_t)(b*SS + qrow)*HH + h)*HDD;
        #pragma unroll
        for (int c = 0; c < 4; ++c) {
            qfh[c] = *(const short8*)(qph + c*32 + lhi*8);
            qfl[c] = *(const short8*)(qpl + c*32 + lhi*8);
        }
    }

    f32x4 oacc[8];
    #pragma unroll
    for (int ch = 0; ch < 8; ++ch) oacc[ch] = 0;
    float m_r[4] = {-1e30f, -1e30f, -1e30f, -1e30f};
    float l_r[4] = {0.f, 0.f, 0.f, 0.f};

    const int nkt = (q0 + 64) >> 5;
    const int kr = tid >> 3, kc = (tid & 7) * 16;
    const int vd = tid >> 1, vj = (tid & 1) * 16;

    for (int kt = 0; kt < nkt; ++kt) {
        __syncthreads();
        {
            size_t koff = ((size_t)(b*SS + kt*32 + kr)*HKK + hk)*HDD + kc;
            *(short8*)&Ksh[kr][kc]     = *(const short8*)(Kh + koff);
            *(short8*)&Ksh[kr][kc + 8] = *(const short8*)(Kh + koff + 8);
            *(short8*)&Ksl[kr][kc]     = *(const short8*)(Kl + koff);
            *(short8*)&Ksl[kr][kc + 8] = *(const short8*)(Kl + koff + 8);
        }
        {
            size_t voff = ((size_t)(b*HKK + hk)*HDD + vd)*SS + kt*32 + vj;
            *(short8*)&Vsh[vd][vj]     = *(const short8*)(Vth + voff);
            *(short8*)&Vsh[vd][vj + 8] = *(const short8*)(Vth + voff + 8);
            *(short8*)&Vsl[vd][vj]     = *(const short8*)(Vtl + voff);
            *(short8*)&Vsl[vd][vj + 8] = *(const short8*)(Vtl + voff + 8);
        }
        __syncthreads();

        f32x4 s0 = 0, s1 = 0;
        #pragma unroll
        for (int c = 0; c < 4; ++c) {
            short8 kh0 = *(const short8*)&Ksh[l15][c*32 + lhi*8];
            short8 kl0 = *(const short8*)&Ksl[l15][c*32 + lhi*8];
            short8 kh1 = *(const short8*)&Ksh[16 + l15][c*32 + lhi*8];
            short8 kl1 = *(const short8*)&Ksl[16 + l15][c*32 + lhi*8];
            s0 = MFMA_16x16x32(qfh[c], kh0, s0);
            s0 = MFMA_16x16x32(qfh[c], kl0, s0);
            s0 = MFMA_16x16x32(qfl[c], kh0, s0);
            s1 = MFMA_16x16x32(qfh[c], kh1, s1);
            s1 = MFMA_16x16x32(qfh[c], kl1, s1);
            s1 = MFMA_16x16x32(qfl[c], kh1, s1);
        }
        const int irow0 = q0 + w*16 + lhi*4;
        const int j0 = kt*32 + l15;
        float ef[4];
        #pragma unroll
        for (int r = 0; r < 4; ++r) {
            float a0 = s0[r] * 0.08838834764831845f;
            float a1 = s1[r] * 0.08838834764831845f;
            const int ir = irow0 + r;
            if (j0 > ir) a0 = -1e30f;
            if (j0 + 16 > ir) a1 = -1e30f;
            float mx = fmaxf(a0, a1);
            #pragma unroll
            for (int o = 1; o < 16; o <<= 1) mx = fmaxf(mx, __shfl_xor(mx, o));
            float mn = fmaxf(m_r[r], mx);
            ef[r] = __expf(m_r[r] - mn);
            m_r[r] = mn;
            float p0 = __expf(a0 - mn);
            float p1 = __expf(a1 - mn);
            float ps = p0 + p1;
            #pragma unroll
            for (int o = 1; o < 16; o <<= 1) ps += __shfl_xor(ps, o);
            l_r[r] = l_r[r]*ef[r] + ps;
            fsplit(p0, Psh[w][lhi*4 + r][l15],      Psl[w][lhi*4 + r][l15]);
            fsplit(p1, Psh[w][lhi*4 + r][16 + l15], Psl[w][lhi*4 + r][16 + l15]);
        }
        #pragma unroll
        for (int ch = 0; ch < 8; ++ch) {
            f32x4 t = oacc[ch];
            t[0] *= ef[0]; t[1] *= ef[1]; t[2] *= ef[2]; t[3] *= ef[3];
            oacc[ch] = t;
        }
        __syncthreads();
        short8 pah = *(const short8*)&Psh[w][l15][lhi*8];
        short8 pal = *(const short8*)&Psl[w][l15][lhi*8];
        #pragma unroll
        for (int ch = 0; ch < 8; ++ch) {
            short8 bvh = *(const short8*)&Vsh[ch*16 + l15][lhi*8];
            short8 bvl = *(const short8*)&Vsl[ch*16 + l15][lhi*8];
            oacc[ch] = MFMA_16x16x32(pah, bvh, oacc[ch]);
            oacc[ch] = MFMA_16x16x32(pah, bvl, oacc[ch]);
            oacc[ch] = MFMA_16x16x32(pal, bvh, oacc[ch]);
        }
    }
    #pragma unroll
    for (int r = 0; r < 4; ++r) {
        const int row = q0 + w*16 + lhi*4 + r;
        const float inv = 1.0f / l_r[r];
        u16* oph = Oh + ((size_t)(b*SS + row)*HH + h)*HDD;
        u16* opl = Ol + ((size_t)(b*SS + row)*HH + h)*HDD;
        #pragma unroll
        for (int ch = 0; ch < 8; ++ch) {
            float o = oacc[ch][r] * inv;
            fsplit(o, oph[ch*16 + l15], opl[ch*16 + l15]);
        }
    }
}

// ---------------- Router: f32 logits, softmax, top-6, slot lists ------------
__global__ __launch_bounds__(256) void k_router(
    const float* __restrict__ X, const float* __restrict__ Wg,
    const float* __restrict__ bias,
    int* __restrict__ cnt, int* __restrict__ list, float* __restrict__ wts)
{
    const int t = blockIdx.x;
    const int e = threadIdx.x & 15, sl = threadIdx.x >> 4;
    const float* x = X + (size_t)t * DD;
    float part = 0.f;
    for (int i = 0; i < 128; ++i) {
        int k = sl * 128 + i;
        part += x[k] * Wg[(size_t)k * EE + e];
    }
    __shared__ float red[16][17];
    red[sl][e] = part;
    __syncthreads();
    if (threadIdx.x == 0) {
        float lg[16], pr[16];
        for (int ee = 0; ee < 16; ++ee) {
            float s = 0.f;
            for (int q = 0; q < 16; ++q) s += red[q][ee];
            lg[ee] = s;
        }
        float mx = lg[0];
        for (int ee = 1; ee < 16; ++ee) mx = fmaxf(mx, lg[ee]);
        float sum = 0.f;
        for (int ee = 0; ee < 16; ++ee) { pr[ee] = expf(lg[ee] - mx); sum += pr[ee]; }
        float isum = 1.0f / sum;
        for (int ee = 0; ee < 16; ++ee) pr[ee] *= isum;
        unsigned used = 0;
        int sel[NTOP]; float rw[NTOP]; float s6 = 0.f;
        for (int kk = 0; kk < NTOP; ++kk) {
            int best = 0; float bv = -1e30f;
            for (int ee = 0; ee < 16; ++ee) {
                if (used & (1u << ee)) continue;
                float sc = pr[ee] + bias[ee];
                if (sc > bv) { bv = sc; best = ee; }
            }
            used |= 1u << best;
            sel[kk] = best; rw[kk] = pr[best]; s6 += pr[best];
        }
        float inv6 = 1.0f / fmaxf(s6, 1e-12f);
        for (int kk = 0; kk < NTOP; ++kk) {
            int ee = sel[kk];
            int pos = atomicAdd(&cnt[ee], 1);
            list[ee*CAP + pos] = (t << 3) | kk;
            wts[ee*CAP + pos] = rw[kk] * inv6;
        }
    }
}

// ---------------- Final: out = h2 + shared + sum_kk routed ------------------
__global__ __launch_bounds__(256) void k_final(
    const float* __restrict__ h2, const float* __restrict__ yb,
    const u16* __restrict__ rb, float* __restrict__ out)
{
    int id = blockIdx.x * 256 + threadIdx.x;     // T*D/4
    size_t i4 = (size_t)id * 4;
    int t = id >> 9;
    int d = (id & 511) * 4;
    f32x4 acc = *(const f32x4*)(h2 + i4);
    f32x4 y = *(const f32x4*)(yb + i4);
    acc += y;
    #pragma unroll
    for (int kk = 0; kk < NTOP; ++kk) {
        s16x4 rv = *(const s16x4*)(rb + ((size_t)t*NTOP + kk)*DD + d);
        acc[0] += b2f((u16)rv[0]); acc[1] += b2f((u16)rv[1]);
        acc[2] += b2f((u16)rv[2]); acc[3] += b2f((u16)rv[3]);
    }
    *(f32x4*)(out + i4) = acc;
}

extern "C" void kernel_launch(void* const* d_in, const int* in_sizes, int n_in,
                              void* d_out, int out_size, void* d_ws, size_t ws_size,
                              hipStream_t stream)
{
    (void)in_sizes; (void)n_in; (void)out_size; (void)ws_size;
    const float* hidden = (const float*)d_in[0];
    const float* cosb   = (const float*)d_in[1];
    const float* sinb   = (const float*)d_in[2];
    const float* ln1    = (const float*)d_in[3];
    const float* ln2    = (const float*)d_in[4];
    const float* Wq     = (const float*)d_in[5];
    const float* Wk     = (const float*)d_in[6];
    const float* Wv     = (const float*)d_in[7];
    const float* Wo     = (const float*)d_in[8];
    const float* Wgate  = (const float*)d_in[9];
    const float* cbias  = (const float*)d_in[10];
    const float* Wg     = (const float*)d_in[11];
    const float* Wu     = (const float*)d_in[12];
    const float* Wd     = (const float*)d_in[13];
    const float* Wgs    = (const float*)d_in[14];
    const float* Wus    = (const float*)d_in[15];
    const float* Wds    = (const float*)d_in[16];
    float* out = (float*)d_out;

    char* ws = (char*)d_ws;
    size_t off = 0;
    auto alloc = [&](size_t bytes) {
        void* p = ws + off;
        off = (off + bytes + 255) & ~(size_t)255;
        return p;
    };
    // Pre-transposed bf16 weights
    u16* WqkvTh = (u16*)alloc((size_t)3072*2048*2);
    u16* WqkvTl = (u16*)alloc((size_t)3072*2048*2);
    u16* WoTh   = (u16*)alloc((size_t)2048*2048*2);
    u16* WoTl   = (u16*)alloc((size_t)2048*2048*2);
    u16* WgsT   = (u16*)alloc((size_t)2048*2048*2);
    u16* WusT   = (u16*)alloc((size_t)2048*2048*2);
    u16* WdsT   = (u16*)alloc((size_t)2048*2048*2);
    u16* WgT    = (u16*)alloc((size_t)EE*II*DD*2);
    u16* WuT    = (u16*)alloc((size_t)EE*II*DD*2);
    u16* WdT    = (u16*)alloc((size_t)EE*DD*II*2);
    // Activations
    u16*   x1h  = (u16*)  alloc((size_t)TT*DD*2);
    u16*   x1l  = (u16*)  alloc((size_t)TT*DD*2);
    float* qkvf = (float*)alloc((size_t)TT*3072*4);
    u16*   qh   = (u16*)  alloc((size_t)TT*HH*HDD*2);
    u16*   ql   = (u16*)  alloc((size_t)TT*HH*HDD*2);
    u16*   kh   = (u16*)  alloc((size_t)TT*HKK*HDD*2);
    u16*   kl   = (u16*)  alloc((size_t)TT*HKK*HDD*2);
    u16*   vth  = (u16*)  alloc((size_t)TT*HKK*HDD*2);
    u16*   vtl  = (u16*)  alloc((size_t)TT*HKK*HDD*2);
    u16*   aoh  = (u16*)  alloc((size_t)TT*HH*HDD*2);
    u16*   aol  = (u16*)  alloc((size_t)TT*HH*HDD*2);
    float* h2   = (float*)alloc((size_t)TT*DD*4);
    u16*   x2   = (u16*)  alloc((size_t)TT*DD*2);
    float* x2f  = (float*)alloc((size_t)TT*DD*4);
    int*   cnt  = (int*)  alloc(256);
    int*   lst  = (int*)  alloc((size_t)EE*CAP*4);
    float* wts  = (float*)alloc((size_t)EE*CAP*4);
    u16*   hE   = (u16*)  alloc((size_t)EE*CAP*II*2);
    u16*   rbuf = (u16*)  alloc((size_t)TT*NTOP*DD*2);
    // Aliases (lifetimes disjoint):
    u16*   hs   = x1h;            // [TT][ISS] bf16 = 8MB, x1h dead after QKV
    float* ybuf = qkvf;           // [TT][DD] f32 = 16MB, qkvf dead after splits

    // ---- Weight prep (transpose + bf16 convert [+ split]), 64x64 tiles ----
    k_prep<true ><<<dim3(32,32,1), 256, 0, stream>>>(Wq, WqkvTh, WqkvTl, 2048, 2048);
    k_prep<true ><<<dim3(8, 32,1), 256, 0, stream>>>(Wk, WqkvTh + (size_t)2048*2048, WqkvTl + (size_t)2048*2048, 2048, 512);
    k_prep<true ><<<dim3(8, 32,1), 256, 0, stream>>>(Wv, WqkvTh + (size_t)2560*2048, WqkvTl + (size_t)2560*2048, 2048, 512);
    k_prep<true ><<<dim3(32,32,1), 256, 0, stream>>>(Wo, WoTh, WoTl, 2048, 2048);
    k_prep<false><<<dim3(32,32,1), 256, 0, stream>>>(Wgs, WgsT, nullptr, 2048, 2048);
    k_prep<false><<<dim3(32,32,1), 256, 0, stream>>>(Wus, WusT, nullptr, 2048, 2048);
    k_prep<false><<<dim3(32,32,1), 256, 0, stream>>>(Wds, WdsT, nullptr, 2048, 2048);
    k_prep<false><<<dim3(16,32,EE), 256, 0, stream>>>(Wg, WgT, nullptr, 2048, 1024);
    k_prep<false><<<dim3(16,32,EE), 256, 0, stream>>>(Wu, WuT, nullptr, 2048, 1024);
    k_prep<false><<<dim3(32,16,EE), 256, 0, stream>>>(Wd, WdT, nullptr, 1024, 2048);

    // ---- Attention path (split-bf16 high precision) ----
    k_rmsnorm_split<<<TT, 256, 0, stream>>>(hidden, ln1, x1h, x1l);
    k_gemm_hi<2><<<dim3(24,16), 256, 0, stream>>>(x1h, x1l, WqkvTh, WqkvTl, qkvf, nullptr, TT, 3072, DD);
    k_rope_vt<<<(TT*20*64 + TT*HKK*HDD/8)/256, 256, 0, stream>>>(qkvf, cosb, sinb, qh, ql, kh, kl, vth, vtl);
    k_attn_hi<<<dim3(SS/64, BB*HH), 256, 0, stream>>>(qh, ql, kh, kl, vth, vtl, aoh, aol);
    k_gemm_hi<1><<<dim3(16,16), 256, 0, stream>>>(aoh, aol, WoTh, WoTl, h2, hidden, TT, DD, HH*HDD);

    // ---- MoE path ----
    k_rmsnorm_bf<<<TT, 256, 0, stream>>>(h2, ln2, x2, x2f);
    (void)hipMemsetAsync(cnt, 0, 256, stream);
    k_router<<<TT, 256, 0, stream>>>(x2f, Wgate, cbias, cnt, lst, wts);
    k_glu_sh<<<dim3(ISS/64, TT/128), 256, 0, stream>>>(x2, WgsT, WusT, hs, TT, ISS, DD);
    k_gemm<2><<<dim3(DD/128, TT/128), 256, 0, stream>>>(hs, WdsT, ybuf, TT, DD, ISS);
    k_glu_rt<<<dim3(II/64, CAP/256, EE), 256, 0, stream>>>(x2, WgT, WuT, hE, lst, cnt, II, DD);
    k_down_scatter<<<dim3(DD/128, CAP/256, EE), 256, 0, stream>>>(hE, WdT, rbuf, lst, wts, cnt, DD, II);
    k_final<<<(TT*DD/4)/256, 256, 0, stream>>>(h2, ybuf, rbuf, out);
}

// Round 12
// 1126.779 us; speedup vs baseline: 1.3236x; 1.0138x over previous
//
#include <hip/hip_runtime.h>
#include <cstdint>

typedef unsigned short u16;
typedef __attribute__((ext_vector_type(8))) short short8;
typedef __attribute__((ext_vector_type(4))) short s16x4;
typedef __attribute__((ext_vector_type(4))) float f32x4;

#define MFMA_16x16x32(a,b,c) __builtin_amdgcn_mfma_f32_16x16x32_bf16(a,b,c,0,0,0)

// async global->LDS, 16B per lane, wave covers 1024B (16 rows of a [*][32] bf16 tile)
#define GLDS16(lds, g) __builtin_amdgcn_global_load_lds( \
    (const __attribute__((address_space(1))) unsigned int*)(g), \
    (__attribute__((address_space(3))) unsigned int*)(lds), 16, 0, 0)

#define BB 2
#define SS 1024
#define DD 2048
#define HH 16
#define HKK 4
#define HDD 128
#define EE 16
#define NTOP 6
#define II 1024
#define ISS 2048
#define TT 2048
#define CAP 2048

__device__ __forceinline__ u16 f2b(float f) {
    union { float f; uint32_t u; } v; v.f = f;
    uint32_t r = v.u + 0x7FFFu + ((v.u >> 16) & 1u);
    return (u16)(r >> 16);
}
__device__ __forceinline__ float b2f(u16 h) {
    union { uint32_t u; float f; } v; v.u = ((uint32_t)h) << 16;
    return v.f;
}
__device__ __forceinline__ void fsplit(float f, u16& hi, u16& lo) {
    u16 h = f2b(f);
    hi = h;
    lo = f2b(f - b2f(h));
}

// T1: bijective chunked XCD swizzle (m204). Launch index -> work index such
// that each XCD covers a contiguous run of original (data-sharing) blocks.
__device__ __forceinline__ void xcd_swz(int& bx, int& by, int& bz) {
    const int gx = gridDim.x, gy = gridDim.y;
    const int n = gx * gy * gridDim.z;
    int lid = bx + gx * (by + gy * bz);
    int q = n >> 3, r = n & 7;
    int xcd = lid & 7, idx = lid >> 3;
    int nid = (xcd < r ? xcd * (q + 1) : r * (q + 1) + (xcd - r) * q) + idx;
    bx = nid % gx;
    int t = nid / gx;
    by = t % gy;
    bz = t / gy;
}

// ---- Prep: transpose+convert W f32 [R][C] -> bf16 [C][R] (hi[,lo]) ---------
template<bool SPLIT>
__global__ __launch_bounds__(256) void k_prep(
    const float* __restrict__ In, u16* __restrict__ Oh, u16* __restrict__ Ol,
    int R, int C)
{
    const size_t zoff = (size_t)blockIdx.z * R * C;
    In += zoff; Oh += zoff; if (SPLIT) Ol += zoff;
    const int r0 = blockIdx.y * 64, c0 = blockIdx.x * 64;
    __shared__ float tile[64][65];
    const int tx = threadIdx.x & 15, ty = threadIdx.x >> 4;   // 16 x 16
    #pragma unroll
    for (int i = 0; i < 4; ++i) {
        f32x4 v = *(const f32x4*)(In + (size_t)(r0 + ty + i*16)*C + c0 + tx*4);
        tile[ty + i*16][tx*4 + 0] = v[0];
        tile[ty + i*16][tx*4 + 1] = v[1];
        tile[ty + i*16][tx*4 + 2] = v[2];
        tile[ty + i*16][tx*4 + 3] = v[3];
    }
    __syncthreads();
    const int c = threadIdx.x >> 2;          // 0..63
    const int rs = (threadIdx.x & 3) * 16;   // 0,16,32,48
    short8 hv0, hv1, lv0, lv1;
    #pragma unroll
    for (int j = 0; j < 8; ++j) {
        float f = tile[rs + j][c];
        u16 hb = f2b(f);
        hv0[j] = (short)hb;
        lv0[j] = SPLIT ? (short)f2b(f - b2f(hb)) : (short)0;
    }
    #pragma unroll
    for (int j = 0; j < 8; ++j) {
        float f = tile[rs + 8 + j][c];
        u16 hb = f2b(f);
        hv1[j] = (short)hb;
        lv1[j] = SPLIT ? (short)f2b(f - b2f(hb)) : (short)0;
    }
    u16* po = Oh + (size_t)(c0 + c)*R + r0 + rs;
    *(short8*)po       = hv0;
    *(short8*)(po + 8) = hv1;
    if (SPLIT) {
        u16* pl = Ol + (size_t)(c0 + c)*R + r0 + rs;
        *(short8*)pl       = lv0;
        *(short8*)(pl + 8) = lv1;
    }
}

// ---------------- RMSNorm f32 in -> split bf16 (hi,lo) ----------------------
__global__ __launch_bounds__(256) void k_rmsnorm_split(
    const float* __restrict__ X, const float* __restrict__ Wt,
    u16* __restrict__ Oh, u16* __restrict__ Ol)
{
    const int t = blockIdx.x;
    const float* x = X + (size_t)t * DD;
    const int base = threadIdx.x * 8;
    f32x4 v0 = *(const f32x4*)(x + base);
    f32x4 v1 = *(const f32x4*)(x + base + 4);
    float ss = 0.f;
    #pragma unroll
    for (int j = 0; j < 4; ++j) ss += v0[j]*v0[j] + v1[j]*v1[j];
    #pragma unroll
    for (int o = 1; o < 64; o <<= 1) ss += __shfl_xor(ss, o);
    __shared__ float red[4];
    if ((threadIdx.x & 63) == 0) red[threadIdx.x >> 6] = ss;
    __syncthreads();
    float tot = red[0] + red[1] + red[2] + red[3];
    float inv = rsqrtf(tot * (1.0f/DD) + 1e-6f);
    f32x4 w0 = *(const f32x4*)(Wt + base);
    f32x4 w1 = *(const f32x4*)(Wt + base + 4);
    u16* oh = Oh + (size_t)t*DD + base;
    u16* ol = Ol + (size_t)t*DD + base;
    #pragma unroll
    for (int j = 0; j < 4; ++j) {
        float y0 = v0[j]*inv*w0[j];
        float y1 = v1[j]*inv*w1[j];
        fsplit(y0, oh[j],   ol[j]);
        fsplit(y1, oh[4+j], ol[4+j]);
    }
}

// ---------------- RMSNorm f32 in -> bf16 + f32 ------------------------------
__global__ __launch_bounds__(256) void k_rmsnorm_bf(
    const float* __restrict__ X, const float* __restrict__ Wt,
    u16* __restrict__ Ob, float* __restrict__ Of)
{
    const int t = blockIdx.x;
    const float* x = X + (size_t)t * DD;
    const int base = threadIdx.x * 8;
    f32x4 v0 = *(const f32x4*)(x + base);
    f32x4 v1 = *(const f32x4*)(x + base + 4);
    float ss = 0.f;
    #pragma unroll
    for (int j = 0; j < 4; ++j) ss += v0[j]*v0[j] + v1[j]*v1[j];
    #pragma unroll
    for (int o = 1; o < 64; o <<= 1) ss += __shfl_xor(ss, o);
    __shared__ float red[4];
    if ((threadIdx.x & 63) == 0) red[threadIdx.x >> 6] = ss;
    __syncthreads();
    float tot = red[0] + red[1] + red[2] + red[3];
    float inv = rsqrtf(tot * (1.0f/DD) + 1e-6f);
    f32x4 w0 = *(const f32x4*)(Wt + base);
    f32x4 w1 = *(const f32x4*)(Wt + base + 4);
    u16* ob = Ob + (size_t)t*DD + base;
    float* of = Of + (size_t)t*DD + base;
    #pragma unroll
    for (int j = 0; j < 4; ++j) {
        float y0 = v0[j]*inv*w0[j];
        float y1 = v1[j]*inv*w1[j];
        ob[j] = f2b(y0); ob[4+j] = f2b(y1);
        of[j] = y0;      of[4+j] = y1;
    }
}

// ------- High-precision GEMM: C = (Ah+Al) @ (Bh+Bl)^T, pre-split bf16 -------
// 2-phase prefetch, dbuf LDS. EPI 1: f32 + residual; 2: f32
template<int EPI>
__global__ __launch_bounds__(256) void k_gemm_hi(
    const u16* __restrict__ Ah, const u16* __restrict__ Al,
    const u16* __restrict__ Bth, const u16* __restrict__ Btl,
    float* __restrict__ C, const float* __restrict__ Res,
    int M, int N, int K)
{
    __shared__ u16 Ash[2][128][32];
    __shared__ u16 Asl[2][128][32];
    __shared__ u16 Bsh[2][128][32];
    __shared__ u16 Bsl[2][128][32];
    int bx = blockIdx.x, by = blockIdx.y, bz = blockIdx.z;
    xcd_swz(bx, by, bz);
    const int tid = threadIdx.x;
    const int lane = tid & 63;
    const int w = tid >> 6;
    const int m0 = by * 128, n0 = bx * 128;
    const int wm = (w >> 1) * 64, wn = (w & 1) * 64;
    const int l15 = lane & 15, lhi = lane >> 4;
    f32x4 acc[4][4];
    #pragma unroll
    for (int a = 0; a < 4; ++a)
        #pragma unroll
        for (int b = 0; b < 4; ++b) acc[a][b] = 0;

    const int gr = w*32 + (lane >> 2);
    const int gc = (lane & 3) * 8;
    const u16* ahP0 = Ah  + (size_t)(m0 + gr) * K + gc;
    const u16* alP0 = Al  + (size_t)(m0 + gr) * K + gc;
    const u16* bhP0 = Bth + (size_t)(n0 + gr) * K + gc;
    const u16* blP0 = Btl + (size_t)(n0 + gr) * K + gc;
    const size_t r16 = (size_t)16 * K;

    GLDS16(&Ash[0][w*32][0],      ahP0);
    GLDS16(&Ash[0][w*32 + 16][0], ahP0 + r16);
    GLDS16(&Asl[0][w*32][0],      alP0);
    GLDS16(&Asl[0][w*32 + 16][0], alP0 + r16);
    GLDS16(&Bsh[0][w*32][0],      bhP0);
    GLDS16(&Bsh[0][w*32 + 16][0], bhP0 + r16);
    GLDS16(&Bsl[0][w*32][0],      blP0);
    GLDS16(&Bsl[0][w*32 + 16][0], blP0 + r16);
    __syncthreads();

    int cur = 0;
    for (int k0 = 0; k0 < K; k0 += 32) {
        const int nxt = k0 + 32;
        if (nxt < K) {
            GLDS16(&Ash[cur^1][w*32][0],      ahP0 + nxt);
            GLDS16(&Ash[cur^1][w*32 + 16][0], ahP0 + r16 + nxt);
            GLDS16(&Asl[cur^1][w*32][0],      alP0 + nxt);
            GLDS16(&Asl[cur^1][w*32 + 16][0], alP0 + r16 + nxt);
            GLDS16(&Bsh[cur^1][w*32][0],      bhP0 + nxt);
            GLDS16(&Bsh[cur^1][w*32 + 16][0], bhP0 + r16 + nxt);
            GLDS16(&Bsl[cur^1][w*32][0],      blP0 + nxt);
            GLDS16(&Bsl[cur^1][w*32 + 16][0], blP0 + r16 + nxt);
        }
        short8 afh[4], afl[4], bfh[4], bfl[4];
        #pragma unroll
        for (int i = 0; i < 4; ++i) {
            afh[i] = *(const short8*)&Ash[cur][wm + i*16 + l15][lhi*8];
            afl[i] = *(const short8*)&Asl[cur][wm + i*16 + l15][lhi*8];
            bfh[i] = *(const short8*)&Bsh[cur][wn + i*16 + l15][lhi*8];
            bfl[i] = *(const short8*)&Bsl[cur][wn + i*16 + l15][lhi*8];
        }
        #pragma unroll
        for (int a = 0; a < 4; ++a)
            #pragma unroll
            for (int b = 0; b < 4; ++b) {
                acc[a][b] = MFMA_16x16x32(afh[a], bfh[b], acc[a][b]);
                acc[a][b] = MFMA_16x16x32(afh[a], bfl[b], acc[a][b]);
                acc[a][b] = MFMA_16x16x32(afl[a], bfh[b], acc[a][b]);
            }
        __syncthreads();
        cur ^= 1;
    }
    #pragma unroll
    for (int a = 0; a < 4; ++a)
      #pragma unroll
      for (int b = 0; b < 4; ++b)
        #pragma unroll
        for (int r = 0; r < 4; ++r) {
            int m = m0 + wm + a*16 + lhi*4 + r;
            int n = n0 + wn + b*16 + l15;
            size_t off = (size_t)m * N + n;
            float v = acc[a][b][r];
            if (EPI == 1) C[off] = v + Res[off];
            else C[off] = v;
        }
}

// ---------------- Dense GEMM: C(MxN) = A_bf16 @ Bt_bf16^T, 2-phase ----------
// EPI 0: bf16 store; 2: f32 store
template<int EPI>
__global__ __launch_bounds__(256) void k_gemm(
    const u16* __restrict__ A, const u16* __restrict__ Bt,
    void* __restrict__ C, int M, int N, int K)
{
    __shared__ u16 As[2][128][32];
    __shared__ u16 Bs[2][128][32];
    int bx = blockIdx.x, by = blockIdx.y, bz = blockIdx.z;
    xcd_swz(bx, by, bz);
    const int tid = threadIdx.x;
    const int lane = tid & 63;
    const int w = tid >> 6;
    const int m0 = by * 128, n0 = bx * 128;
    const int wm = (w >> 1) * 64, wn = (w & 1) * 64;
    const int l15 = lane & 15, lhi = lane >> 4;
    f32x4 acc[4][4];
    #pragma unroll
    for (int a = 0; a < 4; ++a)
        #pragma unroll
        for (int b = 0; b < 4; ++b) acc[a][b] = 0;

    const int gr = w*32 + (lane >> 2);
    const int gc = (lane & 3) * 8;
    const u16* aP0 = A  + (size_t)(m0 + gr) * K + gc;
    const u16* bP0 = Bt + (size_t)(n0 + gr) * K + gc;
    const size_t r16 = (size_t)16 * K;

    GLDS16(&As[0][w*32][0],      aP0);
    GLDS16(&As[0][w*32 + 16][0], aP0 + r16);
    GLDS16(&Bs[0][w*32][0],      bP0);
    GLDS16(&Bs[0][w*32 + 16][0], bP0 + r16);
    __syncthreads();

    int cur = 0;
    for (int k0 = 0; k0 < K; k0 += 32) {
        const int nxt = k0 + 32;
        if (nxt < K) {
            GLDS16(&As[cur^1][w*32][0],      aP0 + nxt);
            GLDS16(&As[cur^1][w*32 + 16][0], aP0 + r16 + nxt);
            GLDS16(&Bs[cur^1][w*32][0],      bP0 + nxt);
            GLDS16(&Bs[cur^1][w*32 + 16][0], bP0 + r16 + nxt);
        }
        short8 af[4], bf[4];
        #pragma unroll
        for (int i = 0; i < 4; ++i) af[i] = *(const short8*)&As[cur][wm + i*16 + l15][lhi*8];
        #pragma unroll
        for (int i = 0; i < 4; ++i) bf[i] = *(const short8*)&Bs[cur][wn + i*16 + l15][lhi*8];
        #pragma unroll
        for (int a = 0; a < 4; ++a)
            #pragma unroll
            for (int b = 0; b < 4; ++b)
                acc[a][b] = MFMA_16x16x32(af[a], bf[b], acc[a][b]);
        __syncthreads();
        cur ^= 1;
    }
    #pragma unroll
    for (int a = 0; a < 4; ++a)
      #pragma unroll
      for (int b = 0; b < 4; ++b)
        #pragma unroll
        for (int r = 0; r < 4; ++r) {
            int m = m0 + wm + a*16 + lhi*4 + r;
            int n = n0 + wn + b*16 + l15;
            size_t off = (size_t)m * N + n;
            float v = acc[a][b][r];
            if (EPI == 0) ((u16*)C)[off] = f2b(v);
            else ((float*)C)[off] = v;
        }
}

// ------- Shared GLU GEMM (R6-proven): 128M x 64N dual, 3 blocks/CU ----------
__global__ __launch_bounds__(256) void k_glu_sh(
    const u16* __restrict__ Xb, const u16* __restrict__ W1t,
    const u16* __restrict__ W2t, u16* __restrict__ Hout,
    int M, int NE, int K)
{
    int bx = blockIdx.x, by = blockIdx.y, bz = blockIdx.z;
    xcd_swz(bx, by, bz);
    const int m0 = by * 128;
    const int n0 = bx * 64;

    __shared__ u16 As[2][128][32];
    __shared__ u16 B1s[2][64][32];
    __shared__ u16 B2s[2][64][32];

    const int tid = threadIdx.x, lane = tid & 63, w = tid >> 6;
    const int wm = (w >> 1) * 64, wn = (w & 1) * 32;
    const int l15 = lane & 15, lhi = lane >> 4;
    f32x4 acc1[4][2], acc2[4][2];
    #pragma unroll
    for (int a = 0; a < 4; ++a)
        #pragma unroll
        for (int j = 0; j < 2; ++j) { acc1[a][j] = 0; acc2[a][j] = 0; }

    const int gr  = w*32 + (lane >> 2);
    const int grB = w*16 + (lane >> 2);
    const int gc  = (lane & 3) * 8;
    const u16* aP0 = Xb  + (size_t)(m0 + gr) * K + gc;
    const u16* aP1 = Xb  + (size_t)(m0 + gr + 16) * K + gc;
    const u16* b1P = W1t + (size_t)(n0 + grB) * K + gc;
    const u16* b2P = W2t + (size_t)(n0 + grB) * K + gc;

    auto stage = [&](int bf, int kk) {
        GLDS16(&As[bf][w*32][0],      aP0 + kk);
        GLDS16(&As[bf][w*32 + 16][0], aP1 + kk);
        GLDS16(&B1s[bf][w*16][0],     b1P + kk);
        GLDS16(&B2s[bf][w*16][0],     b2P + kk);
    };

    stage(0, 0);
    __syncthreads();
    int cur = 0;
    for (int k0 = 0; k0 < K; k0 += 32) {
        const int nxt = k0 + 32;
        if (nxt < K) stage(cur ^ 1, nxt);
        short8 af[4], b1[2], b2[2];
        #pragma unroll
        for (int i = 0; i < 4; ++i) af[i] = *(const short8*)&As[cur][wm + i*16 + l15][lhi*8];
        #pragma unroll
        for (int j = 0; j < 2; ++j) {
            b1[j] = *(const short8*)&B1s[cur][wn + j*16 + l15][lhi*8];
            b2[j] = *(const short8*)&B2s[cur][wn + j*16 + l15][lhi*8];
        }
        #pragma unroll
        for (int a = 0; a < 4; ++a)
            #pragma unroll
            for (int j = 0; j < 2; ++j) {
                acc1[a][j] = MFMA_16x16x32(af[a], b1[j], acc1[a][j]);
                acc2[a][j] = MFMA_16x16x32(af[a], b2[j], acc2[a][j]);
            }
        __syncthreads();
        cur ^= 1;
    }
    #pragma unroll
    for (int a = 0; a < 4; ++a)
      #pragma unroll
      for (int j = 0; j < 2; ++j)
        #pragma unroll
        for (int r = 0; r < 4; ++r) {
            int m = m0 + wm + a*16 + lhi*4 + r;
            int n = n0 + wn + j*16 + l15;
            float g = acc1[a][j][r], u = acc2[a][j][r];
            float hval = g / (1.0f + __expf(-g)) * u;
            Hout[(size_t)m * NE + n] = f2b(hval);
        }
}

// ------- Routed GLU GEMM (R10): tile 256M x 64N dual, per-wave 128x(32+32) --
__global__ __launch_bounds__(256, 2) void k_glu_rt(
    const u16* __restrict__ Xb, const u16* __restrict__ W1t,
    const u16* __restrict__ W2t, u16* __restrict__ Hout,
    const int* __restrict__ list, const int* __restrict__ cntp,
    int NE, int K)
{
    int bx = blockIdx.x, by = blockIdx.y, bz = blockIdx.z;
    xcd_swz(bx, by, bz);
    const int e = bz;
    const int cnt = cntp[e];
    const int m0 = by * 256;
    if (m0 >= cnt) return;
    const int n0 = bx * 64;
    const u16* w1 = W1t + (size_t)e * NE * K;
    const u16* w2 = W2t + (size_t)e * NE * K;
    u16* hout = Hout + (size_t)e * CAP * NE;
    const int* lst = list + e * CAP;

    __shared__ u16 As[2][256][32];
    __shared__ u16 B1s[2][64][32];
    __shared__ u16 B2s[2][64][32];

    const int tid = threadIdx.x, lane = tid & 63, w = tid >> 6;
    const int wm = (w >> 1) * 128, wn = (w & 1) * 32;
    const int l15 = lane & 15, lhi = lane >> 4;
    f32x4 acc1[8][2], acc2[8][2];
    #pragma unroll
    for (int a = 0; a < 8; ++a)
        #pragma unroll
        for (int j = 0; j < 2; ++j) { acc1[a][j] = 0; acc2[a][j] = 0; }

    const int gr = lane >> 2;
    const int gc = (lane & 3) * 8;
    const u16* aP[4];
    #pragma unroll
    for (int j = 0; j < 4; ++j) {
        int mr = m0 + w*64 + j*16 + gr;
        int arow = (mr < cnt) ? (lst[mr] >> 3) : 0;
        aP[j] = Xb + (size_t)arow * K + gc;
    }
    const u16* b1P = w1 + (size_t)(n0 + w*16 + gr) * K + gc;
    const u16* b2P = w2 + (size_t)(n0 + w*16 + gr) * K + gc;

    auto stage = [&](int bf, int kk) {
        #pragma unroll
        for (int j = 0; j < 4; ++j)
            GLDS16(&As[bf][w*64 + j*16][0], aP[j] + kk);
        GLDS16(&B1s[bf][w*16][0], b1P + kk);
        GLDS16(&B2s[bf][w*16][0], b2P + kk);
    };

    stage(0, 0);
    __syncthreads();
    int cur = 0;
    for (int k0 = 0; k0 < K; k0 += 32) {
        const int nxt = k0 + 32;
        if (nxt < K) stage(cur ^ 1, nxt);
        short8 af[8], b1[2], b2[2];
        #pragma unroll
        for (int i = 0; i < 8; ++i) af[i] = *(const short8*)&As[cur][wm + i*16 + l15][lhi*8];
        #pragma unroll
        for (int j = 0; j < 2; ++j) {
            b1[j] = *(const short8*)&B1s[cur][wn + j*16 + l15][lhi*8];
            b2[j] = *(const short8*)&B2s[cur][wn + j*16 + l15][lhi*8];
        }
        #pragma unroll
        for (int a = 0; a < 8; ++a)
            #pragma unroll
            for (int j = 0; j < 2; ++j) {
                acc1[a][j] = MFMA_16x16x32(af[a], b1[j], acc1[a][j]);
                acc2[a][j] = MFMA_16x16x32(af[a], b2[j], acc2[a][j]);
            }
        __syncthreads();
        cur ^= 1;
    }
    #pragma unroll
    for (int a = 0; a < 8; ++a)
      #pragma unroll
      for (int j = 0; j < 2; ++j)
        #pragma unroll
        for (int r = 0; r < 4; ++r) {
            int m = m0 + wm + a*16 + lhi*4 + r;
            if (m < cnt) {
                int n = n0 + wn + j*16 + l15;
                float g = acc1[a][j][r], u = acc2[a][j][r];
                float hval = g / (1.0f + __expf(-g)) * u;
                hout[(size_t)m * NE + n] = f2b(hval);
            }
        }
}

// ------- Routed down GEMM (R10): tile 256x128, per-wave 128x64, scatter -----
__global__ __launch_bounds__(256, 2) void k_down_scatter(
    const u16* __restrict__ Hb, const u16* __restrict__ WdTt,
    u16* __restrict__ Rbuf, const int* __restrict__ list,
    const float* __restrict__ wts, const int* __restrict__ cntp,
    int N, int K)
{
    int bx = blockIdx.x, by = blockIdx.y, bz = blockIdx.z;
    xcd_swz(bx, by, bz);
    const int e = bz;
    const int cnt = cntp[e];
    const int m0 = by * 256;
    if (m0 >= cnt) return;
    const int n0 = bx * 128;
    const u16* A  = Hb   + (size_t)e * CAP * K;
    const u16* Bt = WdTt + (size_t)e * N * K;

    __shared__ u16 As[2][256][32];
    __shared__ u16 Bs[2][128][32];
    const int tid = threadIdx.x, lane = tid & 63, w = tid >> 6;
    const int wm = (w >> 1) * 128, wn = (w & 1) * 64;
    const int l15 = lane & 15, lhi = lane >> 4;
    f32x4 acc[8][4];
    #pragma unroll
    for (int a = 0; a < 8; ++a)
        #pragma unroll
        for (int b = 0; b < 4; ++b) acc[a][b] = 0;

    const int gr = lane >> 2;
    const int gc = (lane & 3) * 8;
    const u16* aP = A  + (size_t)(m0 + w*64 + gr) * K + gc;
    const u16* bP = Bt + (size_t)(n0 + w*32 + gr) * K + gc;
    const size_t r16 = (size_t)16 * K;

    auto stage = [&](int bf, int kk) {
        GLDS16(&As[bf][w*64][0],      aP + kk);
        GLDS16(&As[bf][w*64 + 16][0], aP + r16 + kk);
        GLDS16(&As[bf][w*64 + 32][0], aP + 2*r16 + kk);
        GLDS16(&As[bf][w*64 + 48][0], aP + 3*r16 + kk);
        GLDS16(&Bs[bf][w*32][0],      bP + kk);
        GLDS16(&Bs[bf][w*32 + 16][0], bP + r16 + kk);
    };

    stage(0, 0);
    __syncthreads();
    int cur = 0;
    for (int k0 = 0; k0 < K; k0 += 32) {
        const int nxt = k0 + 32;
        if (nxt < K) stage(cur ^ 1, nxt);
        short8 af[8], bf4[4];
        #pragma unroll
        for (int i = 0; i < 8; ++i) af[i] = *(const short8*)&As[cur][wm + i*16 + l15][lhi*8];
        #pragma unroll
        for (int i = 0; i < 4; ++i) bf4[i] = *(const short8*)&Bs[cur][wn + i*16 + l15][lhi*8];
        #pragma unroll
        for (int a = 0; a < 8; ++a)
            #pragma unroll
            for (int b = 0; b < 4; ++b)
                acc[a][b] = MFMA_16x16x32(af[a], bf4[b], acc[a][b]);
        __syncthreads();
        cur ^= 1;
    }
    #pragma unroll
    for (int a = 0; a < 8; ++a)
      #pragma unroll
      for (int b = 0; b < 4; ++b)
        #pragma unroll
        for (int r = 0; r < 4; ++r) {
            int m = m0 + wm + a*16 + lhi*4 + r;
            if (m < cnt) {
                int n = n0 + wn + b*16 + l15;
                int enc = list[e*CAP + m];
                float wgt = wts[e*CAP + m];
                int tok = enc >> 3, kk = enc & 7;
                Rbuf[((size_t)tok*NTOP + kk)*N + n] = f2b(acc[a][b][r] * wgt);
            }
        }
}

// -------- Fused RoPE+split (q,k) AND V^T split, single launch ---------------
__global__ __launch_bounds__(256) void k_rope_vt(
    const float* __restrict__ QKV,
    const float* __restrict__ Cs, const float* __restrict__ Sn,
    u16* __restrict__ Qh, u16* __restrict__ Ql,
    u16* __restrict__ Kh, u16* __restrict__ Kl,
    u16* __restrict__ Vth, u16* __restrict__ Vtl)
{
    int id = blockIdx.x * 256 + threadIdx.x;
    if (id < TT*20*64) {
        int pr = id & 63;
        int rest = id >> 6;
        int hh = rest % 20;
        int tok = rest / 20;
        int d0 = pr * 2;
        float c0 = Cs[(size_t)tok*HDD + d0];
        float c1 = Cs[(size_t)tok*HDD + d0 + 1];
        float s0 = Sn[(size_t)tok*HDD + d0];
        float s1 = Sn[(size_t)tok*HDD + d0 + 1];
        const float* p = QKV + (size_t)tok*3072 + (hh < HH ? hh*HDD : 2048 + (hh - HH)*HDD);
        float x0 = p[d0], x1 = p[d0+1];
        float y0 = x0*c0 - x1*s0;
        float y1 = x1*c1 + x0*s1;
        u16 *oh, *ol;
        size_t ooff;
        if (hh < HH) { ooff = ((size_t)tok*HH + hh)*HDD + d0; oh = Qh; ol = Ql; }
        else         { ooff = ((size_t)tok*HKK + (hh - HH))*HDD + d0; oh = Kh; ol = Kl; }
        fsplit(y0, oh[ooff],     ol[ooff]);
        fsplit(y1, oh[ooff + 1], ol[ooff + 1]);
    } else {
        int vid = id - TT*20*64;       // 0 .. TT*HKK*HDD/8 - 1
        int oid = vid * 8;
        int s0 = oid & (SS - 1);
        int r = oid >> 10;
        int d = r & (HDD - 1);
        int bh = r >> 7;
        int b = bh >> 2, hk = bh & 3;
        #pragma unroll
        for (int j = 0; j < 8; ++j) {
            int s = s0 + j;
            float v = QKV[(size_t)(b*SS + s)*3072 + 2560 + hk*HDD + d];
            fsplit(v, Vth[oid + j], Vtl[oid + j]);
        }
    }
}

// ---------------- Flash attention, split-bf16 precision ---------------------
__global__ __launch_bounds__(256) void k_attn_hi(
    const u16* __restrict__ Qh, const u16* __restrict__ Ql,
    const u16* __restrict__ Kh, const u16* __restrict__ Kl,
    const u16* __restrict__ Vth, const u16* __restrict__ Vtl,
    u16* __restrict__ Oh, u16* __restrict__ Ol)
{
    const int tid = threadIdx.x;
    const int lane = tid & 63;
    const int w = tid >> 6;
    const int q0 = blockIdx.x * 64;
    const int b = blockIdx.y >> 4;
    const int h = blockIdx.y & 15;
    const int hk = h >> 2;
    const int l15 = lane & 15, lhi = lane >> 4;

    __shared__ u16 Ksh[32][136];
    __shared__ u16 Ksl[32][136];
    __shared__ u16 Vsh[128][40];
    __shared__ u16 Vsl[128][40];
    __shared__ u16 Psh[4][16][40];
    __shared__ u16 Psl[4][16][40];

    short8 qfh[4], qfl[4];
    {
        const int qrow = q0 + w*16 + l15;
        const u16* qph = Qh + ((size_t)(b*SS + qrow)*HH + h)*HDD;
        const u16* qpl = Ql + ((size_t)(b*SS + qrow)*HH + h)*HDD;
        #pragma unroll
        for (int c = 0; c < 4; ++c) {
            qfh[c] = *(const short8*)(qph + c*32 + lhi*8);
            qfl[c] = *(const short8*)(qpl + c*32 + lhi*8);
        }
    }

    f32x4 oacc[8];
    #pragma unroll
    for (int ch = 0; ch < 8; ++ch) oacc[ch] = 0;
    float m_r[4] = {-1e30f, -1e30f, -1e30f, -1e30f};
    float l_r[4] = {0.f, 0.f, 0.f, 0.f};

    const int nkt = (q0 + 64) >> 5;
    const int kr = tid >> 3, kc = (tid & 7) * 16;
    const int vd = tid >> 1, vj = (tid & 1) * 16;

    for (int kt = 0; kt < nkt; ++kt) {
        __syncthreads();
        {
            size_t koff = ((size_t)(b*SS + kt*32 + kr)*HKK + hk)*HDD + kc;
            *(short8*)&Ksh[kr][kc]     = *(const short8*)(Kh + koff);
            *(short8*)&Ksh[kr][kc + 8] = *(const short8*)(Kh + koff + 8);
            *(short8*)&Ksl[kr][kc]     = *(const short8*)(Kl + koff);
            *(short8*)&Ksl[kr][kc + 8] = *(const short8*)(Kl + koff + 8);
        }
        {
            size_t voff = ((size_t)(b*HKK + hk)*HDD + vd)*SS + kt*32 + vj;
            *(short8*)&Vsh[vd][vj]     = *(const short8*)(Vth + voff);
            *(short8*)&Vsh[vd][vj + 8] = *(const short8*)(Vth + voff + 8);
            *(short8*)&Vsl[vd][vj]     = *(const short8*)(Vtl + voff);
            *(short8*)&Vsl[vd][vj + 8] = *(const short8*)(Vtl + voff + 8);
        }
        __syncthreads();

        f32x4 s0 = 0, s1 = 0;
        #pragma unroll
        for (int c = 0; c < 4; ++c) {
            short8 kh0 = *(const short8*)&Ksh[l15][c*32 + lhi*8];
            short8 kl0 = *(const short8*)&Ksl[l15][c*32 + lhi*8];
            short8 kh1 = *(const short8*)&Ksh[16 + l15][c*32 + lhi*8];
            short8 kl1 = *(const short8*)&Ksl[16 + l15][c*32 + lhi*8];
            s0 = MFMA_16x16x32(qfh[c], kh0, s0);
            s0 = MFMA_16x16x32(qfh[c], kl0, s0);
            s0 = MFMA_16x16x32(qfl[c], kh0, s0);
            s1 = MFMA_16x16x32(qfh[c], kh1, s1);
            s1 = MFMA_16x16x32(qfh[c], kl1, s1);
            s1 = MFMA_16x16x32(qfl[c], kh1, s1);
        }
        const int irow0 = q0 + w*16 + lhi*4;
        const int j0 = kt*32 + l15;
        float ef[4];
        #pragma unroll
        for (int r = 0; r < 4; ++r) {
            float a0 = s0[r] * 0.08838834764831845f;
            float a1 = s1[r] * 0.08838834764831845f;
            const int ir = irow0 + r;
            if (j0 > ir) a0 = -1e30f;
            if (j0 + 16 > ir) a1 = -1e30f;
            float mx = fmaxf(a0, a1);
            #pragma unroll
            for (int o = 1; o < 16; o <<= 1) mx = fmaxf(mx, __shfl_xor(mx, o));
            float mn = fmaxf(m_r[r], mx);
            ef[r] = __expf(m_r[r] - mn);
            m_r[r] = mn;
            float p0 = __expf(a0 - mn);
            float p1 = __expf(a1 - mn);
            float ps = p0 + p1;
            #pragma unroll
            for (int o = 1; o < 16; o <<= 1) ps += __shfl_xor(ps, o);
            l_r[r] = l_r[r]*ef[r] + ps;
            fsplit(p0, Psh[w][lhi*4 + r][l15],      Psl[w][lhi*4 + r][l15]);
            fsplit(p1, Psh[w][lhi*4 + r][16 + l15], Psl[w][lhi*4 + r][16 + l15]);
        }
        #pragma unroll
        for (int ch = 0; ch < 8; ++ch) {
            f32x4 t = oacc[ch];
            t[0] *= ef[0]; t[1] *= ef[1]; t[2] *= ef[2]; t[3] *= ef[3];
            oacc[ch] = t;
        }
        __syncthreads();
        short8 pah = *(const short8*)&Psh[w][l15][lhi*8];
        short8 pal = *(const short8*)&Psl[w][l15][lhi*8];
        #pragma unroll
        for (int ch = 0; ch < 8; ++ch) {
            short8 bvh = *(const short8*)&Vsh[ch*16 + l15][lhi*8];
            short8 bvl = *(const short8*)&Vsl[ch*16 + l15][lhi*8];
            oacc[ch] = MFMA_16x16x32(pah, bvh, oacc[ch]);
            oacc[ch] = MFMA_16x16x32(pah, bvl, oacc[ch]);
            oacc[ch] = MFMA_16x16x32(pal, bvh, oacc[ch]);
        }
    }
    #pragma unroll
    for (int r = 0; r < 4; ++r) {
        const int row = q0 + w*16 + lhi*4 + r;
        const float inv = 1.0f / l_r[r];
        u16* oph = Oh + ((size_t)(b*SS + row)*HH + h)*HDD;
        u16* opl = Ol + ((size_t)(b*SS + row)*HH + h)*HDD;
        #pragma unroll
        for (int ch = 0; ch < 8; ++ch) {
            float o = oacc[ch][r] * inv;
            fsplit(o, oph[ch*16 + l15], opl[ch*16 + l15]);
        }
    }
}

// ---------------- Router: f32 logits, softmax, top-6, slot lists ------------
__global__ __launch_bounds__(256) void k_router(
    const float* __restrict__ X, const float* __restrict__ Wg,
    const float* __restrict__ bias,
    int* __restrict__ cnt, int* __restrict__ list, float* __restrict__ wts)
{
    const int t = blockIdx.x;
    const int e = threadIdx.x & 15, sl = threadIdx.x >> 4;
    const float* x = X + (size_t)t * DD;
    float part = 0.f;
    for (int i = 0; i < 128; ++i) {
        int k = sl * 128 + i;
        part += x[k] * Wg[(size_t)k * EE + e];
    }
    __shared__ float red[16][17];
    red[sl][e] = part;
    __syncthreads();
    if (threadIdx.x == 0) {
        float lg[16], pr[16];
        for (int ee = 0; ee < 16; ++ee) {
            float s = 0.f;
            for (int q = 0; q < 16; ++q) s += red[q][ee];
            lg[ee] = s;
        }
        float mx = lg[0];
        for (int ee = 1; ee < 16; ++ee) mx = fmaxf(mx, lg[ee]);
        float sum = 0.f;
        for (int ee = 0; ee < 16; ++ee) { pr[ee] = expf(lg[ee] - mx); sum += pr[ee]; }
        float isum = 1.0f / sum;
        for (int ee = 0; ee < 16; ++ee) pr[ee] *= isum;
        unsigned used = 0;
        int sel[NTOP]; float rw[NTOP]; float s6 = 0.f;
        for (int kk = 0; kk < NTOP; ++kk) {
            int best = 0; float bv = -1e30f;
            for (int ee = 0; ee < 16; ++ee) {
                if (used & (1u << ee)) continue;
                float sc = pr[ee] + bias[ee];
                if (sc > bv) { bv = sc; best = ee; }
            }
            used |= 1u << best;
            sel[kk] = best; rw[kk] = pr[best]; s6 += pr[best];
        }
        float inv6 = 1.0f / fmaxf(s6, 1e-12f);
        for (int kk = 0; kk < NTOP; ++kk) {
            int ee = sel[kk];
            int pos = atomicAdd(&cnt[ee], 1);
            list[ee*CAP + pos] = (t << 3) | kk;
            wts[ee*CAP + pos] = rw[kk] * inv6;
        }
    }
}

// ---------------- Final: out = h2 + shared + sum_kk routed ------------------
__global__ __launch_bounds__(256) void k_final(
    const float* __restrict__ h2, const float* __restrict__ yb,
    const u16* __restrict__ rb, float* __restrict__ out)
{
    int id = blockIdx.x * 256 + threadIdx.x;     // T*D/4
    size_t i4 = (size_t)id * 4;
    int t = id >> 9;
    int d = (id & 511) * 4;
    f32x4 acc = *(const f32x4*)(h2 + i4);
    f32x4 y = *(const f32x4*)(yb + i4);
    acc += y;
    #pragma unroll
    for (int kk = 0; kk < NTOP; ++kk) {
        s16x4 rv = *(const s16x4*)(rb + ((size_t)t*NTOP + kk)*DD + d);
        acc[0] += b2f((u16)rv[0]); acc[1] += b2f((u16)rv[1]);
        acc[2] += b2f((u16)rv[2]); acc[3] += b2f((u16)rv[3]);
    }
    *(f32x4*)(out + i4) = acc;
}

extern "C" void kernel_launch(void* const* d_in, const int* in_sizes, int n_in,
                              void* d_out, int out_size, void* d_ws, size_t ws_size,
                              hipStream_t stream)
{
    (void)in_sizes; (void)n_in; (void)out_size; (void)ws_size;
    const float* hidden = (const float*)d_in[0];
    const float* cosb   = (const float*)d_in[1];
    const float* sinb   = (const float*)d_in[2];
    const float* ln1    = (const float*)d_in[3];
    const float* ln2    = (const float*)d_in[4];
    const float* Wq     = (const float*)d_in[5];
    const float* Wk     = (const float*)d_in[6];
    const float* Wv     = (const float*)d_in[7];
    const float* Wo     = (const float*)d_in[8];
    const float* Wgate  = (const float*)d_in[9];
    const float* cbias  = (const float*)d_in[10];
    const float* Wg     = (const float*)d_in[11];
    const float* Wu     = (const float*)d_in[12];
    const float* Wd     = (const float*)d_in[13];
    const float* Wgs    = (const float*)d_in[14];
    const float* Wus    = (const float*)d_in[15];
    const float* Wds    = (const float*)d_in[16];
    float* out = (float*)d_out;

    char* ws = (char*)d_ws;
    size_t off = 0;
    auto alloc = [&](size_t bytes) {
        void* p = ws + off;
        off = (off + bytes + 255) & ~(size_t)255;
        return p;
    };
    // Pre-transposed bf16 weights
    u16* WqkvTh = (u16*)alloc((size_t)3072*2048*2);
    u16* WqkvTl = (u16*)alloc((size_t)3072*2048*2);
    u16* WoTh   = (u16*)alloc((size_t)2048*2048*2);
    u16* WoTl   = (u16*)alloc((size_t)2048*2048*2);
    u16* WgsT   = (u16*)alloc((size_t)2048*2048*2);
    u16* WusT   = (u16*)alloc((size_t)2048*2048*2);
    u16* WdsT   = (u16*)alloc((size_t)2048*2048*2);
    u16* WgT    = (u16*)alloc((size_t)EE*II*DD*2);
    u16* WuT    = (u16*)alloc((size_t)EE*II*DD*2);
    u16* WdT    = (u16*)alloc((size_t)EE*DD*II*2);
    // Activations
    u16*   x1h  = (u16*)  alloc((size_t)TT*DD*2);
    u16*   x1l  = (u16*)  alloc((size_t)TT*DD*2);
    float* qkvf = (float*)alloc((size_t)TT*3072*4);
    u16*   qh   = (u16*)  alloc((size_t)TT*HH*HDD*2);
    u16*   ql   = (u16*)  alloc((size_t)TT*HH*HDD*2);
    u16*   kh   = (u16*)  alloc((size_t)TT*HKK*HDD*2);
    u16*   kl   = (u16*)  alloc((size_t)TT*HKK*HDD*2);
    u16*   vth  = (u16*)  alloc((size_t)TT*HKK*HDD*2);
    u16*   vtl  = (u16*)  alloc((size_t)TT*HKK*HDD*2);
    u16*   aoh  = (u16*)  alloc((size_t)TT*HH*HDD*2);
    u16*   aol  = (u16*)  alloc((size_t)TT*HH*HDD*2);
    float* h2   = (float*)alloc((size_t)TT*DD*4);
    u16*   x2   = (u16*)  alloc((size_t)TT*DD*2);
    float* x2f  = (float*)alloc((size_t)TT*DD*4);
    int*   cnt  = (int*)  alloc(256);
    int*   lst  = (int*)  alloc((size_t)EE*CAP*4);
    float* wts  = (float*)alloc((size_t)EE*CAP*4);
    u16*   hE   = (u16*)  alloc((size_t)EE*CAP*II*2);
    u16*   rbuf = (u16*)  alloc((size_t)TT*NTOP*DD*2);
    // Aliases (lifetimes disjoint):
    u16*   hs   = x1h;            // [TT][ISS] bf16 = 8MB, x1h dead after QKV
    float* ybuf = qkvf;           // [TT][DD] f32 = 16MB, qkvf dead after splits

    // ---- Weight prep (transpose + bf16 convert [+ split]), 64x64 tiles ----
    k_prep<true ><<<dim3(32,32,1), 256, 0, stream>>>(Wq, WqkvTh, WqkvTl, 2048, 2048);
    k_prep<true ><<<dim3(8, 32,1), 256, 0, stream>>>(Wk, WqkvTh + (size_t)2048*2048, WqkvTl + (size_t)2048*2048, 2048, 512);
    k_prep<true ><<<dim3(8, 32,1), 256, 0, stream>>>(Wv, WqkvTh + (size_t)2560*2048, WqkvTl + (size_t)2560*2048, 2048, 512);
    k_prep<true ><<<dim3(32,32,1), 256, 0, stream>>>(Wo, WoTh, WoTl, 2048, 2048);
    k_prep<false><<<dim3(32,32,1), 256, 0, stream>>>(Wgs, WgsT, nullptr, 2048, 2048);
    k_prep<false><<<dim3(32,32,1), 256, 0, stream>>>(Wus, WusT, nullptr, 2048, 2048);
    k_prep<false><<<dim3(32,32,1), 256, 0, stream>>>(Wds, WdsT, nullptr, 2048, 2048);
    k_prep<false><<<dim3(16,32,EE), 256, 0, stream>>>(Wg, WgT, nullptr, 2048, 1024);
    k_prep<false><<<dim3(16,32,EE), 256, 0, stream>>>(Wu, WuT, nullptr, 2048, 1024);
    k_prep<false><<<dim3(32,16,EE), 256, 0, stream>>>(Wd, WdT, nullptr, 1024, 2048);

    // ---- Attention path (split-bf16 high precision) ----
    k_rmsnorm_split<<<TT, 256, 0, stream>>>(hidden, ln1, x1h, x1l);
    k_gemm_hi<2><<<dim3(24,16), 256, 0, stream>>>(x1h, x1l, WqkvTh, WqkvTl, qkvf, nullptr, TT, 3072, DD);
    k_rope_vt<<<(TT*20*64 + TT*HKK*HDD/8)/256, 256, 0, stream>>>(qkvf, cosb, sinb, qh, ql, kh, kl, vth, vtl);
    k_attn_hi<<<dim3(SS/64, BB*HH), 256, 0, stream>>>(qh, ql, kh, kl, vth, vtl, aoh, aol);
    k_gemm_hi<1><<<dim3(16,16), 256, 0, stream>>>(aoh, aol, WoTh, WoTl, h2, hidden, TT, DD, HH*HDD);

    // ---- MoE path ----
    k_rmsnorm_bf<<<TT, 256, 0, stream>>>(h2, ln2, x2, x2f);
    (void)hipMemsetAsync(cnt, 0, 256, stream);
    k_router<<<TT, 256, 0, stream>>>(x2f, Wgate, cbias, cnt, lst, wts);
    k_glu_sh<<<dim3(ISS/64, TT/128), 256, 0, stream>>>(x2, WgsT, WusT, hs, TT, ISS, DD);
    k_gemm<2><<<dim3(DD/128, TT/128), 256, 0, stream>>>(hs, WdsT, ybuf, TT, DD, ISS);
    k_glu_rt<<<dim3(II/64, CAP/256, EE), 256, 0, stream>>>(x2, WgT, WuT, hE, lst, cnt, II, DD);
    k_down_scatter<<<dim3(DD/128, CAP/256, EE), 256, 0, stream>>>(hE, WdT, rbuf, lst, wts, cnt, DD, II);
    k_final<<<(TT*DD/4)/256, 256, 0, stream>>>(h2, ybuf, rbuf, out);
}

// Round 13
// 1105.371 us; speedup vs baseline: 1.3493x; 1.0194x over previous
//
#include <hip/hip_runtime.h>
#include <cstdint>

typedef unsigned short u16;
typedef __attribute__((ext_vector_type(8))) short short8;
typedef __attribute__((ext_vector_type(4))) short s16x4;
typedef __attribute__((ext_vector_type(4))) float f32x4;

#define MFMA_16x16x32(a,b,c) __builtin_amdgcn_mfma_f32_16x16x32_bf16(a,b,c,0,0,0)

// async global->LDS, 16B per lane, wave covers 1024B (16 rows of a [*][32] bf16 tile)
#define GLDS16(lds, g) __builtin_amdgcn_global_load_lds( \
    (const __attribute__((address_space(1))) unsigned int*)(g), \
    (__attribute__((address_space(3))) unsigned int*)(lds), 16, 0, 0)

#define BB 2
#define SS 1024
#define DD 2048
#define HH 16
#define HKK 4
#define HDD 128
#define EE 16
#define NTOP 6
#define II 1024
#define ISS 2048
#define TT 2048
#define CAP 2048

__device__ __forceinline__ u16 f2b(float f) {
    union { float f; uint32_t u; } v; v.f = f;
    uint32_t r = v.u + 0x7FFFu + ((v.u >> 16) & 1u);
    return (u16)(r >> 16);
}
__device__ __forceinline__ float b2f(u16 h) {
    union { uint32_t u; float f; } v; v.u = ((uint32_t)h) << 16;
    return v.f;
}
__device__ __forceinline__ void fsplit(float f, u16& hi, u16& lo) {
    u16 h = f2b(f);
    hi = h;
    lo = f2b(f - b2f(h));
}

// T1: bijective chunked XCD swizzle (m204).
__device__ __forceinline__ void xcd_swz(int& bx, int& by, int& bz) {
    const int gx = gridDim.x, gy = gridDim.y;
    const int n = gx * gy * gridDim.z;
    int lid = bx + gx * (by + gy * bz);
    int q = n >> 3, r = n & 7;
    int xcd = lid & 7, idx = lid >> 3;
    int nid = (xcd < r ? xcd * (q + 1) : r * (q + 1) + (xcd - r) * q) + idx;
    bx = nid % gx;
    int t = nid / gx;
    by = t % gy;
    bz = t / gy;
}

// T2-lite bank swizzle for [*][32]-u16 LDS tiles (rule #21: both-sides).
// LDS slot (row, c16) holds global (row, c16 ^ (row&3)).
// Staging (gload_lds, linear dest): lane l covers row chunk+l>>2, c16 l&3
//   -> global source c16 = (l&3) ^ ((l>>2)&3)   [per-lane constant]
// Fragment read of logical c16 `lhi` at row ..+l15
//   -> physical c16 = lhi ^ (l15&3)              [per-lane constant]
#define GSWZ(lane)      ((((lane) & 3) ^ (((lane) >> 2) & 3)) * 8)
#define FSWZ(lhi, l15)  ((((lhi) ^ ((l15) & 3))) * 8)

// ---- Prep: transpose+convert W f32 [R][C] -> bf16 [C][R] (hi[,lo]) ---------
template<bool SPLIT>
__global__ __launch_bounds__(256) void k_prep(
    const float* __restrict__ In, u16* __restrict__ Oh, u16* __restrict__ Ol,
    int R, int C)
{
    const size_t zoff = (size_t)blockIdx.z * R * C;
    In += zoff; Oh += zoff; if (SPLIT) Ol += zoff;
    const int r0 = blockIdx.y * 64, c0 = blockIdx.x * 64;
    __shared__ float tile[64][65];
    const int tx = threadIdx.x & 15, ty = threadIdx.x >> 4;   // 16 x 16
    #pragma unroll
    for (int i = 0; i < 4; ++i) {
        f32x4 v = *(const f32x4*)(In + (size_t)(r0 + ty + i*16)*C + c0 + tx*4);
        tile[ty + i*16][tx*4 + 0] = v[0];
        tile[ty + i*16][tx*4 + 1] = v[1];
        tile[ty + i*16][tx*4 + 2] = v[2];
        tile[ty + i*16][tx*4 + 3] = v[3];
    }
    __syncthreads();
    const int c = threadIdx.x >> 2;          // 0..63
    const int rs = (threadIdx.x & 3) * 16;   // 0,16,32,48
    short8 hv0, hv1, lv0, lv1;
    #pragma unroll
    for (int j = 0; j < 8; ++j) {
        float f = tile[rs + j][c];
        u16 hb = f2b(f);
        hv0[j] = (short)hb;
        lv0[j] = SPLIT ? (short)f2b(f - b2f(hb)) : (short)0;
    }
    #pragma unroll
    for (int j = 0; j < 8; ++j) {
        float f = tile[rs + 8 + j][c];
        u16 hb = f2b(f);
        hv1[j] = (short)hb;
        lv1[j] = SPLIT ? (short)f2b(f - b2f(hb)) : (short)0;
    }
    u16* po = Oh + (size_t)(c0 + c)*R + r0 + rs;
    *(short8*)po       = hv0;
    *(short8*)(po + 8) = hv1;
    if (SPLIT) {
        u16* pl = Ol + (size_t)(c0 + c)*R + r0 + rs;
        *(short8*)pl       = lv0;
        *(short8*)(pl + 8) = lv1;
    }
}

// ---------------- RMSNorm f32 in -> split bf16 (hi,lo) ----------------------
__global__ __launch_bounds__(256) void k_rmsnorm_split(
    const float* __restrict__ X, const float* __restrict__ Wt,
    u16* __restrict__ Oh, u16* __restrict__ Ol)
{
    const int t = blockIdx.x;
    const float* x = X + (size_t)t * DD;
    const int base = threadIdx.x * 8;
    f32x4 v0 = *(const f32x4*)(x + base);
    f32x4 v1 = *(const f32x4*)(x + base + 4);
    float ss = 0.f;
    #pragma unroll
    for (int j = 0; j < 4; ++j) ss += v0[j]*v0[j] + v1[j]*v1[j];
    #pragma unroll
    for (int o = 1; o < 64; o <<= 1) ss += __shfl_xor(ss, o);
    __shared__ float red[4];
    if ((threadIdx.x & 63) == 0) red[threadIdx.x >> 6] = ss;
    __syncthreads();
    float tot = red[0] + red[1] + red[2] + red[3];
    float inv = rsqrtf(tot * (1.0f/DD) + 1e-6f);
    f32x4 w0 = *(const f32x4*)(Wt + base);
    f32x4 w1 = *(const f32x4*)(Wt + base + 4);
    u16* oh = Oh + (size_t)t*DD + base;
    u16* ol = Ol + (size_t)t*DD + base;
    #pragma unroll
    for (int j = 0; j < 4; ++j) {
        float y0 = v0[j]*inv*w0[j];
        float y1 = v1[j]*inv*w1[j];
        fsplit(y0, oh[j],   ol[j]);
        fsplit(y1, oh[4+j], ol[4+j]);
    }
}

// ---------------- RMSNorm f32 in -> bf16 + f32 ------------------------------
__global__ __launch_bounds__(256) void k_rmsnorm_bf(
    const float* __restrict__ X, const float* __restrict__ Wt,
    u16* __restrict__ Ob, float* __restrict__ Of)
{
    const int t = blockIdx.x;
    const float* x = X + (size_t)t * DD;
    const int base = threadIdx.x * 8;
    f32x4 v0 = *(const f32x4*)(x + base);
    f32x4 v1 = *(const f32x4*)(x + base + 4);
    float ss = 0.f;
    #pragma unroll
    for (int j = 0; j < 4; ++j) ss += v0[j]*v0[j] + v1[j]*v1[j];
    #pragma unroll
    for (int o = 1; o < 64; o <<= 1) ss += __shfl_xor(ss, o);
    __shared__ float red[4];
    if ((threadIdx.x & 63) == 0) red[threadIdx.x >> 6] = ss;
    __syncthreads();
    float tot = red[0] + red[1] + red[2] + red[3];
    float inv = rsqrtf(tot * (1.0f/DD) + 1e-6f);
    f32x4 w0 = *(const f32x4*)(Wt + base);
    f32x4 w1 = *(const f32x4*)(Wt + base + 4);
    u16* ob = Ob + (size_t)t*DD + base;
    float* of = Of + (size_t)t*DD + base;
    #pragma unroll
    for (int j = 0; j < 4; ++j) {
        float y0 = v0[j]*inv*w0[j];
        float y1 = v1[j]*inv*w1[j];
        ob[j] = f2b(y0); ob[4+j] = f2b(y1);
        of[j] = y0;      of[4+j] = y1;
    }
}

// ------- High-precision GEMM: C = (Ah+Al) @ (Bh+Bl)^T, pre-split bf16 -------
// 2-phase prefetch, dbuf LDS, bank-swizzled. EPI 1: f32 + residual; 2: f32
template<int EPI>
__global__ __launch_bounds__(256) void k_gemm_hi(
    const u16* __restrict__ Ah, const u16* __restrict__ Al,
    const u16* __restrict__ Bth, const u16* __restrict__ Btl,
    float* __restrict__ C, const float* __restrict__ Res,
    int M, int N, int K)
{
    __shared__ u16 Ash[2][128][32];
    __shared__ u16 Asl[2][128][32];
    __shared__ u16 Bsh[2][128][32];
    __shared__ u16 Bsl[2][128][32];
    int bx = blockIdx.x, by = blockIdx.y, bz = blockIdx.z;
    xcd_swz(bx, by, bz);
    const int tid = threadIdx.x;
    const int lane = tid & 63;
    const int w = tid >> 6;
    const int m0 = by * 128, n0 = bx * 128;
    const int wm = (w >> 1) * 64, wn = (w & 1) * 64;
    const int l15 = lane & 15, lhi = lane >> 4;
    f32x4 acc[4][4];
    #pragma unroll
    for (int a = 0; a < 4; ++a)
        #pragma unroll
        for (int b = 0; b < 4; ++b) acc[a][b] = 0;

    const int gr = w*32 + (lane >> 2);
    const int gc = GSWZ(lane);
    const int fsA = FSWZ(lhi, l15);
    const u16* ahP0 = Ah  + (size_t)(m0 + gr) * K + gc;
    const u16* alP0 = Al  + (size_t)(m0 + gr) * K + gc;
    const u16* bhP0 = Bth + (size_t)(n0 + gr) * K + gc;
    const u16* blP0 = Btl + (size_t)(n0 + gr) * K + gc;
    const size_t r16 = (size_t)16 * K;

    GLDS16(&Ash[0][w*32][0],      ahP0);
    GLDS16(&Ash[0][w*32 + 16][0], ahP0 + r16);
    GLDS16(&Asl[0][w*32][0],      alP0);
    GLDS16(&Asl[0][w*32 + 16][0], alP0 + r16);
    GLDS16(&Bsh[0][w*32][0],      bhP0);
    GLDS16(&Bsh[0][w*32 + 16][0], bhP0 + r16);
    GLDS16(&Bsl[0][w*32][0],      blP0);
    GLDS16(&Bsl[0][w*32 + 16][0], blP0 + r16);
    __syncthreads();

    int cur = 0;
    for (int k0 = 0; k0 < K; k0 += 32) {
        const int nxt = k0 + 32;
        if (nxt < K) {
            GLDS16(&Ash[cur^1][w*32][0],      ahP0 + nxt);
            GLDS16(&Ash[cur^1][w*32 + 16][0], ahP0 + r16 + nxt);
            GLDS16(&Asl[cur^1][w*32][0],      alP0 + nxt);
            GLDS16(&Asl[cur^1][w*32 + 16][0], alP0 + r16 + nxt);
            GLDS16(&Bsh[cur^1][w*32][0],      bhP0 + nxt);
            GLDS16(&Bsh[cur^1][w*32 + 16][0], bhP0 + r16 + nxt);
            GLDS16(&Bsl[cur^1][w*32][0],      blP0 + nxt);
            GLDS16(&Bsl[cur^1][w*32 + 16][0], blP0 + r16 + nxt);
        }
        short8 afh[4], afl[4], bfh[4], bfl[4];
        #pragma unroll
        for (int i = 0; i < 4; ++i) {
            afh[i] = *(const short8*)&Ash[cur][wm + i*16 + l15][fsA];
            afl[i] = *(const short8*)&Asl[cur][wm + i*16 + l15][fsA];
            bfh[i] = *(const short8*)&Bsh[cur][wn + i*16 + l15][fsA];
            bfl[i] = *(const short8*)&Bsl[cur][wn + i*16 + l15][fsA];
        }
        #pragma unroll
        for (int a = 0; a < 4; ++a)
            #pragma unroll
            for (int b = 0; b < 4; ++b) {
                acc[a][b] = MFMA_16x16x32(afh[a], bfh[b], acc[a][b]);
                acc[a][b] = MFMA_16x16x32(afh[a], bfl[b], acc[a][b]);
                acc[a][b] = MFMA_16x16x32(afl[a], bfh[b], acc[a][b]);
            }
        __syncthreads();
        cur ^= 1;
    }
    #pragma unroll
    for (int a = 0; a < 4; ++a)
      #pragma unroll
      for (int b = 0; b < 4; ++b)
        #pragma unroll
        for (int r = 0; r < 4; ++r) {
            int m = m0 + wm + a*16 + lhi*4 + r;
            int n = n0 + wn + b*16 + l15;
            size_t off = (size_t)m * N + n;
            float v = acc[a][b][r];
            if (EPI == 1) C[off] = v + Res[off];
            else C[off] = v;
        }
}

// ---------------- Dense GEMM: C(MxN) = A_bf16 @ Bt_bf16^T, 2-phase ----------
// EPI 0: bf16 store; 2: f32 store
template<int EPI>
__global__ __launch_bounds__(256) void k_gemm(
    const u16* __restrict__ A, const u16* __restrict__ Bt,
    void* __restrict__ C, int M, int N, int K)
{
    __shared__ u16 As[2][128][32];
    __shared__ u16 Bs[2][128][32];
    int bx = blockIdx.x, by = blockIdx.y, bz = blockIdx.z;
    xcd_swz(bx, by, bz);
    const int tid = threadIdx.x;
    const int lane = tid & 63;
    const int w = tid >> 6;
    const int m0 = by * 128, n0 = bx * 128;
    const int wm = (w >> 1) * 64, wn = (w & 1) * 64;
    const int l15 = lane & 15, lhi = lane >> 4;
    f32x4 acc[4][4];
    #pragma unroll
    for (int a = 0; a < 4; ++a)
        #pragma unroll
        for (int b = 0; b < 4; ++b) acc[a][b] = 0;

    const int gr = w*32 + (lane >> 2);
    const int gc = GSWZ(lane);
    const int fsA = FSWZ(lhi, l15);
    const u16* aP0 = A  + (size_t)(m0 + gr) * K + gc;
    const u16* bP0 = Bt + (size_t)(n0 + gr) * K + gc;
    const size_t r16 = (size_t)16 * K;

    GLDS16(&As[0][w*32][0],      aP0);
    GLDS16(&As[0][w*32 + 16][0], aP0 + r16);
    GLDS16(&Bs[0][w*32][0],      bP0);
    GLDS16(&Bs[0][w*32 + 16][0], bP0 + r16);
    __syncthreads();

    int cur = 0;
    for (int k0 = 0; k0 < K; k0 += 32) {
        const int nxt = k0 + 32;
        if (nxt < K) {
            GLDS16(&As[cur^1][w*32][0],      aP0 + nxt);
            GLDS16(&As[cur^1][w*32 + 16][0], aP0 + r16 + nxt);
            GLDS16(&Bs[cur^1][w*32][0],      bP0 + nxt);
            GLDS16(&Bs[cur^1][w*32 + 16][0], bP0 + r16 + nxt);
        }
        short8 af[4], bf[4];
        #pragma unroll
        for (int i = 0; i < 4; ++i) af[i] = *(const short8*)&As[cur][wm + i*16 + l15][fsA];
        #pragma unroll
        for (int i = 0; i < 4; ++i) bf[i] = *(const short8*)&Bs[cur][wn + i*16 + l15][fsA];
        #pragma unroll
        for (int a = 0; a < 4; ++a)
            #pragma unroll
            for (int b = 0; b < 4; ++b)
                acc[a][b] = MFMA_16x16x32(af[a], bf[b], acc[a][b]);
        __syncthreads();
        cur ^= 1;
    }
    #pragma unroll
    for (int a = 0; a < 4; ++a)
      #pragma unroll
      for (int b = 0; b < 4; ++b)
        #pragma unroll
        for (int r = 0; r < 4; ++r) {
            int m = m0 + wm + a*16 + lhi*4 + r;
            int n = n0 + wn + b*16 + l15;
            size_t off = (size_t)m * N + n;
            float v = acc[a][b][r];
            if (EPI == 0) ((u16*)C)[off] = f2b(v);
            else ((float*)C)[off] = v;
        }
}

// ------- Shared GLU GEMM: 128M x 64N dual, 3 blocks/CU, bank-swizzled -------
__global__ __launch_bounds__(256) void k_glu_sh(
    const u16* __restrict__ Xb, const u16* __restrict__ W1t,
    const u16* __restrict__ W2t, u16* __restrict__ Hout,
    int M, int NE, int K)
{
    int bx = blockIdx.x, by = blockIdx.y, bz = blockIdx.z;
    xcd_swz(bx, by, bz);
    const int m0 = by * 128;
    const int n0 = bx * 64;

    __shared__ u16 As[2][128][32];
    __shared__ u16 B1s[2][64][32];
    __shared__ u16 B2s[2][64][32];

    const int tid = threadIdx.x, lane = tid & 63, w = tid >> 6;
    const int wm = (w >> 1) * 64, wn = (w & 1) * 32;
    const int l15 = lane & 15, lhi = lane >> 4;
    f32x4 acc1[4][2], acc2[4][2];
    #pragma unroll
    for (int a = 0; a < 4; ++a)
        #pragma unroll
        for (int j = 0; j < 2; ++j) { acc1[a][j] = 0; acc2[a][j] = 0; }

    const int gr  = w*32 + (lane >> 2);
    const int grB = w*16 + (lane >> 2);
    const int gc  = GSWZ(lane);
    const int fsA = FSWZ(lhi, l15);
    const u16* aP0 = Xb  + (size_t)(m0 + gr) * K + gc;
    const u16* aP1 = Xb  + (size_t)(m0 + gr + 16) * K + gc;
    const u16* b1P = W1t + (size_t)(n0 + grB) * K + gc;
    const u16* b2P = W2t + (size_t)(n0 + grB) * K + gc;

    auto stage = [&](int bf, int kk) {
        GLDS16(&As[bf][w*32][0],      aP0 + kk);
        GLDS16(&As[bf][w*32 + 16][0], aP1 + kk);
        GLDS16(&B1s[bf][w*16][0],     b1P + kk);
        GLDS16(&B2s[bf][w*16][0],     b2P + kk);
    };

    stage(0, 0);
    __syncthreads();
    int cur = 0;
    for (int k0 = 0; k0 < K; k0 += 32) {
        const int nxt = k0 + 32;
        if (nxt < K) stage(cur ^ 1, nxt);
        short8 af[4], b1[2], b2[2];
        #pragma unroll
        for (int i = 0; i < 4; ++i) af[i] = *(const short8*)&As[cur][wm + i*16 + l15][fsA];
        #pragma unroll
        for (int j = 0; j < 2; ++j) {
            b1[j] = *(const short8*)&B1s[cur][wn + j*16 + l15][fsA];
            b2[j] = *(const short8*)&B2s[cur][wn + j*16 + l15][fsA];
        }
        #pragma unroll
        for (int a = 0; a < 4; ++a)
            #pragma unroll
            for (int j = 0; j < 2; ++j) {
                acc1[a][j] = MFMA_16x16x32(af[a], b1[j], acc1[a][j]);
                acc2[a][j] = MFMA_16x16x32(af[a], b2[j], acc2[a][j]);
            }
        __syncthreads();
        cur ^= 1;
    }
    #pragma unroll
    for (int a = 0; a < 4; ++a)
      #pragma unroll
      for (int j = 0; j < 2; ++j)
        #pragma unroll
        for (int r = 0; r < 4; ++r) {
            int m = m0 + wm + a*16 + lhi*4 + r;
            int n = n0 + wn + j*16 + l15;
            float g = acc1[a][j][r], u = acc2[a][j][r];
            float hval = g / (1.0f + __expf(-g)) * u;
            Hout[(size_t)m * NE + n] = f2b(hval);
        }
}

// ------- Routed GLU GEMM: tile 256M x 64N dual, per-wave 128x(32+32) --------
__global__ __launch_bounds__(256, 2) void k_glu_rt(
    const u16* __restrict__ Xb, const u16* __restrict__ W1t,
    const u16* __restrict__ W2t, u16* __restrict__ Hout,
    const int* __restrict__ list, const int* __restrict__ cntp,
    int NE, int K)
{
    int bx = blockIdx.x, by = blockIdx.y, bz = blockIdx.z;
    xcd_swz(bx, by, bz);
    const int e = bz;
    const int cnt = cntp[e];
    const int m0 = by * 256;
    if (m0 >= cnt) return;
    const int n0 = bx * 64;
    const u16* w1 = W1t + (size_t)e * NE * K;
    const u16* w2 = W2t + (size_t)e * NE * K;
    u16* hout = Hout + (size_t)e * CAP * NE;
    const int* lst = list + e * CAP;

    __shared__ u16 As[2][256][32];
    __shared__ u16 B1s[2][64][32];
    __shared__ u16 B2s[2][64][32];

    const int tid = threadIdx.x, lane = tid & 63, w = tid >> 6;
    const int wm = (w >> 1) * 128, wn = (w & 1) * 32;
    const int l15 = lane & 15, lhi = lane >> 4;
    f32x4 acc1[8][2], acc2[8][2];
    #pragma unroll
    for (int a = 0; a < 8; ++a)
        #pragma unroll
        for (int j = 0; j < 2; ++j) { acc1[a][j] = 0; acc2[a][j] = 0; }

    const int gr = lane >> 2;
    const int gc = GSWZ(lane);
    const int fsA = FSWZ(lhi, l15);
    const u16* aP[4];
    #pragma unroll
    for (int j = 0; j < 4; ++j) {
        int mr = m0 + w*64 + j*16 + gr;
        int arow = (mr < cnt) ? (lst[mr] >> 3) : 0;
        aP[j] = Xb + (size_t)arow * K + gc;
    }
    const u16* b1P = w1 + (size_t)(n0 + w*16 + gr) * K + gc;
    const u16* b2P = w2 + (size_t)(n0 + w*16 + gr) * K + gc;

    auto stage = [&](int bf, int kk) {
        #pragma unroll
        for (int j = 0; j < 4; ++j)
            GLDS16(&As[bf][w*64 + j*16][0], aP[j] + kk);
        GLDS16(&B1s[bf][w*16][0], b1P + kk);
        GLDS16(&B2s[bf][w*16][0], b2P + kk);
    };

    stage(0, 0);
    __syncthreads();
    int cur = 0;
    for (int k0 = 0; k0 < K; k0 += 32) {
        const int nxt = k0 + 32;
        if (nxt < K) stage(cur ^ 1, nxt);
        short8 af[8], b1[2], b2[2];
        #pragma unroll
        for (int i = 0; i < 8; ++i) af[i] = *(const short8*)&As[cur][wm + i*16 + l15][fsA];
        #pragma unroll
        for (int j = 0; j < 2; ++j) {
            b1[j] = *(const short8*)&B1s[cur][wn + j*16 + l15][fsA];
            b2[j] = *(const short8*)&B2s[cur][wn + j*16 + l15][fsA];
        }
        #pragma unroll
        for (int a = 0; a < 8; ++a)
            #pragma unroll
            for (int j = 0; j < 2; ++j) {
                acc1[a][j] = MFMA_16x16x32(af[a], b1[j], acc1[a][j]);
                acc2[a][j] = MFMA_16x16x32(af[a], b2[j], acc2[a][j]);
            }
        __syncthreads();
        cur ^= 1;
    }
    #pragma unroll
    for (int a = 0; a < 8; ++a)
      #pragma unroll
      for (int j = 0; j < 2; ++j)
        #pragma unroll
        for (int r = 0; r < 4; ++r) {
            int m = m0 + wm + a*16 + lhi*4 + r;
            if (m < cnt) {
                int n = n0 + wn + j*16 + l15;
                float g = acc1[a][j][r], u = acc2[a][j][r];
                float hval = g / (1.0f + __expf(-g)) * u;
                hout[(size_t)m * NE + n] = f2b(hval);
            }
        }
}

// ------- Routed down GEMM: tile 256x128, per-wave 128x64, scatter -----------
__global__ __launch_bounds__(256, 2) void k_down_scatter(
    const u16* __restrict__ Hb, const u16* __restrict__ WdTt,
    u16* __restrict__ Rbuf, const int* __restrict__ list,
    const float* __restrict__ wts, const int* __restrict__ cntp,
    int N, int K)
{
    int bx = blockIdx.x, by = blockIdx.y, bz = blockIdx.z;
    xcd_swz(bx, by, bz);
    const int e = bz;
    const int cnt = cntp[e];
    const int m0 = by * 256;
    if (m0 >= cnt) return;
    const int n0 = bx * 128;
    const u16* A  = Hb   + (size_t)e * CAP * K;
    const u16* Bt = WdTt + (size_t)e * N * K;

    __shared__ u16 As[2][256][32];
    __shared__ u16 Bs[2][128][32];
    const int tid = threadIdx.x, lane = tid & 63, w = tid >> 6;
    const int wm = (w >> 1) * 128, wn = (w & 1) * 64;
    const int l15 = lane & 15, lhi = lane >> 4;
    f32x4 acc[8][4];
    #pragma unroll
    for (int a = 0; a < 8; ++a)
        #pragma unroll
        for (int b = 0; b < 4; ++b) acc[a][b] = 0;

    const int gr = lane >> 2;
    const int gc = GSWZ(lane);
    const int fsA = FSWZ(lhi, l15);
    const u16* aP = A  + (size_t)(m0 + w*64 + gr) * K + gc;
    const u16* bP = Bt + (size_t)(n0 + w*32 + gr) * K + gc;
    const size_t r16 = (size_t)16 * K;

    auto stage = [&](int bf, int kk) {
        GLDS16(&As[bf][w*64][0],      aP + kk);
        GLDS16(&As[bf][w*64 + 16][0], aP + r16 + kk);
        GLDS16(&As[bf][w*64 + 32][0], aP + 2*r16 + kk);
        GLDS16(&As[bf][w*64 + 48][0], aP + 3*r16 + kk);
        GLDS16(&Bs[bf][w*32][0],      bP + kk);
        GLDS16(&Bs[bf][w*32 + 16][0], bP + r16 + kk);
    };

    stage(0, 0);
    __syncthreads();
    int cur = 0;
    for (int k0 = 0; k0 < K; k0 += 32) {
        const int nxt = k0 + 32;
        if (nxt < K) stage(cur ^ 1, nxt);
        short8 af[8], bf4[4];
        #pragma unroll
        for (int i = 0; i < 8; ++i) af[i] = *(const short8*)&As[cur][wm + i*16 + l15][fsA];
        #pragma unroll
        for (int i = 0; i < 4; ++i) bf4[i] = *(const short8*)&Bs[cur][wn + i*16 + l15][fsA];
        #pragma unroll
        for (int a = 0; a < 8; ++a)
            #pragma unroll
            for (int b = 0; b < 4; ++b)
                acc[a][b] = MFMA_16x16x32(af[a], bf4[b], acc[a][b]);
        __syncthreads();
        cur ^= 1;
    }
    #pragma unroll
    for (int a = 0; a < 8; ++a)
      #pragma unroll
      for (int b = 0; b < 4; ++b)
        #pragma unroll
        for (int r = 0; r < 4; ++r) {
            int m = m0 + wm + a*16 + lhi*4 + r;
            if (m < cnt) {
                int n = n0 + wn + b*16 + l15;
                int enc = list[e*CAP + m];
                float wgt = wts[e*CAP + m];
                int tok = enc >> 3, kk = enc & 7;
                Rbuf[((size_t)tok*NTOP + kk)*N + n] = f2b(acc[a][b][r] * wgt);
            }
        }
}

// -------- Fused RoPE+split (q,k) AND V^T split, single launch ---------------
__global__ __launch_bounds__(256) void k_rope_vt(
    const float* __restrict__ QKV,
    const float* __restrict__ Cs, const float* __restrict__ Sn,
    u16* __restrict__ Qh, u16* __restrict__ Ql,
    u16* __restrict__ Kh, u16* __restrict__ Kl,
    u16* __restrict__ Vth, u16* __restrict__ Vtl)
{
    int id = blockIdx.x * 256 + threadIdx.x;
    if (id < TT*20*64) {
        int pr = id & 63;
        int rest = id >> 6;
        int hh = rest % 20;
        int tok = rest / 20;
        int d0 = pr * 2;
        float c0 = Cs[(size_t)tok*HDD + d0];
        float c1 = Cs[(size_t)tok*HDD + d0 + 1];
        float s0 = Sn[(size_t)tok*HDD + d0];
        float s1 = Sn[(size_t)tok*HDD + d0 + 1];
        const float* p = QKV + (size_t)tok*3072 + (hh < HH ? hh*HDD : 2048 + (hh - HH)*HDD);
        float x0 = p[d0], x1 = p[d0+1];
        float y0 = x0*c0 - x1*s0;
        float y1 = x1*c1 + x0*s1;
        u16 *oh, *ol;
        size_t ooff;
        if (hh < HH) { ooff = ((size_t)tok*HH + hh)*HDD + d0; oh = Qh; ol = Ql; }
        else         { ooff = ((size_t)tok*HKK + (hh - HH))*HDD + d0; oh = Kh; ol = Kl; }
        fsplit(y0, oh[ooff],     ol[ooff]);
        fsplit(y1, oh[ooff + 1], ol[ooff + 1]);
    } else {
        int vid = id - TT*20*64;       // 0 .. TT*HKK*HDD/8 - 1
        int oid = vid * 8;
        int s0 = oid & (SS - 1);
        int r = oid >> 10;
        int d = r & (HDD - 1);
        int bh = r >> 7;
        int b = bh >> 2, hk = bh & 3;
        #pragma unroll
        for (int j = 0; j < 8; ++j) {
            int s = s0 + j;
            float v = QKV[(size_t)(b*SS + s)*3072 + 2560 + hk*HDD + d];
            fsplit(v, Vth[oid + j], Vtl[oid + j]);
        }
    }
}

// ---------------- Flash attention, split-bf16 precision ---------------------
__global__ __launch_bounds__(256) void k_attn_hi(
    const u16* __restrict__ Qh, const u16* __restrict__ Ql,
    const u16* __restrict__ Kh, const u16* __restrict__ Kl,
    const u16* __restrict__ Vth, const u16* __restrict__ Vtl,
    u16* __restrict__ Oh, u16* __restrict__ Ol)
{
    const int tid = threadIdx.x;
    const int lane = tid & 63;
    const int w = tid >> 6;
    const int q0 = blockIdx.x * 64;
    const int b = blockIdx.y >> 4;
    const int h = blockIdx.y & 15;
    const int hk = h >> 2;
    const int l15 = lane & 15, lhi = lane >> 4;

    __shared__ u16 Ksh[32][136];
    __shared__ u16 Ksl[32][136];
    __shared__ u16 Vsh[128][40];
    __shared__ u16 Vsl[128][40];
    __shared__ u16 Psh[4][16][40];
    __shared__ u16 Psl[4][16][40];

    short8 qfh[4], qfl[4];
    {
        const int qrow = q0 + w*16 + l15;
        const u16* qph = Qh + ((size_t)(b*SS + qrow)*HH + h)*HDD;
        const u16* qpl = Ql + ((size_t)(b*SS + qrow)*HH + h)*HDD;
        #pragma unroll
        for (int c = 0; c < 4; ++c) {
            qfh[c] = *(const short8*)(qph + c*32 + lhi*8);
            qfl[c] = *(const short8*)(qpl + c*32 + lhi*8);
        }
    }

    f32x4 oacc[8];
    #pragma unroll
    for (int ch = 0; ch < 8; ++ch) oacc[ch] = 0;
    float m_r[4] = {-1e30f, -1e30f, -1e30f, -1e30f};
    float l_r[4] = {0.f, 0.f, 0.f, 0.f};

    const int nkt = (q0 + 64) >> 5;
    const int kr = tid >> 3, kc = (tid & 7) * 16;
    const int vd = tid >> 1, vj = (tid & 1) * 16;

    for (int kt = 0; kt < nkt; ++kt) {
        __syncthreads();
        {
            size_t koff = ((size_t)(b*SS + kt*32 + kr)*HKK + hk)*HDD + kc;
            *(short8*)&Ksh[kr][kc]     = *(const short8*)(Kh + koff);
            *(short8*)&Ksh[kr][kc + 8] = *(const short8*)(Kh + koff + 8);
            *(short8*)&Ksl[kr][kc]     = *(const short8*)(Kl + koff);
            *(short8*)&Ksl[kr][kc + 8] = *(const short8*)(Kl + koff + 8);
        }
        {
            size_t voff = ((size_t)(b*HKK + hk)*HDD + vd)*SS + kt*32 + vj;
            *(short8*)&Vsh[vd][vj]     = *(const short8*)(Vth + voff);
            *(short8*)&Vsh[vd][vj + 8] = *(const short8*)(Vth + voff + 8);
            *(short8*)&Vsl[vd][vj]     = *(const short8*)(Vtl + voff);
            *(short8*)&Vsl[vd][vj + 8] = *(const short8*)(Vtl + voff + 8);
        }
        __syncthreads();

        f32x4 s0 = 0, s1 = 0;
        #pragma unroll
        for (int c = 0; c < 4; ++c) {
            short8 kh0 = *(const short8*)&Ksh[l15][c*32 + lhi*8];
            short8 kl0 = *(const short8*)&Ksl[l15][c*32 + lhi*8];
            short8 kh1 = *(const short8*)&Ksh[16 + l15][c*32 + lhi*8];
            short8 kl1 = *(const short8*)&Ksl[16 + l15][c*32 + lhi*8];
            s0 = MFMA_16x16x32(qfh[c], kh0, s0);
            s0 = MFMA_16x16x32(qfh[c], kl0, s0);
            s0 = MFMA_16x16x32(qfl[c], kh0, s0);
            s1 = MFMA_16x16x32(qfh[c], kh1, s1);
            s1 = MFMA_16x16x32(qfh[c], kl1, s1);
            s1 = MFMA_16x16x32(qfl[c], kh1, s1);
        }
        const int irow0 = q0 + w*16 + lhi*4;
        const int j0 = kt*32 + l15;
        float ef[4];
        #pragma unroll
        for (int r = 0; r < 4; ++r) {
            float a0 = s0[r] * 0.08838834764831845f;
            float a1 = s1[r] * 0.08838834764831845f;
            const int ir = irow0 + r;
            if (j0 > ir) a0 = -1e30f;
            if (j0 + 16 > ir) a1 = -1e30f;
            float mx = fmaxf(a0, a1);
            #pragma unroll
            for (int o = 1; o < 16; o <<= 1) mx = fmaxf(mx, __shfl_xor(mx, o));
            float mn = fmaxf(m_r[r], mx);
            ef[r] = __expf(m_r[r] - mn);
            m_r[r] = mn;
            float p0 = __expf(a0 - mn);
            float p1 = __expf(a1 - mn);
            float ps = p0 + p1;
            #pragma unroll
            for (int o = 1; o < 16; o <<= 1) ps += __shfl_xor(ps, o);
            l_r[r] = l_r[r]*ef[r] + ps;
            fsplit(p0, Psh[w][lhi*4 + r][l15],      Psl[w][lhi*4 + r][l15]);
            fsplit(p1, Psh[w][lhi*4 + r][16 + l15], Psl[w][lhi*4 + r][16 + l15]);
        }
        #pragma unroll
        for (int ch = 0; ch < 8; ++ch) {
            f32x4 t = oacc[ch];
            t[0] *= ef[0]; t[1] *= ef[1]; t[2] *= ef[2]; t[3] *= ef[3];
            oacc[ch] = t;
        }
        __syncthreads();
        short8 pah = *(const short8*)&Psh[w][l15][lhi*8];
        short8 pal = *(const short8*)&Psl[w][l15][lhi*8];
        #pragma unroll
        for (int ch = 0; ch < 8; ++ch) {
            short8 bvh = *(const short8*)&Vsh[ch*16 + l15][lhi*8];
            short8 bvl = *(const short8*)&Vsl[ch*16 + l15][lhi*8];
            oacc[ch] = MFMA_16x16x32(pah, bvh, oacc[ch]);
            oacc[ch] = MFMA_16x16x32(pah, bvl, oacc[ch]);
            oacc[ch] = MFMA_16x16x32(pal, bvh, oacc[ch]);
        }
    }
    #pragma unroll
    for (int r = 0; r < 4; ++r) {
        const int row = q0 + w*16 + lhi*4 + r;
        const float inv = 1.0f / l_r[r];
        u16* oph = Oh + ((size_t)(b*SS + row)*HH + h)*HDD;
        u16* opl = Ol + ((size_t)(b*SS + row)*HH + h)*HDD;
        #pragma unroll
        for (int ch = 0; ch < 8; ++ch) {
            float o = oacc[ch][r] * inv;
            fsplit(o, oph[ch*16 + l15], opl[ch*16 + l15]);
        }
    }
}

// ---------------- Router: f32 logits, softmax, top-6, slot lists ------------
__global__ __launch_bounds__(256) void k_router(
    const float* __restrict__ X, const float* __restrict__ Wg,
    const float* __restrict__ bias,
    int* __restrict__ cnt, int* __restrict__ list, float* __restrict__ wts)
{
    const int t = blockIdx.x;
    const int e = threadIdx.x & 15, sl = threadIdx.x >> 4;
    const float* x = X + (size_t)t * DD;
    float part = 0.f;
    for (int i = 0; i < 128; ++i) {
        int k = sl * 128 + i;
        part += x[k] * Wg[(size_t)k * EE + e];
    }
    __shared__ float red[16][17];
    red[sl][e] = part;
    __syncthreads();
    if (threadIdx.x == 0) {
        float lg[16], pr[16];
        for (int ee = 0; ee < 16; ++ee) {
            float s = 0.f;
            for (int q = 0; q < 16; ++q) s += red[q][ee];
            lg[ee] = s;
        }
        float mx = lg[0];
        for (int ee = 1; ee < 16; ++ee) mx = fmaxf(mx, lg[ee]);
        float sum = 0.f;
        for (int ee = 0; ee < 16; ++ee) { pr[ee] = expf(lg[ee] - mx); sum += pr[ee]; }
        float isum = 1.0f / sum;
        for (int ee = 0; ee < 16; ++ee) pr[ee] *= isum;
        unsigned used = 0;
        int sel[NTOP]; float rw[NTOP]; float s6 = 0.f;
        for (int kk = 0; kk < NTOP; ++kk) {
            int best = 0; float bv = -1e30f;
            for (int ee = 0; ee < 16; ++ee) {
                if (used & (1u << ee)) continue;
                float sc = pr[ee] + bias[ee];
                if (sc > bv) { bv = sc; best = ee; }
            }
            used |= 1u << best;
            sel[kk] = best; rw[kk] = pr[best]; s6 += pr[best];
        }
        float inv6 = 1.0f / fmaxf(s6, 1e-12f);
        for (int kk = 0; kk < NTOP; ++kk) {
            int ee = sel[kk];
            int pos = atomicAdd(&cnt[ee], 1);
            list[ee*CAP + pos] = (t << 3) | kk;
            wts[ee*CAP + pos] = rw[kk] * inv6;
        }
    }
}

// ---------------- Final: out = h2 + shared + sum_kk routed ------------------
__global__ __launch_bounds__(256) void k_final(
    const float* __restrict__ h2, const float* __restrict__ yb,
    const u16* __restrict__ rb, float* __restrict__ out)
{
    int id = blockIdx.x * 256 + threadIdx.x;     // T*D/4
    size_t i4 = (size_t)id * 4;
    int t = id >> 9;
    int d = (id & 511) * 4;
    f32x4 acc = *(const f32x4*)(h2 + i4);
    f32x4 y = *(const f32x4*)(yb + i4);
    acc += y;
    #pragma unroll
    for (int kk = 0; kk < NTOP; ++kk) {
        s16x4 rv = *(const s16x4*)(rb + ((size_t)t*NTOP + kk)*DD + d);
        acc[0] += b2f((u16)rv[0]); acc[1] += b2f((u16)rv[1]);
        acc[2] += b2f((u16)rv[2]); acc[3] += b2f((u16)rv[3]);
    }
    *(f32x4*)(out + i4) = acc;
}

extern "C" void kernel_launch(void* const* d_in, const int* in_sizes, int n_in,
                              void* d_out, int out_size, void* d_ws, size_t ws_size,
                              hipStream_t stream)
{
    (void)in_sizes; (void)n_in; (void)out_size; (void)ws_size;
    const float* hidden = (const float*)d_in[0];
    const float* cosb   = (const float*)d_in[1];
    const float* sinb   = (const float*)d_in[2];
    const float* ln1    = (const float*)d_in[3];
    const float* ln2    = (const float*)d_in[4];
    const float* Wq     = (const float*)d_in[5];
    const float* Wk     = (const float*)d_in[6];
    const float* Wv     = (const float*)d_in[7];
    const float* Wo     = (const float*)d_in[8];
    const float* Wgate  = (const float*)d_in[9];
    const float* cbias  = (const float*)d_in[10];
    const float* Wg     = (const float*)d_in[11];
    const float* Wu     = (const float*)d_in[12];
    const float* Wd     = (const float*)d_in[13];
    const float* Wgs    = (const float*)d_in[14];
    const float* Wus    = (const float*)d_in[15];
    const float* Wds    = (const float*)d_in[16];
    float* out = (float*)d_out;

    char* ws = (char*)d_ws;
    size_t off = 0;
    auto alloc = [&](size_t bytes) {
        void* p = ws + off;
        off = (off + bytes + 255) & ~(size_t)255;
        return p;
    };
    // Pre-transposed bf16 weights
    u16* WqkvTh = (u16*)alloc((size_t)3072*2048*2);
    u16* WqkvTl = (u16*)alloc((size_t)3072*2048*2);
    u16* WoTh   = (u16*)alloc((size_t)2048*2048*2);
    u16* WoTl   = (u16*)alloc((size_t)2048*2048*2);
    u16* WgsT   = (u16*)alloc((size_t)2048*2048*2);
    u16* WusT   = (u16*)alloc((size_t)2048*2048*2);
    u16* WdsT   = (u16*)alloc((size_t)2048*2048*2);
    u16* WgT    = (u16*)alloc((size_t)EE*II*DD*2);
    u16* WuT    = (u16*)alloc((size_t)EE*II*DD*2);
    u16* WdT    = (u16*)alloc((size_t)EE*DD*II*2);
    // Activations
    u16*   x1h  = (u16*)  alloc((size_t)TT*DD*2);
    u16*   x1l  = (u16*)  alloc((size_t)TT*DD*2);
    float* qkvf = (float*)alloc((size_t)TT*3072*4);
    u16*   qh   = (u16*)  alloc((size_t)TT*HH*HDD*2);
    u16*   ql   = (u16*)  alloc((size_t)TT*HH*HDD*2);
    u16*   kh   = (u16*)  alloc((size_t)TT*HKK*HDD*2);
    u16*   kl   = (u16*)  alloc((size_t)TT*HKK*HDD*2);
    u16*   vth  = (u16*)  alloc((size_t)TT*HKK*HDD*2);
    u16*   vtl  = (u16*)  alloc((size_t)TT*HKK*HDD*2);
    u16*   aoh  = (u16*)  alloc((size_t)TT*HH*HDD*2);
    u16*   aol  = (u16*)  alloc((size_t)TT*HH*HDD*2);
    float* h2   = (float*)alloc((size_t)TT*DD*4);
    u16*   x2   = (u16*)  alloc((size_t)TT*DD*2);
    float* x2f  = (float*)alloc((size_t)TT*DD*4);
    int*   cnt  = (int*)  alloc(256);
    int*   lst  = (int*)  alloc((size_t)EE*CAP*4);
    float* wts  = (float*)alloc((size_t)EE*CAP*4);
    u16*   hE   = (u16*)  alloc((size_t)EE*CAP*II*2);
    u16*   rbuf = (u16*)  alloc((size_t)TT*NTOP*DD*2);
    // Aliases (lifetimes disjoint):
    u16*   hs   = x1h;            // [TT][ISS] bf16 = 8MB, x1h dead after QKV
    float* ybuf = qkvf;           // [TT][DD] f32 = 16MB, qkvf dead after splits

    // ---- Weight prep (transpose + bf16 convert [+ split]), 64x64 tiles ----
    k_prep<true ><<<dim3(32,32,1), 256, 0, stream>>>(Wq, WqkvTh, WqkvTl, 2048, 2048);
    k_prep<true ><<<dim3(8, 32,1), 256, 0, stream>>>(Wk, WqkvTh + (size_t)2048*2048, WqkvTl + (size_t)2048*2048, 2048, 512);
    k_prep<true ><<<dim3(8, 32,1), 256, 0, stream>>>(Wv, WqkvTh + (size_t)2560*2048, WqkvTl + (size_t)2560*2048, 2048, 512);
    k_prep<true ><<<dim3(32,32,1), 256, 0, stream>>>(Wo, WoTh, WoTl, 2048, 2048);
    k_prep<false><<<dim3(32,32,1), 256, 0, stream>>>(Wgs, WgsT, nullptr, 2048, 2048);
    k_prep<false><<<dim3(32,32,1), 256, 0, stream>>>(Wus, WusT, nullptr, 2048, 2048);
    k_prep<false><<<dim3(32,32,1), 256, 0, stream>>>(Wds, WdsT, nullptr, 2048, 2048);
    k_prep<false><<<dim3(16,32,EE), 256, 0, stream>>>(Wg, WgT, nullptr, 2048, 1024);
    k_prep<false><<<dim3(16,32,EE), 256, 0, stream>>>(Wu, WuT, nullptr, 2048, 1024);
    k_prep<false><<<dim3(32,16,EE), 256, 0, stream>>>(Wd, WdT, nullptr, 1024, 2048);

    // ---- Attention path (split-bf16 high precision) ----
    k_rmsnorm_split<<<TT, 256, 0, stream>>>(hidden, ln1, x1h, x1l);
    k_gemm_hi<2><<<dim3(24,16), 256, 0, stream>>>(x1h, x1l, WqkvTh, WqkvTl, qkvf, nullptr, TT, 3072, DD);
    k_rope_vt<<<(TT*20*64 + TT*HKK*HDD/8)/256, 256, 0, stream>>>(qkvf, cosb, sinb, qh, ql, kh, kl, vth, vtl);
    k_attn_hi<<<dim3(SS/64, BB*HH), 256, 0, stream>>>(qh, ql, kh, kl, vth, vtl, aoh, aol);
    k_gemm_hi<1><<<dim3(16,16), 256, 0, stream>>>(aoh, aol, WoTh, WoTl, h2, hidden, TT, DD, HH*HDD);

    // ---- MoE path ----
    k_rmsnorm_bf<<<TT, 256, 0, stream>>>(h2, ln2, x2, x2f);
    (void)hipMemsetAsync(cnt, 0, 256, stream);
    k_router<<<TT, 256, 0, stream>>>(x2f, Wgate, cbias, cnt, lst, wts);
    k_glu_sh<<<dim3(ISS/64, TT/128), 256, 0, stream>>>(x2, WgsT, WusT, hs, TT, ISS, DD);
    k_gemm<2><<<dim3(DD/128, TT/128), 256, 0, stream>>>(hs, WdsT, ybuf, TT, DD, ISS);
    k_glu_rt<<<dim3(II/64, CAP/256, EE), 256, 0, stream>>>(x2, WgT, WuT, hE, lst, cnt, II, DD);
    k_down_scatter<<<dim3(DD/128, CAP/256, EE), 256, 0, stream>>>(hE, WdT, rbuf, lst, wts, cnt, DD, II);
    k_final<<<(TT*DD/4)/256, 256, 0, stream>>>(h2, ybuf, rbuf, out);
}